// Round 1
// baseline (884.054 us; speedup 1.0000x reference)
//
#include <hip/hip_runtime.h>
#include <math.h>

#define Bv 4
#define Nv 3136
#define Cv 64
#define Hh 56
#define Ww 56
#define HIDv 256
#define TOPKv 8

constexpr float SCALE = 0.125f;   // d^-0.5, d=64
constexpr float EPS = 1e-5f;

__device__ __forceinline__ float wave_sum(float v) {
#pragma unroll
  for (int off = 32; off > 0; off >>= 1) v += __shfl_xor(v, off, 64);
  return v;
}

// ---------------- K0: weight transposes (coalesced-read layouts) ------------
// w1t[o*64+c] = w1[c*512+o]      (64x512 -> 512x64)
// lwt[(ci*9+tap)*64+co] = local_w[co*576+ci*9+tap]
__global__ void k_transpose(const float* __restrict__ w1, const float* __restrict__ lw,
                            float* __restrict__ w1t, float* __restrict__ lwt) {
  int p = blockIdx.x * 256 + threadIdx.x;
  if (p < 64 * 512) {
    int o = p >> 6, c = p & 63;
    w1t[p] = w1[c * 512 + o];
  }
  if (p < 64 * 576) {
    int co = p & 63, it = p >> 6;
    int ci = it / 9, tap = it % 9;
    lwt[p] = lw[co * 576 + ci * 9 + tap];
  }
}

// ---------------- K1: LN1 + Q/K/V projection (1 wave per token) -------------
__global__ void k_ln_qkv(const float* __restrict__ x,
                         const float* __restrict__ g1, const float* __restrict__ b1,
                         const float* __restrict__ wq, const float* __restrict__ bq,
                         const float* __restrict__ wkv, const float* __restrict__ bkv,
                         float* __restrict__ qo, float* __restrict__ ko,
                         float* __restrict__ vo) {
  __shared__ float xs[4][64];
  int tok = threadIdx.x >> 6, c = threadIdx.x & 63;
  int nt = blockIdx.x * 4 + tok;  // flat token over B*N
  float xv = x[nt * 64 + c];
  float m = wave_sum(xv) * (1.0f / 64.0f);
  float d = xv - m;
  float var = wave_sum(d * d) * (1.0f / 64.0f);
  float xn = d * rsqrtf(var + EPS) * g1[c] + b1[c];
  xs[tok][c] = xn;
  __syncthreads();
  float qa = bq[c], ka = bkv[c], va = bkv[64 + c];
#pragma unroll 8
  for (int j = 0; j < 64; ++j) {
    float xj = xs[tok][j];
    qa += xj * wq[j * 64 + c];
    ka += xj * wkv[j * 128 + c];
    va += xj * wkv[j * 128 + 64 + c];
  }
  qo[nt * 64 + c] = qa;
  ko[nt * 64 + c] = ka;
  vo[nt * 64 + c] = va;
}

// ---------------- K1b: sum of V rows per batch ------------------------------
__global__ void k_sumv(const float* __restrict__ v, float* __restrict__ sumv) {
  int b = blockIdx.x >> 4, slice = blockIdx.x & 15;
  int c = threadIdx.x;  // 64 threads
  float acc = 0.0f;
  int base = b * Nv + slice * 196;
  for (int n = 0; n < 196; ++n) acc += v[(size_t)(base + n) * 64 + c];
  atomicAdd(&sumv[b * 64 + c], acc);
}

// ---------------- K2: QK^T + top-8 + corrected softmax*V --------------------
// One workgroup = 16 query rows. 256 threads = (qi 0..15) x (jl 0..15).
// Exploits: p_j = 1/Z for non-top8 j  =>  g = (sum_v + sum_top8 (e^s - 1) v)/Z
__global__ __launch_bounds__(256) void k_attn(
    const float* __restrict__ qg, const float* __restrict__ kg,
    const float* __restrict__ vg, const float* __restrict__ sumv,
    float* __restrict__ gout) {
  __shared__ float qs[16][68];
  __shared__ float ks[64][68];
  __shared__ float candv[16][132];
  __shared__ int candi[16][132];
  __shared__ float kwS[16][8];
  __shared__ int kidxS[16][8];
  __shared__ float invZS[16];

  int b = blockIdx.x / 196, tile = blockIdx.x % 196;
  int qbase = b * Nv + tile * 16;  // flat token index of first query
  int t = threadIdx.x;

  for (int p = t; p < 16 * 64; p += 256)
    qs[p >> 6][p & 63] = qg[(size_t)(qbase + (p >> 6)) * 64 + (p & 63)];
  __syncthreads();

  int qi = t >> 4, jl = t & 15;
  float4 qreg[16];
#pragma unroll
  for (int c4 = 0; c4 < 16; ++c4) qreg[c4] = *(const float4*)&qs[qi][c4 * 4];

  float vals[8];
  int idxs[8];
#pragma unroll
  for (int u = 0; u < 8; ++u) { vals[u] = -1e30f; idxs[u] = -1; }

  for (int ch = 0; ch < 49; ++ch) {
    int jb = ch * 64;
    __syncthreads();  // protect ks against consumers of previous chunk
    for (int p = t; p < 64 * 64; p += 256)
      ks[p >> 6][p & 63] = kg[(size_t)(b * Nv + jb + (p >> 6)) * 64 + (p & 63)];
    __syncthreads();
#pragma unroll
    for (int i = 0; i < 4; ++i) {
      int j = jl + 16 * i;
      float4 a4 = make_float4(0.f, 0.f, 0.f, 0.f);
#pragma unroll
      for (int c4 = 0; c4 < 16; ++c4) {
        float4 k4 = *(const float4*)&ks[j][c4 * 4];
        a4.x += qreg[c4].x * k4.x;
        a4.y += qreg[c4].y * k4.y;
        a4.z += qreg[c4].z * k4.z;
        a4.w += qreg[c4].w * k4.w;
      }
      float s = (a4.x + a4.y + a4.z + a4.w) * SCALE;
      if (s > vals[7]) {  // sorted-descending insert (8 cndmask chains)
        float nv = s;
        int ni = jb + j;
#pragma unroll
        for (int u = 0; u < 8; ++u) {
          if (nv > vals[u]) {
            float tv = vals[u]; int ti = idxs[u];
            vals[u] = nv; idxs[u] = ni;
            nv = tv; ni = ti;
          }
        }
      }
    }
  }

#pragma unroll
  for (int u = 0; u < 8; ++u) {
    candv[qi][jl * 8 + u] = vals[u];
    candi[qi][jl * 8 + u] = idxs[u];
  }
  __syncthreads();

  if (t < 16) {
    int r = t;
    float Z = (float)(Nv - TOPKv);
#pragma unroll 1
    for (int u = 0; u < 8; ++u) {
      float best = -1e30f;
      int bp = 0;
      for (int i = 0; i < 128; ++i) {
        float vv = candv[r][i];
        if (vv > best) { best = vv; bp = i; }
      }
      float e = __expf(best);
      kwS[r][u] = e - 1.0f;
      Z += e;
      kidxS[r][u] = candi[r][bp];
      candv[r][bp] = -1e30f;
    }
    invZS[r] = 1.0f / Z;
  }
  __syncthreads();

  int c = t & 63, rg = t >> 6;
#pragma unroll 1
  for (int rr = 0; rr < 4; ++rr) {
    int r = rg * 4 + rr;
    float acc = sumv[b * 64 + c];
#pragma unroll
    for (int u = 0; u < 8; ++u)
      acc += kwS[r][u] * vg[(size_t)(b * Nv + kidxS[r][u]) * 64 + c];
    gout[(size_t)(qbase + r) * 64 + c] = acc * invZS[r];
  }
}

// ---------------- K3a: local 3x3 full conv (64->64) -------------------------
__global__ void k_locconv(const float* __restrict__ x, const float* __restrict__ lwt,
                          const float* __restrict__ lb, float* __restrict__ loc) {
  __shared__ float xt[3][6][64];
  int bid = blockIdx.x;
  int b = bid / (Hh * 14);
  int rem = bid % (Hh * 14);
  int h = rem / 14, wt = rem % 14;
  int t = threadIdx.x;
  for (int p = t; p < 18 * 64; p += 256) {
    int chn = p & 63, rc = p >> 6;
    int r = rc / 6, cc = rc % 6;
    int gh = h - 1 + r, gw = wt * 4 - 1 + cc;
    float v = 0.0f;
    if (gh >= 0 && gh < Hh && gw >= 0 && gw < Ww)
      v = x[(size_t)((b * Nv) + gh * Ww + gw) * 64 + chn];
    xt[r][cc][chn] = v;
  }
  __syncthreads();
  int tok = t >> 6, co = t & 63;
  float acc = lb[co];
  for (int ci = 0; ci < 64; ++ci) {
#pragma unroll
    for (int kh = 0; kh < 3; ++kh)
#pragma unroll
      for (int kw2 = 0; kw2 < 3; ++kw2)
        acc += xt[kh][tok + kw2][ci] * lwt[((ci * 9) + kh * 3 + kw2) * 64 + co];
  }
  int n = h * Ww + wt * 4 + tok;
  loc[(size_t)(b * Nv + n) * 64 + co] = acc;
}

// ---------------- K3b: proj + add loc + LN1 + residual + LN2 ----------------
__global__ void k_proj_res(const float* __restrict__ x, const float* __restrict__ gin,
                           const float* __restrict__ loc,
                           const float* __restrict__ wproj, const float* __restrict__ bproj,
                           const float* __restrict__ g1, const float* __restrict__ b1,
                           const float* __restrict__ g2, const float* __restrict__ b2,
                           float* __restrict__ x2, float* __restrict__ xn2) {
  __shared__ float gs[4][64];
  int tok = threadIdx.x >> 6, c = threadIdx.x & 63;
  int nt = blockIdx.x * 4 + tok;
  gs[tok][c] = gin[(size_t)nt * 64 + c];
  __syncthreads();
  float acc = bproj[c];
#pragma unroll 8
  for (int j = 0; j < 64; ++j) acc += gs[tok][j] * wproj[j * 64 + c];
  float y = acc + loc[(size_t)nt * 64 + c];
  float m = wave_sum(y) * (1.0f / 64.0f);
  float d = y - m;
  float var = wave_sum(d * d) * (1.0f / 64.0f);
  float t1 = d * rsqrtf(var + EPS) * g1[c] + b1[c];
  float x2v = x[(size_t)nt * 64 + c] + t1;
  float m2 = wave_sum(x2v) * (1.0f / 64.0f);
  float d2 = x2v - m2;
  float v2 = wave_sum(d2 * d2) * (1.0f / 64.0f);
  float xn2v = d2 * rsqrtf(v2 + EPS) * g2[c] + b2[c];
  x2[(size_t)nt * 64 + c] = x2v;
  xn2[(size_t)nt * 64 + c] = xn2v;
}

// ---------------- K5: MSFN (dw3x3 + dw5x5 -> 1x1) + final residual ----------
__global__ __launch_bounds__(256) void k_msfn(
    const float* __restrict__ xn2, const float* __restrict__ x2,
    const float* __restrict__ w3, const float* __restrict__ b3,
    const float* __restrict__ w5, const float* __restrict__ b5,
    const float* __restrict__ w1t, const float* __restrict__ b1,
    float* __restrict__ out) {
  __shared__ float xt[5 * 12 * 65];  // rows h-2..h+2, cols w0-2..w0+9, 64ch (+1 pad)
  __shared__ float ts[512 * 8];      // t[o][tok]
  int bid = blockIdx.x;
  int b = bid / (Hh * 7);
  int rem = bid % (Hh * 7);
  int h = rem / 7, wt = rem % 7;
  int t = threadIdx.x;
  for (int p = t; p < 60 * 64; p += 256) {
    int chn = p & 63, rc = p >> 6;
    int r = rc / 12, cc = rc % 12;
    int gh = h - 2 + r, gw = wt * 8 - 2 + cc;
    float v = 0.0f;
    if (gh >= 0 && gh < Hh && gw >= 0 && gw < Ww)
      v = xn2[(size_t)((b * Nv) + gh * Ww + gw) * 64 + chn];
    xt[(r * 12 + cc) * 65 + chn] = v;
  }
  __syncthreads();
  for (int p = t; p < 4096; p += 256) {
    int o = p >> 3, tok = p & 7;
    float acc;
    if (o < 256) {
      int cin = o >> 2;
      acc = b3[o];
#pragma unroll
      for (int kh = 0; kh < 3; ++kh)
#pragma unroll
        for (int kw2 = 0; kw2 < 3; ++kw2)
          acc += xt[((kh + 1) * 12 + tok + kw2 + 1) * 65 + cin] * w3[o * 9 + kh * 3 + kw2];
    } else {
      int oo = o - 256;
      int cin = oo >> 2;
      acc = b5[oo];
#pragma unroll
      for (int kh = 0; kh < 5; ++kh)
#pragma unroll
        for (int kw2 = 0; kw2 < 5; ++kw2)
          acc += xt[(kh * 12 + tok + kw2) * 65 + cin] * w5[oo * 25 + kh * 5 + kw2];
    }
    ts[o * 8 + tok] = acc;
  }
  __syncthreads();
  int c = t & 63, rg = t >> 6;
  for (int half = 0; half < 2; ++half) {
    int tok = rg + 4 * half;
    float acc = b1[c];
#pragma unroll 8
    for (int o = 0; o < 512; ++o) acc += ts[o * 8 + tok] * w1t[o * 64 + c];
    int n = h * Ww + wt * 8 + tok;
    out[(size_t)(b * Nv + n) * 64 + c] = x2[(size_t)(b * Nv + n) * 64 + c] + acc;
  }
}

extern "C" void kernel_launch(void* const* d_in, const int* in_sizes, int n_in,
                              void* d_out, int out_size, void* d_ws, size_t ws_size,
                              hipStream_t stream) {
  const float* x = (const float*)d_in[0];
  const float* n1g = (const float*)d_in[1];
  const float* n1b = (const float*)d_in[2];
  const float* wq = (const float*)d_in[3];
  const float* bq = (const float*)d_in[4];
  const float* wkv = (const float*)d_in[5];
  const float* bkv = (const float*)d_in[6];
  const float* wproj = (const float*)d_in[7];
  const float* bproj = (const float*)d_in[8];
  const float* lw = (const float*)d_in[9];
  const float* lb = (const float*)d_in[10];
  const float* n2g = (const float*)d_in[11];
  const float* n2b = (const float*)d_in[12];
  const float* w3 = (const float*)d_in[13];
  const float* b3 = (const float*)d_in[14];
  const float* w5 = (const float*)d_in[15];
  const float* b5 = (const float*)d_in[16];
  const float* w1 = (const float*)d_in[17];
  const float* b1 = (const float*)d_in[18];
  float* out = (float*)d_out;

  float* ws = (float*)d_ws;
  const size_t TOK = (size_t)Bv * Nv * Cv;  // 802816 floats
  float* qb = ws;
  float* kb = qb + TOK;
  float* vb = kb + TOK;
  float* gb = vb + TOK;
  float* sumv = gb + TOK;  // 256 floats
  float* loc = sumv + 256;
  float* x2 = loc + TOK;
  float* xn2 = x2 + TOK;
  float* w1t = xn2 + TOK;        // 64*512
  float* lwt = w1t + 64 * 512;   // 64*576

  k_transpose<<<144, 256, 0, stream>>>(w1, lw, w1t, lwt);
  k_ln_qkv<<<Bv * Nv / 4, 256, 0, stream>>>(x, n1g, n1b, wq, bq, wkv, bkv, qb, kb, vb);
  hipMemsetAsync(sumv, 0, 256 * sizeof(float), stream);
  k_sumv<<<64, 64, 0, stream>>>(vb, sumv);
  k_attn<<<Bv * 196, 256, 0, stream>>>(qb, kb, vb, sumv, gb);
  k_locconv<<<Bv * Hh * 14, 256, 0, stream>>>(x, lwt, lb, loc);
  k_proj_res<<<Bv * Nv / 4, 256, 0, stream>>>(x, gb, loc, wproj, bproj, n1g, n1b, n2g, n2b, x2, xn2);
  k_msfn<<<Bv * Hh * 7, 256, 0, stream>>>(xn2, x2, w3, b3, w5, b5, w1t, b1, out);
}

// Round 2
// 346.540 us; speedup vs baseline: 2.5511x; 2.5511x over previous
//
#include <hip/hip_runtime.h>
#include <math.h>

#define Bv 4
#define Nv 3136
#define Cv 64
#define Hh 56
#define Ww 56
#define HIDv 256
#define TOPKv 8

constexpr float SCALE = 0.125f;   // d^-0.5, d=64
constexpr float EPS = 1e-5f;

typedef short bf16x8 __attribute__((ext_vector_type(8)));
typedef float f32x4 __attribute__((ext_vector_type(4)));

__device__ __forceinline__ float wave_sum(float v) {
#pragma unroll
  for (int off = 32; off > 0; off >>= 1) v += __shfl_xor(v, off, 64);
  return v;
}

__device__ __forceinline__ unsigned short f2bf(float f) {
  unsigned int u = __float_as_uint(f);
  u = (u + 0x7FFFu + ((u >> 16) & 1u)) >> 16;
  return (unsigned short)u;
}

// monotone float->uint map, low 12 bits replaced by index
__device__ __forceinline__ unsigned int packScore(float s, int j) {
  unsigned int b = __float_as_uint(s);
  unsigned int m = b ^ ((b & 0x80000000u) ? 0xFFFFFFFFu : 0x80000000u);
  return (m & 0xFFFFF000u) | (unsigned int)j;
}
__device__ __forceinline__ float unpackScore(unsigned int p) {
  unsigned int m = p & 0xFFFFF000u;
  unsigned int b = (m & 0x80000000u) ? (m ^ 0x80000000u) : ~m;
  return __uint_as_float(b);
}

// ---------------- K0: weight transposes (coalesced-read layouts) ------------
__global__ void k_transpose(const float* __restrict__ w1, const float* __restrict__ lw,
                            float* __restrict__ w1t, float* __restrict__ lwt) {
  int p = blockIdx.x * 256 + threadIdx.x;
  if (p < 64 * 512) {
    int o = p >> 6, c = p & 63;
    w1t[p] = w1[c * 512 + o];
  }
  if (p < 64 * 576) {
    int co = p & 63, it = p >> 6;
    int ci = it / 9, tap = it % 9;
    lwt[p] = lw[co * 576 + ci * 9 + tap];
  }
}

// ---------------- K1: LN1 + Q/K/V projection (1 wave per token) -------------
// Writes Q,K as bf16 (for MFMA in k_attn), V as fp32.
__global__ void k_ln_qkv(const float* __restrict__ x,
                         const float* __restrict__ g1, const float* __restrict__ b1,
                         const float* __restrict__ wq, const float* __restrict__ bq,
                         const float* __restrict__ wkv, const float* __restrict__ bkv,
                         unsigned short* __restrict__ q16, unsigned short* __restrict__ k16,
                         float* __restrict__ vo) {
  __shared__ float xs[4][64];
  int tok = threadIdx.x >> 6, c = threadIdx.x & 63;
  int nt = blockIdx.x * 4 + tok;  // flat token over B*N
  float xv = x[nt * 64 + c];
  float m = wave_sum(xv) * (1.0f / 64.0f);
  float d = xv - m;
  float var = wave_sum(d * d) * (1.0f / 64.0f);
  float xn = d * rsqrtf(var + EPS) * g1[c] + b1[c];
  xs[tok][c] = xn;
  __syncthreads();
  float qa = bq[c], ka = bkv[c], va = bkv[64 + c];
#pragma unroll 8
  for (int j = 0; j < 64; ++j) {
    float xj = xs[tok][j];
    qa += xj * wq[j * 64 + c];
    ka += xj * wkv[j * 128 + c];
    va += xj * wkv[j * 128 + 64 + c];
  }
  q16[(size_t)nt * 64 + c] = f2bf(qa);
  k16[(size_t)nt * 64 + c] = f2bf(ka);
  vo[(size_t)nt * 64 + c] = va;
}

// ---------------- K1b: sum of V rows per batch ------------------------------
__global__ void k_sumv(const float* __restrict__ v, float* __restrict__ sumv) {
  int b = blockIdx.x >> 4, slice = blockIdx.x & 15;
  int c = threadIdx.x;  // 64 threads
  float acc = 0.0f;
  int base = b * Nv + slice * 196;
  for (int n = 0; n < 196; ++n) acc += v[(size_t)(base + n) * 64 + c];
  atomicAdd(&sumv[b * 64 + c], acc);
}

// ---------------- K2: MFMA QK^T + packed top-8 + corrected softmax*V --------
// Block = 4 waves, 16 query rows. Wave w covers keys ch*64 + w*16 + (lane&15).
// Scores packed as sortable uint32 (low 12 bits = key index); per-lane sorted
// top-8 per row, merged by shfl_xor bitonic butterfly, then 4-way LDS merge.
__global__ __launch_bounds__(256) void k_attn(
    const unsigned short* __restrict__ q16, const unsigned short* __restrict__ k16,
    const float* __restrict__ vg, const float* __restrict__ sumv,
    float* __restrict__ gout) {
  __shared__ unsigned int candLDS[16][4][8];
  __shared__ float kwS[16][8];
  __shared__ int kidxS[16][8];
  __shared__ float invZS[16];

  int b = blockIdx.x / 196, tile = blockIdx.x % 196;
  int qbase = b * Nv + tile * 16;  // flat token index of first query
  int t = threadIdx.x;
  int w = t >> 6, lane = t & 63;
  int n = lane & 15, quad = lane >> 4;
  size_t bN = (size_t)b * Nv;

  // A fragments: Q rows, A[m=lane&15][k=quad*8+j]
  const bf16x8 a0 = *(const bf16x8*)&q16[((size_t)(qbase + n)) * 64 + quad * 8];
  const bf16x8 a1 = *(const bf16x8*)&q16[((size_t)(qbase + n)) * 64 + 32 + quad * 8];

  unsigned int t8[4][8];
#pragma unroll
  for (int r = 0; r < 4; ++r)
#pragma unroll
    for (int u = 0; u < 8; ++u) t8[r][u] = 0u;

  // prefetch chunk 0 B frags
  int j0 = w * 16 + n;
  bf16x8 b0 = *(const bf16x8*)&k16[(bN + j0) * 64 + quad * 8];
  bf16x8 b1 = *(const bf16x8*)&k16[(bN + j0) * 64 + 32 + quad * 8];

  for (int ch = 0; ch < 49; ++ch) {
    bf16x8 c0 = b0, c1 = b1;
    int jcur = ch * 64 + w * 16 + n;
    if (ch < 48) {
      int jn = (ch + 1) * 64 + w * 16 + n;
      b0 = *(const bf16x8*)&k16[(bN + jn) * 64 + quad * 8];
      b1 = *(const bf16x8*)&k16[(bN + jn) * 64 + 32 + quad * 8];
    }
    f32x4 acc = {0.f, 0.f, 0.f, 0.f};
    acc = __builtin_amdgcn_mfma_f32_16x16x32_bf16(a0, c0, acc, 0, 0, 0);
    acc = __builtin_amdgcn_mfma_f32_16x16x32_bf16(a1, c1, acc, 0, 0, 0);
    // lane's score for row quad*4+r, key jcur
#pragma unroll
    for (int r = 0; r < 4; ++r) {
      float s = acc[r] * SCALE;
      unsigned int p = packScore(s, jcur);
      if (p > t8[r][7]) {
#pragma unroll
        for (int u = 0; u < 8; ++u) {
          unsigned int old = t8[r][u];
          t8[r][u] = max(p, old);
          p = min(p, old);
        }
      }
    }
  }

  // in-wave butterfly merge across the 16 lanes of each quad (same rows)
#pragma unroll
  for (int r = 0; r < 4; ++r) {
#pragma unroll
    for (int step = 1; step < 16; step <<= 1) {
      unsigned int o[8];
#pragma unroll
      for (int i = 0; i < 8; ++i) o[i] = __shfl_xor((int)t8[r][i], step, 64);
      unsigned int L[8];
#pragma unroll
      for (int i = 0; i < 8; ++i) L[i] = max(t8[r][i], o[7 - i]);
      // bitonic sort desc (8)
#pragma unroll
      for (int d = 4; d >= 1; d >>= 1) {
#pragma unroll
        for (int i = 0; i < 8; ++i) {
          if ((i & d) == 0 && (i ^ d) < 8 && (i ^ d) > i) {
            unsigned int hi = max(L[i], L[i | d]);
            unsigned int lo = min(L[i], L[i | d]);
            L[i] = hi;
            L[i | d] = lo;
          }
        }
      }
#pragma unroll
      for (int i = 0; i < 8; ++i) t8[r][i] = L[i];
    }
    if (n == 0) {
#pragma unroll
      for (int i = 0; i < 8; ++i) candLDS[quad * 4 + r][w][i] = t8[r][i];
    }
  }
  __syncthreads();

  // final 4-way merge + weights (threads 0..15, one per row)
  if (t < 16) {
    int r = t;
    int p0 = 0, p1 = 0, p2 = 0, p3 = 0;
    float Z = (float)(Nv - TOPKv);
#pragma unroll
    for (int u = 0; u < 8; ++u) {
      unsigned int c0 = (p0 < 8) ? candLDS[r][0][p0] : 0u;
      unsigned int c1 = (p1 < 8) ? candLDS[r][1][p1] : 0u;
      unsigned int c2 = (p2 < 8) ? candLDS[r][2][p2] : 0u;
      unsigned int c3 = (p3 < 8) ? candLDS[r][3][p3] : 0u;
      unsigned int best = c0;
      int bw = 0;
      if (c1 > best) { best = c1; bw = 1; }
      if (c2 > best) { best = c2; bw = 2; }
      if (c3 > best) { best = c3; bw = 3; }
      p0 += (bw == 0); p1 += (bw == 1); p2 += (bw == 2); p3 += (bw == 3);
      float s = unpackScore(best);
      float e = __expf(s);
      kwS[r][u] = e - 1.0f;
      kidxS[r][u] = (int)(best & 0xFFFu);
      Z += e;
    }
    invZS[r] = 1.0f / Z;
  }
  __syncthreads();

  // output: g = (sumv + sum_top8 (e^s - 1) v) / Z
  int c = lane, rg = w;  // 64 channels x 4 thread-groups
#pragma unroll 1
  for (int rr = 0; rr < 4; ++rr) {
    int r = rg * 4 + rr;
    float acc = sumv[b * 64 + c];
#pragma unroll
    for (int u = 0; u < 8; ++u)
      acc += kwS[r][u] * vg[(bN + kidxS[r][u]) * 64 + c];
    gout[(size_t)(qbase + r) * 64 + c] = acc * invZS[r];
  }
}

// ---------------- K3a: local 3x3 full conv (64->64) -------------------------
__global__ void k_locconv(const float* __restrict__ x, const float* __restrict__ lwt,
                          const float* __restrict__ lb, float* __restrict__ loc) {
  __shared__ float xt[3][6][64];
  int bid = blockIdx.x;
  int b = bid / (Hh * 14);
  int rem = bid % (Hh * 14);
  int h = rem / 14, wt = rem % 14;
  int t = threadIdx.x;
  for (int p = t; p < 18 * 64; p += 256) {
    int chn = p & 63, rc = p >> 6;
    int r = rc / 6, cc = rc % 6;
    int gh = h - 1 + r, gw = wt * 4 - 1 + cc;
    float v = 0.0f;
    if (gh >= 0 && gh < Hh && gw >= 0 && gw < Ww)
      v = x[(size_t)((b * Nv) + gh * Ww + gw) * 64 + chn];
    xt[r][cc][chn] = v;
  }
  __syncthreads();
  int tok = t >> 6, co = t & 63;
  float acc = lb[co];
  for (int ci = 0; ci < 64; ++ci) {
#pragma unroll
    for (int kh = 0; kh < 3; ++kh)
#pragma unroll
      for (int kw2 = 0; kw2 < 3; ++kw2)
        acc += xt[kh][tok + kw2][ci] * lwt[((ci * 9) + kh * 3 + kw2) * 64 + co];
  }
  int n = h * Ww + wt * 4 + tok;
  loc[(size_t)(b * Nv + n) * 64 + co] = acc;
}

// ---------------- K3b: proj + add loc + LN1 + residual + LN2 ----------------
__global__ void k_proj_res(const float* __restrict__ x, const float* __restrict__ gin,
                           const float* __restrict__ loc,
                           const float* __restrict__ wproj, const float* __restrict__ bproj,
                           const float* __restrict__ g1, const float* __restrict__ b1,
                           const float* __restrict__ g2, const float* __restrict__ b2,
                           float* __restrict__ x2, float* __restrict__ xn2) {
  __shared__ float gs[4][64];
  int tok = threadIdx.x >> 6, c = threadIdx.x & 63;
  int nt = blockIdx.x * 4 + tok;
  gs[tok][c] = gin[(size_t)nt * 64 + c];
  __syncthreads();
  float acc = bproj[c];
#pragma unroll 8
  for (int j = 0; j < 64; ++j) acc += gs[tok][j] * wproj[j * 64 + c];
  float y = acc + loc[(size_t)nt * 64 + c];
  float m = wave_sum(y) * (1.0f / 64.0f);
  float d = y - m;
  float var = wave_sum(d * d) * (1.0f / 64.0f);
  float t1 = d * rsqrtf(var + EPS) * g1[c] + b1[c];
  float x2v = x[(size_t)nt * 64 + c] + t1;
  float m2 = wave_sum(x2v) * (1.0f / 64.0f);
  float d2 = x2v - m2;
  float v2 = wave_sum(d2 * d2) * (1.0f / 64.0f);
  float xn2v = d2 * rsqrtf(v2 + EPS) * g2[c] + b2[c];
  x2[(size_t)nt * 64 + c] = x2v;
  xn2[(size_t)nt * 64 + c] = xn2v;
}

// ---------------- K5: MSFN (dw3x3 + dw5x5 -> 1x1) + final residual ----------
__global__ __launch_bounds__(256) void k_msfn(
    const float* __restrict__ xn2, const float* __restrict__ x2,
    const float* __restrict__ w3, const float* __restrict__ b3,
    const float* __restrict__ w5, const float* __restrict__ b5,
    const float* __restrict__ w1t, const float* __restrict__ b1,
    float* __restrict__ out) {
  __shared__ float xt[5 * 12 * 65];  // rows h-2..h+2, cols w0-2..w0+9, 64ch (+1 pad)
  __shared__ float ts[512 * 8];      // t[o][tok]
  int bid = blockIdx.x;
  int b = bid / (Hh * 7);
  int rem = bid % (Hh * 7);
  int h = rem / 7, wt = rem % 7;
  int t = threadIdx.x;
  for (int p = t; p < 60 * 64; p += 256) {
    int chn = p & 63, rc = p >> 6;
    int r = rc / 12, cc = rc % 12;
    int gh = h - 2 + r, gw = wt * 8 - 2 + cc;
    float v = 0.0f;
    if (gh >= 0 && gh < Hh && gw >= 0 && gw < Ww)
      v = xn2[(size_t)((b * Nv) + gh * Ww + gw) * 64 + chn];
    xt[(r * 12 + cc) * 65 + chn] = v;
  }
  __syncthreads();
  for (int p = t; p < 4096; p += 256) {
    int o = p >> 3, tok = p & 7;
    float acc;
    if (o < 256) {
      int cin = o >> 2;
      acc = b3[o];
#pragma unroll
      for (int kh = 0; kh < 3; ++kh)
#pragma unroll
        for (int kw2 = 0; kw2 < 3; ++kw2)
          acc += xt[((kh + 1) * 12 + tok + kw2 + 1) * 65 + cin] * w3[o * 9 + kh * 3 + kw2];
    } else {
      int oo = o - 256;
      int cin = oo >> 2;
      acc = b5[oo];
#pragma unroll
      for (int kh = 0; kh < 5; ++kh)
#pragma unroll
        for (int kw2 = 0; kw2 < 5; ++kw2)
          acc += xt[(kh * 12 + tok + kw2) * 65 + cin] * w5[oo * 25 + kh * 5 + kw2];
    }
    ts[o * 8 + tok] = acc;
  }
  __syncthreads();
  int c = t & 63, rg = t >> 6;
  for (int half = 0; half < 2; ++half) {
    int tok = rg + 4 * half;
    float acc = b1[c];
#pragma unroll 8
    for (int o = 0; o < 512; ++o) acc += ts[o * 8 + tok] * w1t[o * 64 + c];
    int n = h * Ww + wt * 8 + tok;
    out[(size_t)(b * Nv + n) * 64 + c] = x2[(size_t)(b * Nv + n) * 64 + c] + acc;
  }
}

extern "C" void kernel_launch(void* const* d_in, const int* in_sizes, int n_in,
                              void* d_out, int out_size, void* d_ws, size_t ws_size,
                              hipStream_t stream) {
  const float* x = (const float*)d_in[0];
  const float* n1g = (const float*)d_in[1];
  const float* n1b = (const float*)d_in[2];
  const float* wq = (const float*)d_in[3];
  const float* bq = (const float*)d_in[4];
  const float* wkv = (const float*)d_in[5];
  const float* bkv = (const float*)d_in[6];
  const float* wproj = (const float*)d_in[7];
  const float* bproj = (const float*)d_in[8];
  const float* lw = (const float*)d_in[9];
  const float* lb = (const float*)d_in[10];
  const float* n2g = (const float*)d_in[11];
  const float* n2b = (const float*)d_in[12];
  const float* w3 = (const float*)d_in[13];
  const float* b3 = (const float*)d_in[14];
  const float* w5 = (const float*)d_in[15];
  const float* b5 = (const float*)d_in[16];
  const float* w1 = (const float*)d_in[17];
  const float* b1 = (const float*)d_in[18];
  float* out = (float*)d_out;

  float* ws = (float*)d_ws;
  const size_t TOK = (size_t)Bv * Nv * Cv;  // 802816 floats
  float* vb = ws;
  float* gb = vb + TOK;
  float* sumv = gb + TOK;  // 256 floats
  float* loc = sumv + 256;
  float* x2 = loc + TOK;
  float* xn2 = x2 + TOK;
  float* w1t = xn2 + TOK;                    // 64*512
  float* lwt = w1t + 64 * 512;               // 64*576
  unsigned short* q16 = (unsigned short*)(lwt + 64 * 576);  // TOK ushorts
  unsigned short* k16 = q16 + TOK;

  k_transpose<<<144, 256, 0, stream>>>(w1, lw, w1t, lwt);
  k_ln_qkv<<<Bv * Nv / 4, 256, 0, stream>>>(x, n1g, n1b, wq, bq, wkv, bkv, q16, k16, vb);
  hipMemsetAsync(sumv, 0, 256 * sizeof(float), stream);
  k_sumv<<<64, 64, 0, stream>>>(vb, sumv);
  k_attn<<<Bv * 196, 256, 0, stream>>>(q16, k16, vb, sumv, gb);
  k_locconv<<<Bv * Hh * 14, 256, 0, stream>>>(x, lwt, lb, loc);
  k_proj_res<<<Bv * Nv / 4, 256, 0, stream>>>(x, gb, loc, wproj, bproj, n1g, n1b, n2g, n2b, x2, xn2);
  k_msfn<<<Bv * Hh * 7, 256, 0, stream>>>(xn2, x2, w3, b3, w5, b5, w1t, b1, out);
}

// Round 3
// 270.434 us; speedup vs baseline: 3.2690x; 1.2814x over previous
//
#include <hip/hip_runtime.h>
#include <math.h>

#define Bv 4
#define Nv 3136
#define Cv 64
#define Hh 56
#define Ww 56
#define HIDv 256
#define TOPKv 8
#define TSP 520   // ts row pitch in bf16 (512 + 8): b128 A-frag reads hit bank floor

constexpr float SCALE = 0.125f;   // d^-0.5, d=64
constexpr float EPS = 1e-5f;

typedef short bf16x8 __attribute__((ext_vector_type(8)));
typedef float f32x4 __attribute__((ext_vector_type(4)));

__device__ __forceinline__ float wave_sum(float v) {
#pragma unroll
  for (int off = 32; off > 0; off >>= 1) v += __shfl_xor(v, off, 64);
  return v;
}

__device__ __forceinline__ unsigned short f2bf(float f) {
  unsigned int u = __float_as_uint(f);
  u = (u + 0x7FFFu + ((u >> 16) & 1u)) >> 16;
  return (unsigned short)u;
}
__device__ __forceinline__ float bf2f(unsigned short u) {
  return __uint_as_float(((unsigned int)u) << 16);
}

// monotone float->uint map, low 12 bits replaced by index
__device__ __forceinline__ unsigned int packScore(float s, int j) {
  unsigned int b = __float_as_uint(s);
  unsigned int m = b ^ ((b & 0x80000000u) ? 0xFFFFFFFFu : 0x80000000u);
  return (m & 0xFFFFF000u) | (unsigned int)j;
}
__device__ __forceinline__ float unpackScore(unsigned int p) {
  unsigned int m = p & 0xFFFFF000u;
  unsigned int b = (m & 0x80000000u) ? (m ^ 0x80000000u) : ~m;
  return __uint_as_float(b);
}

// ---------------- K0: weight prep -------------------------------------------
// w1bf[p]            : bf16 cast of w1 (layout [cout][512] already B-frag friendly)
// lwt[(ci*9+tap)*64+co] = local_w[co*576+ci*9+tap]
// w3t[(tap*4+m)*64+cin] = w3[(cin*4+m)*9+tap]   (coalesced depthwise reads)
// w5t[(tap*4+m)*64+cin] = w5[(cin*4+m)*25+tap]
__global__ void k_transpose(const float* __restrict__ w1, const float* __restrict__ lw,
                            const float* __restrict__ w3, const float* __restrict__ w5,
                            unsigned short* __restrict__ w1bf, float* __restrict__ lwt,
                            float* __restrict__ w3t, float* __restrict__ w5t) {
  int p = blockIdx.x * 256 + threadIdx.x;
  if (p < 64 * 512) w1bf[p] = f2bf(w1[p]);
  if (p < 64 * 576) {
    int co = p & 63, it = p >> 6;
    int ci = it / 9, tap = it % 9;
    lwt[p] = lw[co * 576 + ci * 9 + tap];
  }
  if (p < 36 * 64) {
    int cin = p & 63, tm = p >> 6;
    int tap = tm >> 2, m = tm & 3;
    w3t[p] = w3[(cin * 4 + m) * 9 + tap];
  }
  if (p < 100 * 64) {
    int cin = p & 63, tm = p >> 6;
    int tap = tm >> 2, m = tm & 3;
    w5t[p] = w5[(cin * 4 + m) * 25 + tap];
  }
}

// ---------------- K1: LN1 + Q/K/V projection (1 wave per token) -------------
__global__ void k_ln_qkv(const float* __restrict__ x,
                         const float* __restrict__ g1, const float* __restrict__ b1,
                         const float* __restrict__ wq, const float* __restrict__ bq,
                         const float* __restrict__ wkv, const float* __restrict__ bkv,
                         unsigned short* __restrict__ q16, unsigned short* __restrict__ k16,
                         float* __restrict__ vo) {
  __shared__ float xs[4][64];
  int tok = threadIdx.x >> 6, c = threadIdx.x & 63;
  int nt = blockIdx.x * 4 + tok;  // flat token over B*N
  float xv = x[nt * 64 + c];
  float m = wave_sum(xv) * (1.0f / 64.0f);
  float d = xv - m;
  float var = wave_sum(d * d) * (1.0f / 64.0f);
  float xn = d * rsqrtf(var + EPS) * g1[c] + b1[c];
  xs[tok][c] = xn;
  __syncthreads();
  float qa = bq[c], ka = bkv[c], va = bkv[64 + c];
#pragma unroll 8
  for (int j = 0; j < 64; ++j) {
    float xj = xs[tok][j];
    qa += xj * wq[j * 64 + c];
    ka += xj * wkv[j * 128 + c];
    va += xj * wkv[j * 128 + 64 + c];
  }
  q16[(size_t)nt * 64 + c] = f2bf(qa);
  k16[(size_t)nt * 64 + c] = f2bf(ka);
  vo[(size_t)nt * 64 + c] = va;
}

// ---------------- K1b: sum of V rows per batch ------------------------------
__global__ void k_sumv(const float* __restrict__ v, float* __restrict__ sumv) {
  int b = blockIdx.x >> 4, slice = blockIdx.x & 15;
  int c = threadIdx.x;  // 64 threads
  float acc = 0.0f;
  int base = b * Nv + slice * 196;
  for (int n = 0; n < 196; ++n) acc += v[(size_t)(base + n) * 64 + c];
  atomicAdd(&sumv[b * 64 + c], acc);
}

// ---------------- K2: MFMA QK^T + packed top-8 + corrected softmax*V --------
__global__ __launch_bounds__(256) void k_attn(
    const unsigned short* __restrict__ q16, const unsigned short* __restrict__ k16,
    const float* __restrict__ vg, const float* __restrict__ sumv,
    float* __restrict__ gout) {
  __shared__ unsigned int candLDS[16][4][8];
  __shared__ float kwS[16][8];
  __shared__ int kidxS[16][8];
  __shared__ float invZS[16];

  int b = blockIdx.x / 196, tile = blockIdx.x % 196;
  int qbase = b * Nv + tile * 16;  // flat token index of first query
  int t = threadIdx.x;
  int w = t >> 6, lane = t & 63;
  int n = lane & 15, quad = lane >> 4;
  size_t bN = (size_t)b * Nv;

  const bf16x8 a0 = *(const bf16x8*)&q16[((size_t)(qbase + n)) * 64 + quad * 8];
  const bf16x8 a1 = *(const bf16x8*)&q16[((size_t)(qbase + n)) * 64 + 32 + quad * 8];

  unsigned int t8[4][8];
#pragma unroll
  for (int r = 0; r < 4; ++r)
#pragma unroll
    for (int u = 0; u < 8; ++u) t8[r][u] = 0u;

  int j0 = w * 16 + n;
  bf16x8 b0 = *(const bf16x8*)&k16[(bN + j0) * 64 + quad * 8];
  bf16x8 b1 = *(const bf16x8*)&k16[(bN + j0) * 64 + 32 + quad * 8];

  for (int ch = 0; ch < 49; ++ch) {
    bf16x8 c0 = b0, c1 = b1;
    int jcur = ch * 64 + w * 16 + n;
    if (ch < 48) {
      int jn = (ch + 1) * 64 + w * 16 + n;
      b0 = *(const bf16x8*)&k16[(bN + jn) * 64 + quad * 8];
      b1 = *(const bf16x8*)&k16[(bN + jn) * 64 + 32 + quad * 8];
    }
    f32x4 acc = {0.f, 0.f, 0.f, 0.f};
    acc = __builtin_amdgcn_mfma_f32_16x16x32_bf16(a0, c0, acc, 0, 0, 0);
    acc = __builtin_amdgcn_mfma_f32_16x16x32_bf16(a1, c1, acc, 0, 0, 0);
#pragma unroll
    for (int r = 0; r < 4; ++r) {
      float s = acc[r] * SCALE;
      unsigned int p = packScore(s, jcur);
      if (p > t8[r][7]) {
#pragma unroll
        for (int u = 0; u < 8; ++u) {
          unsigned int old = t8[r][u];
          t8[r][u] = max(p, old);
          p = min(p, old);
        }
      }
    }
  }

#pragma unroll
  for (int r = 0; r < 4; ++r) {
#pragma unroll
    for (int step = 1; step < 16; step <<= 1) {
      unsigned int o[8];
#pragma unroll
      for (int i = 0; i < 8; ++i) o[i] = __shfl_xor((int)t8[r][i], step, 64);
      unsigned int L[8];
#pragma unroll
      for (int i = 0; i < 8; ++i) L[i] = max(t8[r][i], o[7 - i]);
#pragma unroll
      for (int d = 4; d >= 1; d >>= 1) {
#pragma unroll
        for (int i = 0; i < 8; ++i) {
          if ((i & d) == 0 && (i ^ d) < 8 && (i ^ d) > i) {
            unsigned int hi = max(L[i], L[i | d]);
            unsigned int lo = min(L[i], L[i | d]);
            L[i] = hi;
            L[i | d] = lo;
          }
        }
      }
#pragma unroll
      for (int i = 0; i < 8; ++i) t8[r][i] = L[i];
    }
    if (n == 0) {
#pragma unroll
      for (int i = 0; i < 8; ++i) candLDS[quad * 4 + r][w][i] = t8[r][i];
    }
  }
  __syncthreads();

  if (t < 16) {
    int r = t;
    int p0 = 0, p1 = 0, p2 = 0, p3 = 0;
    float Z = (float)(Nv - TOPKv);
#pragma unroll
    for (int u = 0; u < 8; ++u) {
      unsigned int c0 = (p0 < 8) ? candLDS[r][0][p0] : 0u;
      unsigned int c1 = (p1 < 8) ? candLDS[r][1][p1] : 0u;
      unsigned int c2 = (p2 < 8) ? candLDS[r][2][p2] : 0u;
      unsigned int c3 = (p3 < 8) ? candLDS[r][3][p3] : 0u;
      unsigned int best = c0;
      int bw = 0;
      if (c1 > best) { best = c1; bw = 1; }
      if (c2 > best) { best = c2; bw = 2; }
      if (c3 > best) { best = c3; bw = 3; }
      p0 += (bw == 0); p1 += (bw == 1); p2 += (bw == 2); p3 += (bw == 3);
      float s = unpackScore(best);
      float e = __expf(s);
      kwS[r][u] = e - 1.0f;
      kidxS[r][u] = (int)(best & 0xFFFu);
      Z += e;
    }
    invZS[r] = 1.0f / Z;
  }
  __syncthreads();

  int c = lane, rg = w;
#pragma unroll 1
  for (int rr = 0; rr < 4; ++rr) {
    int r = rg * 4 + rr;
    float acc = sumv[b * 64 + c];
#pragma unroll
    for (int u = 0; u < 8; ++u)
      acc += kwS[r][u] * vg[(bN + kidxS[r][u]) * 64 + c];
    gout[(size_t)(qbase + r) * 64 + c] = acc * invZS[r];
  }
}

// ---------------- K3a: local 3x3 full conv (64->64) -------------------------
__global__ void k_locconv(const float* __restrict__ x, const float* __restrict__ lwt,
                          const float* __restrict__ lb, float* __restrict__ loc) {
  __shared__ float xt[3][6][64];
  int bid = blockIdx.x;
  int b = bid / (Hh * 14);
  int rem = bid % (Hh * 14);
  int h = rem / 14, wt = rem % 14;
  int t = threadIdx.x;
  for (int p = t; p < 18 * 64; p += 256) {
    int chn = p & 63, rc = p >> 6;
    int r = rc / 6, cc = rc % 6;
    int gh = h - 1 + r, gw = wt * 4 - 1 + cc;
    float v = 0.0f;
    if (gh >= 0 && gh < Hh && gw >= 0 && gw < Ww)
      v = x[(size_t)((b * Nv) + gh * Ww + gw) * 64 + chn];
    xt[r][cc][chn] = v;
  }
  __syncthreads();
  int tok = t >> 6, co = t & 63;
  float acc = lb[co];
  for (int ci = 0; ci < 64; ++ci) {
#pragma unroll
    for (int kh = 0; kh < 3; ++kh)
#pragma unroll
      for (int kw2 = 0; kw2 < 3; ++kw2)
        acc += xt[kh][tok + kw2][ci] * lwt[((ci * 9) + kh * 3 + kw2) * 64 + co];
  }
  int n = h * Ww + wt * 4 + tok;
  loc[(size_t)(b * Nv + n) * 64 + co] = acc;
}

// ---------------- K3b: proj + add loc + LN1 + residual + LN2 ----------------
// xn2 now stored bf16 (sole consumer is k_msfn depthwise convs).
__global__ void k_proj_res(const float* __restrict__ x, const float* __restrict__ gin,
                           const float* __restrict__ loc,
                           const float* __restrict__ wproj, const float* __restrict__ bproj,
                           const float* __restrict__ g1, const float* __restrict__ b1,
                           const float* __restrict__ g2, const float* __restrict__ b2,
                           float* __restrict__ x2, unsigned short* __restrict__ xn2b) {
  __shared__ float gs[4][64];
  int tok = threadIdx.x >> 6, c = threadIdx.x & 63;
  int nt = blockIdx.x * 4 + tok;
  gs[tok][c] = gin[(size_t)nt * 64 + c];
  __syncthreads();
  float acc = bproj[c];
#pragma unroll 8
  for (int j = 0; j < 64; ++j) acc += gs[tok][j] * wproj[j * 64 + c];
  float y = acc + loc[(size_t)nt * 64 + c];
  float m = wave_sum(y) * (1.0f / 64.0f);
  float d = y - m;
  float var = wave_sum(d * d) * (1.0f / 64.0f);
  float t1 = d * rsqrtf(var + EPS) * g1[c] + b1[c];
  float x2v = x[(size_t)nt * 64 + c] + t1;
  float m2 = wave_sum(x2v) * (1.0f / 64.0f);
  float d2 = x2v - m2;
  float v2 = wave_sum(d2 * d2) * (1.0f / 64.0f);
  float xn2v = d2 * rsqrtf(v2 + EPS) * g2[c] + b2[c];
  x2[(size_t)nt * 64 + c] = x2v;
  xn2b[(size_t)nt * 64 + c] = f2bf(xn2v);
}

// ---------------- K5: MSFN — depthwise in regs, 1x1 via MFMA ----------------
// Tile: 2 rows x 8 cols = 16 tokens. Thread (cin, tg): 4 tokens of channel cin,
// 5x8 input window in 40 regs, weights from pre-transposed w3t/w5t (coalesced).
// 1x1: C[16 tok][64 cout] = ts[16x512] @ w1bf^T via 16 MFMAs per wave.
__global__ __launch_bounds__(256) void k_msfn(
    const unsigned short* __restrict__ xn2b, const float* __restrict__ x2,
    const float* __restrict__ w3t, const float* __restrict__ b3,
    const float* __restrict__ w5t, const float* __restrict__ b5,
    const unsigned short* __restrict__ w1bf, const float* __restrict__ b1,
    float* __restrict__ out) {
  __shared__ __align__(16) unsigned short xtS[6 * 12 * 64];  // bf16 input tile
  __shared__ __align__(16) unsigned short tsS[16 * TSP];     // bf16 concat [tok][512]

  int bid = blockIdx.x;
  int b = bid / 196;
  int rem = bid % 196;
  int th = rem / 7, tw = rem % 7;
  int h0 = th * 2, w0 = tw * 8;
  size_t bN = (size_t)b * Nv;
  int t = threadIdx.x;

  // stage input tile (rows h0-2..h0+3, cols w0-2..w0+9) as ushort2
  unsigned int* xtU = (unsigned int*)xtS;
  for (int p = t; p < 6 * 12 * 32; p += 256) {
    int cp = p & 31, rc = p >> 5;
    int r = rc / 12, cc = rc % 12;
    int gh = h0 - 2 + r, gw = w0 - 2 + cc;
    unsigned int v = 0;
    if (gh >= 0 && gh < Hh && gw >= 0 && gw < Ww)
      v = *(const unsigned int*)&xn2b[(bN + gh * Ww + gw) * 64 + cp * 2];
    xtU[rc * 32 + cp] = v;
  }
  __syncthreads();

  int cin = t & 63, tg = t >> 6;
  int tr = tg >> 1, tc0 = (tg & 1) * 4;
  float win[5][8];
#pragma unroll
  for (int r = 0; r < 5; ++r)
#pragma unroll
    for (int c = 0; c < 8; ++c)
      win[r][c] = bf2f(xtS[((tr + r) * 12 + tc0 + c) * 64 + cin]);

  unsigned int* tsU = (unsigned int*)tsS;
#pragma unroll 1
  for (int m2 = 0; m2 < 4; m2 += 2) {
    float a3[2][9], a5[2][25], bb3[2], bb5[2];
#pragma unroll
    for (int mm = 0; mm < 2; ++mm) {
      int m = m2 + mm;
#pragma unroll
      for (int tap = 0; tap < 9; ++tap) a3[mm][tap] = w3t[(tap * 4 + m) * 64 + cin];
#pragma unroll
      for (int tap = 0; tap < 25; ++tap) a5[mm][tap] = w5t[(tap * 4 + m) * 64 + cin];
      bb3[mm] = b3[cin * 4 + m];
      bb5[mm] = b5[cin * 4 + m];
    }
#pragma unroll
    for (int tk = 0; tk < 4; ++tk) {
      int tok = tg * 4 + tk;
      unsigned int p3 = 0, p5 = 0;
#pragma unroll
      for (int mm = 0; mm < 2; ++mm) {
        float acc3 = bb3[mm];
#pragma unroll
        for (int kh = 0; kh < 3; ++kh)
#pragma unroll
          for (int kw2 = 0; kw2 < 3; ++kw2)
            acc3 += win[1 + kh][tk + 1 + kw2] * a3[mm][kh * 3 + kw2];
        float acc5 = bb5[mm];
#pragma unroll
        for (int kh = 0; kh < 5; ++kh)
#pragma unroll
          for (int kw2 = 0; kw2 < 5; ++kw2)
            acc5 += win[kh][tk + kw2] * a5[mm][kh * 5 + kw2];
        p3 |= (unsigned int)f2bf(acc3) << (16 * mm);
        p5 |= (unsigned int)f2bf(acc5) << (16 * mm);
      }
      tsU[(tok * TSP + cin * 4 + m2) >> 1] = p3;
      tsU[(tok * TSP + 256 + cin * 4 + m2) >> 1] = p5;
    }
  }
  __syncthreads();

  // 1x1 conv: wave wv covers couts wv*16..wv*16+15
  int wv = tg, lane = t & 63;
  int n16 = lane & 15, quad = lane >> 4;
  const unsigned short* wrow = &w1bf[(size_t)(wv * 16 + n16) * 512];
  f32x4 acc = {0.f, 0.f, 0.f, 0.f};
#pragma unroll 4
  for (int kk = 0; kk < 16; ++kk) {
    bf16x8 af = *(const bf16x8*)&tsS[n16 * TSP + kk * 32 + quad * 8];
    bf16x8 bfr = *(const bf16x8*)&wrow[kk * 32 + quad * 8];
    acc = __builtin_amdgcn_mfma_f32_16x16x32_bf16(af, bfr, acc, 0, 0, 0);
  }
  float bias = b1[wv * 16 + n16];
#pragma unroll
  for (int r = 0; r < 4; ++r) {
    int tok = quad * 4 + r;
    int trr = tok >> 3, tcc = tok & 7;
    size_t idx = (bN + (size_t)(h0 + trr) * Ww + w0 + tcc) * 64 + wv * 16 + n16;
    out[idx] = x2[idx] + acc[r] + bias;
  }
}

extern "C" void kernel_launch(void* const* d_in, const int* in_sizes, int n_in,
                              void* d_out, int out_size, void* d_ws, size_t ws_size,
                              hipStream_t stream) {
  const float* x = (const float*)d_in[0];
  const float* n1g = (const float*)d_in[1];
  const float* n1b = (const float*)d_in[2];
  const float* wq = (const float*)d_in[3];
  const float* bq = (const float*)d_in[4];
  const float* wkv = (const float*)d_in[5];
  const float* bkv = (const float*)d_in[6];
  const float* wproj = (const float*)d_in[7];
  const float* bproj = (const float*)d_in[8];
  const float* lw = (const float*)d_in[9];
  const float* lb = (const float*)d_in[10];
  const float* n2g = (const float*)d_in[11];
  const float* n2b = (const float*)d_in[12];
  const float* w3 = (const float*)d_in[13];
  const float* b3 = (const float*)d_in[14];
  const float* w5 = (const float*)d_in[15];
  const float* b5 = (const float*)d_in[16];
  const float* w1 = (const float*)d_in[17];
  const float* b1 = (const float*)d_in[18];
  float* out = (float*)d_out;

  float* ws = (float*)d_ws;
  const size_t TOK = (size_t)Bv * Nv * Cv;  // 802816
  float* vb = ws;
  float* gb = vb + TOK;
  float* sumv = gb + TOK;            // 256
  float* loc = sumv + 256;
  float* x2 = loc + TOK;
  float* lwt = x2 + TOK;             // 64*576
  float* w3t = lwt + 64 * 576;       // 2304
  float* w5t = w3t + 2304;           // 6400
  unsigned short* q16 = (unsigned short*)(w5t + 6400);
  unsigned short* k16 = q16 + TOK;
  unsigned short* xn2b = k16 + TOK;
  unsigned short* w1bf = xn2b + TOK; // 64*512

  k_transpose<<<144, 256, 0, stream>>>(w1, lw, w3, w5, w1bf, lwt, w3t, w5t);
  k_ln_qkv<<<Bv * Nv / 4, 256, 0, stream>>>(x, n1g, n1b, wq, bq, wkv, bkv, q16, k16, vb);
  hipMemsetAsync(sumv, 0, 256 * sizeof(float), stream);
  k_sumv<<<64, 64, 0, stream>>>(vb, sumv);
  k_attn<<<Bv * 196, 256, 0, stream>>>(q16, k16, vb, sumv, gb);
  k_locconv<<<Bv * Hh * 14, 256, 0, stream>>>(x, lwt, lb, loc);
  k_proj_res<<<Bv * Nv / 4, 256, 0, stream>>>(x, gb, loc, wproj, bproj, n1g, n1b, n2g, n2b, x2, xn2b);
  k_msfn<<<Bv * 196, 256, 0, stream>>>(xn2b, x2, w3t, b3, w5t, b5, w1bf, b1, out);
}

// Round 4
// 221.781 us; speedup vs baseline: 3.9862x; 1.2194x over previous
//
#include <hip/hip_runtime.h>
#include <math.h>

#define Bv 4
#define Nv 3136
#define Cv 64
#define Hh 56
#define Ww 56
#define HIDv 256
#define TOPKv 8
#define TSP 520   // msfn ts row pitch (bf16): dword pitch % 32 == 4 -> conflict-free b128
#define LCP 584   // locconv im2col row pitch (576+8): same property

constexpr float SCALE = 0.125f;   // d^-0.5, d=64
constexpr float EPS = 1e-5f;

typedef short bf16x8 __attribute__((ext_vector_type(8)));
typedef float f32x4 __attribute__((ext_vector_type(4)));

__device__ __forceinline__ float wave_sum(float v) {
#pragma unroll
  for (int off = 32; off > 0; off >>= 1) v += __shfl_xor(v, off, 64);
  return v;
}

__device__ __forceinline__ unsigned short f2bf(float f) {
  unsigned int u = __float_as_uint(f);
  u = (u + 0x7FFFu + ((u >> 16) & 1u)) >> 16;
  return (unsigned short)u;
}
__device__ __forceinline__ float bf2f(unsigned short u) {
  return __uint_as_float(((unsigned int)u) << 16);
}

// monotone float->uint map, low 12 bits replaced by index
__device__ __forceinline__ unsigned int packScore(float s, int j) {
  unsigned int b = __float_as_uint(s);
  unsigned int m = b ^ ((b & 0x80000000u) ? 0xFFFFFFFFu : 0x80000000u);
  return (m & 0xFFFFF000u) | (unsigned int)j;
}
__device__ __forceinline__ float unpackScore(unsigned int p) {
  unsigned int m = p & 0xFFFFF000u;
  unsigned int b = (m & 0x80000000u) ? (m ^ 0x80000000u) : ~m;
  return __uint_as_float(b);
}

// ---------------- K0: weight prep -------------------------------------------
// w1bf[p]               : bf16 of w1 ([cout][512] is already B-frag layout)
// lwb[co*576+tap*64+ci] : bf16 im2col of local_w (tap-major K order)
// w3t[(tap*4+m)*64+cin] = w3[(cin*4+m)*9+tap]
// w5t[(tap*4+m)*64+cin] = w5[(cin*4+m)*25+tap]
__global__ void k_transpose(const float* __restrict__ w1, const float* __restrict__ lw,
                            const float* __restrict__ w3, const float* __restrict__ w5,
                            unsigned short* __restrict__ w1bf, unsigned short* __restrict__ lwb,
                            float* __restrict__ w3t, float* __restrict__ w5t) {
  int p = blockIdx.x * 256 + threadIdx.x;
  if (p < 64 * 512) w1bf[p] = f2bf(w1[p]);
  if (p < 64 * 576) {
    int co = p / 576, k = p % 576;
    int tap = k >> 6, ci = k & 63;
    lwb[p] = f2bf(lw[co * 576 + ci * 9 + tap]);
  }
  if (p < 36 * 64) {
    int cin = p & 63, tm = p >> 6;
    int tap = tm >> 2, m = tm & 3;
    w3t[p] = w3[(cin * 4 + m) * 9 + tap];
  }
  if (p < 100 * 64) {
    int cin = p & 63, tm = p >> 6;
    int tap = tm >> 2, m = tm & 3;
    w5t[p] = w5[(cin * 4 + m) * 25 + tap];
  }
}

// ---------------- K1: LN1 + Q/K/V projection (1 wave per token) -------------
// Also emits x16 = bf16(x) for the MFMA local-conv.
__global__ void k_ln_qkv(const float* __restrict__ x,
                         const float* __restrict__ g1, const float* __restrict__ b1,
                         const float* __restrict__ wq, const float* __restrict__ bq,
                         const float* __restrict__ wkv, const float* __restrict__ bkv,
                         unsigned short* __restrict__ q16, unsigned short* __restrict__ k16,
                         float* __restrict__ vo, unsigned short* __restrict__ x16) {
  __shared__ float xs[4][64];
  int tok = threadIdx.x >> 6, c = threadIdx.x & 63;
  int nt = blockIdx.x * 4 + tok;  // flat token over B*N
  float xv = x[nt * 64 + c];
  x16[(size_t)nt * 64 + c] = f2bf(xv);
  float m = wave_sum(xv) * (1.0f / 64.0f);
  float d = xv - m;
  float var = wave_sum(d * d) * (1.0f / 64.0f);
  float xn = d * rsqrtf(var + EPS) * g1[c] + b1[c];
  xs[tok][c] = xn;
  __syncthreads();
  float qa = bq[c], ka = bkv[c], va = bkv[64 + c];
#pragma unroll 8
  for (int j = 0; j < 64; ++j) {
    float xj = xs[tok][j];
    qa += xj * wq[j * 64 + c];
    ka += xj * wkv[j * 128 + c];
    va += xj * wkv[j * 128 + 64 + c];
  }
  q16[(size_t)nt * 64 + c] = f2bf(qa);
  k16[(size_t)nt * 64 + c] = f2bf(ka);
  vo[(size_t)nt * 64 + c] = va;
}

// ---------------- K1b: sum of V rows per batch ------------------------------
__global__ void k_sumv(const float* __restrict__ v, float* __restrict__ sumv) {
  __shared__ float part[4][64];
  int b = blockIdx.x / 49, slice = blockIdx.x % 49;
  int w = threadIdx.x >> 6, c = threadIdx.x & 63;
  float acc = 0.0f;
  int base = b * Nv + slice * 64 + w * 16;
#pragma unroll
  for (int n = 0; n < 16; ++n) acc += v[(size_t)(base + n) * 64 + c];
  part[w][c] = acc;
  __syncthreads();
  if (threadIdx.x < 64) {
    float s = part[0][c] + part[1][c] + part[2][c] + part[3][c];
    atomicAdd(&sumv[b * 64 + c], s);
  }
}

// ---------------- K2: MFMA QK^T + packed top-8 + corrected softmax*V --------
__global__ __launch_bounds__(256) void k_attn(
    const unsigned short* __restrict__ q16, const unsigned short* __restrict__ k16,
    const float* __restrict__ vg, const float* __restrict__ sumv,
    float* __restrict__ gout) {
  __shared__ unsigned int candLDS[16][4][8];
  __shared__ float kwS[16][8];
  __shared__ int kidxS[16][8];
  __shared__ float invZS[16];

  int b = blockIdx.x / 196, tile = blockIdx.x % 196;
  int qbase = b * Nv + tile * 16;  // flat token index of first query
  int t = threadIdx.x;
  int w = t >> 6, lane = t & 63;
  int n = lane & 15, quad = lane >> 4;
  size_t bN = (size_t)b * Nv;

  const bf16x8 a0 = *(const bf16x8*)&q16[((size_t)(qbase + n)) * 64 + quad * 8];
  const bf16x8 a1 = *(const bf16x8*)&q16[((size_t)(qbase + n)) * 64 + 32 + quad * 8];

  unsigned int t8[4][8];
#pragma unroll
  for (int r = 0; r < 4; ++r)
#pragma unroll
    for (int u = 0; u < 8; ++u) t8[r][u] = 0u;

  int j0 = w * 16 + n;
  bf16x8 b0 = *(const bf16x8*)&k16[(bN + j0) * 64 + quad * 8];
  bf16x8 b1 = *(const bf16x8*)&k16[(bN + j0) * 64 + 32 + quad * 8];

  for (int ch = 0; ch < 49; ++ch) {
    bf16x8 c0 = b0, c1 = b1;
    int jcur = ch * 64 + w * 16 + n;
    if (ch < 48) {
      int jn = (ch + 1) * 64 + w * 16 + n;
      b0 = *(const bf16x8*)&k16[(bN + jn) * 64 + quad * 8];
      b1 = *(const bf16x8*)&k16[(bN + jn) * 64 + 32 + quad * 8];
    }
    f32x4 acc = {0.f, 0.f, 0.f, 0.f};
    acc = __builtin_amdgcn_mfma_f32_16x16x32_bf16(a0, c0, acc, 0, 0, 0);
    acc = __builtin_amdgcn_mfma_f32_16x16x32_bf16(a1, c1, acc, 0, 0, 0);
#pragma unroll
    for (int r = 0; r < 4; ++r) {
      float s = acc[r] * SCALE;
      unsigned int p = packScore(s, jcur);
      if (p > t8[r][7]) {
#pragma unroll
        for (int u = 0; u < 8; ++u) {
          unsigned int old = t8[r][u];
          t8[r][u] = max(p, old);
          p = min(p, old);
        }
      }
    }
  }

#pragma unroll
  for (int r = 0; r < 4; ++r) {
#pragma unroll
    for (int step = 1; step < 16; step <<= 1) {
      unsigned int o[8];
#pragma unroll
      for (int i = 0; i < 8; ++i) o[i] = __shfl_xor((int)t8[r][i], step, 64);
      unsigned int L[8];
#pragma unroll
      for (int i = 0; i < 8; ++i) L[i] = max(t8[r][i], o[7 - i]);
#pragma unroll
      for (int d = 4; d >= 1; d >>= 1) {
#pragma unroll
        for (int i = 0; i < 8; ++i) {
          if ((i & d) == 0 && (i ^ d) < 8 && (i ^ d) > i) {
            unsigned int hi = max(L[i], L[i | d]);
            unsigned int lo = min(L[i], L[i | d]);
            L[i] = hi;
            L[i | d] = lo;
          }
        }
      }
#pragma unroll
      for (int i = 0; i < 8; ++i) t8[r][i] = L[i];
    }
    if (n == 0) {
#pragma unroll
      for (int i = 0; i < 8; ++i) candLDS[quad * 4 + r][w][i] = t8[r][i];
    }
  }
  __syncthreads();

  if (t < 16) {
    int r = t;
    int p0 = 0, p1 = 0, p2 = 0, p3 = 0;
    float Z = (float)(Nv - TOPKv);
#pragma unroll
    for (int u = 0; u < 8; ++u) {
      unsigned int c0 = (p0 < 8) ? candLDS[r][0][p0] : 0u;
      unsigned int c1 = (p1 < 8) ? candLDS[r][1][p1] : 0u;
      unsigned int c2 = (p2 < 8) ? candLDS[r][2][p2] : 0u;
      unsigned int c3 = (p3 < 8) ? candLDS[r][3][p3] : 0u;
      unsigned int best = c0;
      int bw = 0;
      if (c1 > best) { best = c1; bw = 1; }
      if (c2 > best) { best = c2; bw = 2; }
      if (c3 > best) { best = c3; bw = 3; }
      p0 += (bw == 0); p1 += (bw == 1); p2 += (bw == 2); p3 += (bw == 3);
      float s = unpackScore(best);
      float e = __expf(s);
      kwS[r][u] = e - 1.0f;
      kidxS[r][u] = (int)(best & 0xFFFu);
      Z += e;
    }
    invZS[r] = 1.0f / Z;
  }
  __syncthreads();

  int c = lane, rg = w;
#pragma unroll 1
  for (int rr = 0; rr < 4; ++rr) {
    int r = rg * 4 + rr;
    float acc = sumv[b * 64 + c];
#pragma unroll
    for (int u = 0; u < 8; ++u)
      acc += kwS[r][u] * vg[(bN + kidxS[r][u]) * 64 + c];
    gout[(size_t)(qbase + r) * 64 + c] = acc * invZS[r];
  }
}

// ---------------- K3a: local 3x3 full conv (64->64) via im2col + MFMA -------
// 2x8 token tile, im2col in LDS [16][584] (tap-major K), 18 MFMAs per wave.
__global__ __launch_bounds__(256) void k_locconv(
    const unsigned short* __restrict__ x16, const unsigned short* __restrict__ lwb,
    const float* __restrict__ lb, float* __restrict__ loc) {
  __shared__ __align__(16) unsigned short im[16 * LCP];
  int bid = blockIdx.x;
  int b = bid / 196, rem = bid % 196;
  int th = rem / 7, tw = rem % 7;
  int h0 = th * 2, w0 = tw * 8;
  size_t bN = (size_t)b * Nv;
  int t = threadIdx.x;
  // 144 (tok,tap) segments x 8 sub-slices of 8 channels
  for (int p = t; p < 1152; p += 256) {
    int sub = p & 7, s = p >> 3;
    int tok = s / 9, tap = s % 9;
    int tr = tok >> 3, tc = tok & 7;
    int dh = tap / 3, dw = tap % 3;
    int gh = h0 + tr - 1 + dh, gw = w0 + tc - 1 + dw;
    bf16x8 v = {};
    if (gh >= 0 && gh < Hh && gw >= 0 && gw < Ww)
      v = *(const bf16x8*)&x16[(bN + gh * Ww + gw) * 64 + sub * 8];
    *(bf16x8*)&im[tok * LCP + tap * 64 + sub * 8] = v;
  }
  __syncthreads();
  int wv = t >> 6, lane = t & 63;
  int n16 = lane & 15, quad = lane >> 4;
  const unsigned short* wrow = &lwb[(size_t)(wv * 16 + n16) * 576];
  f32x4 acc = {0.f, 0.f, 0.f, 0.f};
#pragma unroll 6
  for (int kk = 0; kk < 18; ++kk) {
    bf16x8 af = *(const bf16x8*)&im[n16 * LCP + kk * 32 + quad * 8];
    bf16x8 bfr = *(const bf16x8*)&wrow[kk * 32 + quad * 8];
    acc = __builtin_amdgcn_mfma_f32_16x16x32_bf16(af, bfr, acc, 0, 0, 0);
  }
  float bias = lb[wv * 16 + n16];
#pragma unroll
  for (int r = 0; r < 4; ++r) {
    int tok = quad * 4 + r;
    int trr = tok >> 3, tcc = tok & 7;
    size_t idx = (bN + (size_t)(h0 + trr) * Ww + w0 + tcc) * 64 + wv * 16 + n16;
    loc[idx] = acc[r] + bias;
  }
}

// ---------------- K3b: proj + add loc + LN1 + residual + LN2 ----------------
__global__ void k_proj_res(const float* __restrict__ x, const float* __restrict__ gin,
                           const float* __restrict__ loc,
                           const float* __restrict__ wproj, const float* __restrict__ bproj,
                           const float* __restrict__ g1, const float* __restrict__ b1,
                           const float* __restrict__ g2, const float* __restrict__ b2,
                           float* __restrict__ x2, unsigned short* __restrict__ xn2b) {
  __shared__ float gs[4][64];
  int tok = threadIdx.x >> 6, c = threadIdx.x & 63;
  int nt = blockIdx.x * 4 + tok;
  gs[tok][c] = gin[(size_t)nt * 64 + c];
  __syncthreads();
  float acc = bproj[c];
#pragma unroll 8
  for (int j = 0; j < 64; ++j) acc += gs[tok][j] * wproj[j * 64 + c];
  float y = acc + loc[(size_t)nt * 64 + c];
  float m = wave_sum(y) * (1.0f / 64.0f);
  float d = y - m;
  float var = wave_sum(d * d) * (1.0f / 64.0f);
  float t1 = d * rsqrtf(var + EPS) * g1[c] + b1[c];
  float x2v = x[(size_t)nt * 64 + c] + t1;
  float m2 = wave_sum(x2v) * (1.0f / 64.0f);
  float d2 = x2v - m2;
  float v2 = wave_sum(d2 * d2) * (1.0f / 64.0f);
  float xn2v = d2 * rsqrtf(v2 + EPS) * g2[c] + b2[c];
  x2[(size_t)nt * 64 + c] = x2v;
  xn2b[(size_t)nt * 64 + c] = f2bf(xn2v);
}

// ---------------- K5: MSFN — depthwise in regs, 1x1 via MFMA ----------------
__global__ __launch_bounds__(256) void k_msfn(
    const unsigned short* __restrict__ xn2b, const float* __restrict__ x2,
    const float* __restrict__ w3t, const float* __restrict__ b3,
    const float* __restrict__ w5t, const float* __restrict__ b5,
    const unsigned short* __restrict__ w1bf, const float* __restrict__ b1,
    float* __restrict__ out) {
  __shared__ __align__(16) unsigned short xtS[6 * 12 * 64];
  __shared__ __align__(16) unsigned short tsS[16 * TSP];

  int bid = blockIdx.x;
  int b = bid / 196;
  int rem = bid % 196;
  int th = rem / 7, tw = rem % 7;
  int h0 = th * 2, w0 = tw * 8;
  size_t bN = (size_t)b * Nv;
  int t = threadIdx.x;

  unsigned int* xtU = (unsigned int*)xtS;
  for (int p = t; p < 6 * 12 * 32; p += 256) {
    int cp = p & 31, rc = p >> 5;
    int r = rc / 12, cc = rc % 12;
    int gh = h0 - 2 + r, gw = w0 - 2 + cc;
    unsigned int v = 0;
    if (gh >= 0 && gh < Hh && gw >= 0 && gw < Ww)
      v = *(const unsigned int*)&xn2b[(bN + gh * Ww + gw) * 64 + cp * 2];
    xtU[rc * 32 + cp] = v;
  }
  __syncthreads();

  int cin = t & 63, tg = t >> 6;
  int tr = tg >> 1, tc0 = (tg & 1) * 4;
  float win[5][8];
#pragma unroll
  for (int r = 0; r < 5; ++r)
#pragma unroll
    for (int c = 0; c < 8; ++c)
      win[r][c] = bf2f(xtS[((tr + r) * 12 + tc0 + c) * 64 + cin]);

  unsigned int* tsU = (unsigned int*)tsS;
#pragma unroll 1
  for (int m2 = 0; m2 < 4; m2 += 2) {
    float a3[2][9], a5[2][25], bb3[2], bb5[2];
#pragma unroll
    for (int mm = 0; mm < 2; ++mm) {
      int m = m2 + mm;
#pragma unroll
      for (int tap = 0; tap < 9; ++tap) a3[mm][tap] = w3t[(tap * 4 + m) * 64 + cin];
#pragma unroll
      for (int tap = 0; tap < 25; ++tap) a5[mm][tap] = w5t[(tap * 4 + m) * 64 + cin];
      bb3[mm] = b3[cin * 4 + m];
      bb5[mm] = b5[cin * 4 + m];
    }
#pragma unroll
    for (int tk = 0; tk < 4; ++tk) {
      int tok = tg * 4 + tk;
      unsigned int p3 = 0, p5 = 0;
#pragma unroll
      for (int mm = 0; mm < 2; ++mm) {
        float acc3 = bb3[mm];
#pragma unroll
        for (int kh = 0; kh < 3; ++kh)
#pragma unroll
          for (int kw2 = 0; kw2 < 3; ++kw2)
            acc3 += win[1 + kh][tk + 1 + kw2] * a3[mm][kh * 3 + kw2];
        float acc5 = bb5[mm];
#pragma unroll
        for (int kh = 0; kh < 5; ++kh)
#pragma unroll
          for (int kw2 = 0; kw2 < 5; ++kw2)
            acc5 += win[kh][tk + kw2] * a5[mm][kh * 5 + kw2];
        p3 |= (unsigned int)f2bf(acc3) << (16 * mm);
        p5 |= (unsigned int)f2bf(acc5) << (16 * mm);
      }
      tsU[(tok * TSP + cin * 4 + m2) >> 1] = p3;
      tsU[(tok * TSP + 256 + cin * 4 + m2) >> 1] = p5;
    }
  }
  __syncthreads();

  int wv = tg, lane = t & 63;
  int n16 = lane & 15, quad = lane >> 4;
  const unsigned short* wrow = &w1bf[(size_t)(wv * 16 + n16) * 512];
  f32x4 acc = {0.f, 0.f, 0.f, 0.f};
#pragma unroll 4
  for (int kk = 0; kk < 16; ++kk) {
    bf16x8 af = *(const bf16x8*)&tsS[n16 * TSP + kk * 32 + quad * 8];
    bf16x8 bfr = *(const bf16x8*)&wrow[kk * 32 + quad * 8];
    acc = __builtin_amdgcn_mfma_f32_16x16x32_bf16(af, bfr, acc, 0, 0, 0);
  }
  float bias = b1[wv * 16 + n16];
#pragma unroll
  for (int r = 0; r < 4; ++r) {
    int tok = quad * 4 + r;
    int trr = tok >> 3, tcc = tok & 7;
    size_t idx = (bN + (size_t)(h0 + trr) * Ww + w0 + tcc) * 64 + wv * 16 + n16;
    out[idx] = x2[idx] + acc[r] + bias;
  }
}

extern "C" void kernel_launch(void* const* d_in, const int* in_sizes, int n_in,
                              void* d_out, int out_size, void* d_ws, size_t ws_size,
                              hipStream_t stream) {
  const float* x = (const float*)d_in[0];
  const float* n1g = (const float*)d_in[1];
  const float* n1b = (const float*)d_in[2];
  const float* wq = (const float*)d_in[3];
  const float* bq = (const float*)d_in[4];
  const float* wkv = (const float*)d_in[5];
  const float* bkv = (const float*)d_in[6];
  const float* wproj = (const float*)d_in[7];
  const float* bproj = (const float*)d_in[8];
  const float* lw = (const float*)d_in[9];
  const float* lb = (const float*)d_in[10];
  const float* n2g = (const float*)d_in[11];
  const float* n2b = (const float*)d_in[12];
  const float* w3 = (const float*)d_in[13];
  const float* b3 = (const float*)d_in[14];
  const float* w5 = (const float*)d_in[15];
  const float* b5 = (const float*)d_in[16];
  const float* w1 = (const float*)d_in[17];
  const float* b1 = (const float*)d_in[18];
  float* out = (float*)d_out;

  float* ws = (float*)d_ws;
  const size_t TOK = (size_t)Bv * Nv * Cv;  // 802816
  float* vb = ws;
  float* gb = vb + TOK;
  float* sumv = gb + TOK;            // 256
  float* loc = sumv + 256;
  float* x2 = loc + TOK;
  float* w3t = x2 + TOK;             // 2304
  float* w5t = w3t + 2304;           // 6400
  unsigned short* q16 = (unsigned short*)(w5t + 6400);
  unsigned short* k16 = q16 + TOK;
  unsigned short* xn2b = k16 + TOK;
  unsigned short* x16 = xn2b + TOK;
  unsigned short* w1bf = x16 + TOK;  // 64*512
  unsigned short* lwb = w1bf + 64 * 512;  // 64*576

  k_transpose<<<144, 256, 0, stream>>>(w1, lw, w3, w5, w1bf, lwb, w3t, w5t);
  k_ln_qkv<<<Bv * Nv / 4, 256, 0, stream>>>(x, n1g, n1b, wq, bq, wkv, bkv, q16, k16, vb, x16);
  hipMemsetAsync(sumv, 0, 256 * sizeof(float), stream);
  k_sumv<<<Bv * 49, 256, 0, stream>>>(vb, sumv);
  k_attn<<<Bv * 196, 256, 0, stream>>>(q16, k16, vb, sumv, gb);
  k_locconv<<<Bv * 196, 256, 0, stream>>>(x16, lwb, lb, loc);
  k_proj_res<<<Bv * Nv / 4, 256, 0, stream>>>(x, gb, loc, wproj, bproj, n1g, n1b, n2g, n2b, x2, xn2b);
  k_msfn<<<Bv * 196, 256, 0, stream>>>(xn2b, x2, w3t, b3, w5t, b5, w1bf, b1, out);
}

// Round 5
// 216.851 us; speedup vs baseline: 4.0768x; 1.0227x over previous
//
#include <hip/hip_runtime.h>
#include <math.h>

#define Bv 4
#define Nv 3136
#define Cv 64
#define Hh 56
#define Ww 56
#define HIDv 256
#define TOPKv 8
#define TSP 520   // msfn ts row pitch (bf16): dword pitch % 32 == 4 -> conflict-free b128
#define LCP 584   // locconv im2col row pitch (576+8): same property

constexpr float SCALE = 0.125f;   // d^-0.5, d=64
constexpr float EPS = 1e-5f;

typedef short bf16x8 __attribute__((ext_vector_type(8)));
typedef float f32x4 __attribute__((ext_vector_type(4)));

#define CSWAP(a, b) { unsigned int _hi = max(a, b); unsigned int _lo = min(a, b); a = _hi; b = _lo; }
// descending bitonic clean of 8 (input: bitonic), 3 stages
#define BITONIC8(T) \
  CSWAP(T[0], T[4]); CSWAP(T[1], T[5]); CSWAP(T[2], T[6]); CSWAP(T[3], T[7]); \
  CSWAP(T[0], T[2]); CSWAP(T[1], T[3]); CSWAP(T[4], T[6]); CSWAP(T[5], T[7]); \
  CSWAP(T[0], T[1]); CSWAP(T[2], T[3]); CSWAP(T[4], T[5]); CSWAP(T[6], T[7]);

__device__ __forceinline__ float wave_sum(float v) {
#pragma unroll
  for (int off = 32; off > 0; off >>= 1) v += __shfl_xor(v, off, 64);
  return v;
}

__device__ __forceinline__ unsigned short f2bf(float f) {
  unsigned int u = __float_as_uint(f);
  u = (u + 0x7FFFu + ((u >> 16) & 1u)) >> 16;
  return (unsigned short)u;
}
__device__ __forceinline__ float bf2f(unsigned short u) {
  return __uint_as_float(((unsigned int)u) << 16);
}

// monotone float->uint map, low 12 bits replaced by index
__device__ __forceinline__ unsigned int packScore(float s, int j) {
  unsigned int b = __float_as_uint(s);
  unsigned int m = b ^ ((b & 0x80000000u) ? 0xFFFFFFFFu : 0x80000000u);
  return (m & 0xFFFFF000u) | (unsigned int)j;
}
__device__ __forceinline__ float unpackScore(unsigned int p) {
  unsigned int m = p & 0xFFFFF000u;
  unsigned int b = (m & 0x80000000u) ? (m ^ 0x80000000u) : ~m;
  return __uint_as_float(b);
}

// ---------------- K0: weight prep -------------------------------------------
__global__ void k_transpose(const float* __restrict__ w1, const float* __restrict__ lw,
                            const float* __restrict__ w3, const float* __restrict__ w5,
                            unsigned short* __restrict__ w1bf, unsigned short* __restrict__ lwb,
                            float* __restrict__ w3t, float* __restrict__ w5t) {
  int p = blockIdx.x * 256 + threadIdx.x;
  if (p < 64 * 512) w1bf[p] = f2bf(w1[p]);
  if (p < 64 * 576) {
    int co = p / 576, k = p % 576;
    int tap = k >> 6, ci = k & 63;
    lwb[p] = f2bf(lw[co * 576 + ci * 9 + tap]);
  }
  if (p < 36 * 64) {
    int cin = p & 63, tm = p >> 6;
    int tap = tm >> 2, m = tm & 3;
    w3t[p] = w3[(cin * 4 + m) * 9 + tap];
  }
  if (p < 100 * 64) {
    int cin = p & 63, tm = p >> 6;
    int tap = tm >> 2, m = tm & 3;
    w5t[p] = w5[(cin * 4 + m) * 25 + tap];
  }
}

// ---------------- K1: LN1 + Q/K/V projection (1 wave per token) -------------
__global__ void k_ln_qkv(const float* __restrict__ x,
                         const float* __restrict__ g1, const float* __restrict__ b1,
                         const float* __restrict__ wq, const float* __restrict__ bq,
                         const float* __restrict__ wkv, const float* __restrict__ bkv,
                         unsigned short* __restrict__ q16, unsigned short* __restrict__ k16,
                         float* __restrict__ vo, unsigned short* __restrict__ x16) {
  __shared__ float xs[4][64];
  int tok = threadIdx.x >> 6, c = threadIdx.x & 63;
  int nt = blockIdx.x * 4 + tok;  // flat token over B*N
  float xv = x[nt * 64 + c];
  x16[(size_t)nt * 64 + c] = f2bf(xv);
  float m = wave_sum(xv) * (1.0f / 64.0f);
  float d = xv - m;
  float var = wave_sum(d * d) * (1.0f / 64.0f);
  float xn = d * rsqrtf(var + EPS) * g1[c] + b1[c];
  xs[tok][c] = xn;
  __syncthreads();
  float qa = bq[c], ka = bkv[c], va = bkv[64 + c];
#pragma unroll 8
  for (int j = 0; j < 64; ++j) {
    float xj = xs[tok][j];
    qa += xj * wq[j * 64 + c];
    ka += xj * wkv[j * 128 + c];
    va += xj * wkv[j * 128 + 64 + c];
  }
  q16[(size_t)nt * 64 + c] = f2bf(qa);
  k16[(size_t)nt * 64 + c] = f2bf(ka);
  vo[(size_t)nt * 64 + c] = va;
}

// ---------------- K1b: sum of V rows per batch ------------------------------
__global__ void k_sumv(const float* __restrict__ v, float* __restrict__ sumv) {
  __shared__ float part[4][64];
  int b = blockIdx.x / 49, slice = blockIdx.x % 49;
  int w = threadIdx.x >> 6, c = threadIdx.x & 63;
  float acc = 0.0f;
  int base = b * Nv + slice * 64 + w * 16;
#pragma unroll
  for (int n = 0; n < 16; ++n) acc += v[(size_t)(base + n) * 64 + c];
  part[w][c] = acc;
  __syncthreads();
  if (threadIdx.x < 64) {
    float s = part[0][c] + part[1][c] + part[2][c] + part[3][c];
    atomicAdd(&sumv[b * 64 + c], s);
  }
}

// ---------------- K2a: MFMA QK^T + per-row top-8 over a key half ------------
// Transposed MFMA: A=keys, B=queries -> lane owns ONE query row (col=lane&15)
// and 4 keys (row=quad*4+r) per chunk. 8-reg packed top-8 state per lane.
// Grid: Bv*196*2 blocks (bit0 = key half).
__global__ __launch_bounds__(256) void k_attn_topk(
    const unsigned short* __restrict__ q16, const unsigned short* __restrict__ k16,
    unsigned int* __restrict__ top8out) {
  __shared__ unsigned int candLDS[16][4][8];
  int bid = blockIdx.x;
  int half = bid & 1;
  int lin = bid >> 1;
  int b = lin / 196, tile = lin % 196;
  int qbase = b * Nv + tile * 16;
  size_t bN = (size_t)b * Nv;
  int t = threadIdx.x;
  int w = t >> 6, lane = t & 63;
  int qcol = lane & 15, quad = lane >> 4;

  // B fragments: 16 query rows (held for whole kernel)
  const bf16x8 qf0 = *(const bf16x8*)&q16[((size_t)(qbase + qcol)) * 64 + quad * 8];
  const bf16x8 qf1 = *(const bf16x8*)&q16[((size_t)(qbase + qcol)) * 64 + 32 + quad * 8];

  unsigned int t8[8];
  unsigned int PACKNEG = packScore(-1e30f, 0);
#pragma unroll
  for (int u = 0; u < 8; ++u) t8[u] = PACKNEG;
  float thrRaw = -3.0e38f;  // threshold on RAW (unscaled) scores

  int chBeg = half ? 24 : 0;
  int chEnd = half ? 49 : 24;
  int keyRow = w * 16 + qcol;  // A-frag m index within a 64-key chunk
  bf16x8 kf0 = *(const bf16x8*)&k16[(bN + chBeg * 64 + keyRow) * 64 + quad * 8];
  bf16x8 kf1 = *(const bf16x8*)&k16[(bN + chBeg * 64 + keyRow) * 64 + 32 + quad * 8];

  for (int ch = chBeg; ch < chEnd; ++ch) {
    bf16x8 c0 = kf0, c1 = kf1;
    if (ch + 1 < chEnd) {
      kf0 = *(const bf16x8*)&k16[(bN + (ch + 1) * 64 + keyRow) * 64 + quad * 8];
      kf1 = *(const bf16x8*)&k16[(bN + (ch + 1) * 64 + keyRow) * 64 + 32 + quad * 8];
    }
    f32x4 acc = {0.f, 0.f, 0.f, 0.f};
    acc = __builtin_amdgcn_mfma_f32_16x16x32_bf16(c0, qf0, acc, 0, 0, 0);
    acc = __builtin_amdgcn_mfma_f32_16x16x32_bf16(c1, qf1, acc, 0, 0, 0);
    float m01 = fmaxf(acc[0], acc[1]);
    float m23 = fmaxf(acc[2], acc[3]);
    if (fmaxf(m01, m23) > thrRaw) {
      int jb = ch * 64 + w * 16 + quad * 4;
      unsigned int p0 = packScore(acc[0] * SCALE, jb + 0);
      unsigned int p1 = packScore(acc[1] * SCALE, jb + 1);
      unsigned int p2 = packScore(acc[2] * SCALE, jb + 2);
      unsigned int p3 = packScore(acc[3] * SCALE, jb + 3);
      // sort4 desc
      CSWAP(p0, p1); CSWAP(p2, p3); CSWAP(p0, p2); CSWAP(p1, p3); CSWAP(p1, p2);
      // half-clean merge of sorted8 + sorted4 (tail), then 3-stage bitonic
      t8[4] = max(t8[4], p3);
      t8[5] = max(t8[5], p2);
      t8[6] = max(t8[6], p1);
      t8[7] = max(t8[7], p0);
      BITONIC8(t8);
      thrRaw = unpackScore(t8[7]) * 8.0f;
    }
  }

  // merge across quads (same query col): butterfly xor 16, 32
#pragma unroll
  for (int step = 16; step <= 32; step <<= 1) {
    unsigned int o[8];
#pragma unroll
    for (int i = 0; i < 8; ++i) o[i] = (unsigned int)__shfl_xor((int)t8[i], step, 64);
    unsigned int nw[8];
#pragma unroll
    for (int i = 0; i < 8; ++i) nw[i] = max(t8[i], o[7 - i]);
#pragma unroll
    for (int i = 0; i < 8; ++i) t8[i] = nw[i];
    BITONIC8(t8);
  }
  if (quad == 0) {
#pragma unroll
    for (int i = 0; i < 8; ++i) candLDS[qcol][w][i] = t8[i];
  }
  __syncthreads();

  // 4-way merge across waves; emit sorted top-8 of this key half
  if (t < 16) {
    int r = t;
    int p0 = 0, p1 = 0, p2 = 0, p3 = 0;
    size_t obase = ((size_t)(bN + tile * 16 + r)) * 16 + half * 8;
#pragma unroll
    for (int u = 0; u < 8; ++u) {
      unsigned int c0 = (p0 < 8) ? candLDS[r][0][p0] : 0u;
      unsigned int c1 = (p1 < 8) ? candLDS[r][1][p1] : 0u;
      unsigned int c2 = (p2 < 8) ? candLDS[r][2][p2] : 0u;
      unsigned int c3 = (p3 < 8) ? candLDS[r][3][p3] : 0u;
      unsigned int best = c0;
      int bw = 0;
      if (c1 > best) { best = c1; bw = 1; }
      if (c2 > best) { best = c2; bw = 2; }
      if (c3 > best) { best = c3; bw = 3; }
      p0 += (bw == 0); p1 += (bw == 1); p2 += (bw == 2); p3 += (bw == 3);
      top8out[obase + u] = best;
    }
  }
}

// ---------------- K2b: merge halves + corrected softmax*V -------------------
__global__ __launch_bounds__(256) void k_attn_out(
    const unsigned int* __restrict__ top8, const float* __restrict__ vg,
    const float* __restrict__ sumv, float* __restrict__ gout) {
  __shared__ float kwS[16][8];
  __shared__ int kidxS[16][8];
  __shared__ float invZS[16];
  int b = blockIdx.x / 196, tile = blockIdx.x % 196;
  int qbase = b * Nv + tile * 16;
  size_t bN = (size_t)b * Nv;
  int t = threadIdx.x;
  if (t < 16) {
    size_t base = (size_t)(qbase + t) * 16;
    unsigned int A[8], Bb[8];
#pragma unroll
    for (int i = 0; i < 8; ++i) A[i] = top8[base + i];
#pragma unroll
    for (int i = 0; i < 8; ++i) Bb[i] = top8[base + 8 + i];
#pragma unroll
    for (int i = 0; i < 8; ++i) A[i] = max(A[i], Bb[7 - i]);
    BITONIC8(A);
    float Z = (float)(Nv - TOPKv);
#pragma unroll
    for (int u = 0; u < 8; ++u) {
      float s = unpackScore(A[u]);
      float e = __expf(s);
      kwS[t][u] = e - 1.0f;
      kidxS[t][u] = (int)(A[u] & 0xFFFu);
      Z += e;
    }
    invZS[t] = 1.0f / Z;
  }
  __syncthreads();
  int c = t & 63, rg = t >> 6;
#pragma unroll 1
  for (int rr = 0; rr < 4; ++rr) {
    int r = rg * 4 + rr;
    float acc = sumv[b * 64 + c];
#pragma unroll
    for (int u = 0; u < 8; ++u)
      acc += kwS[r][u] * vg[(bN + kidxS[r][u]) * 64 + c];
    gout[(size_t)(qbase + r) * 64 + c] = acc * invZS[r];
  }
}

// ---------------- K3a: local 3x3 full conv (64->64) via im2col + MFMA -------
__global__ __launch_bounds__(256) void k_locconv(
    const unsigned short* __restrict__ x16, const unsigned short* __restrict__ lwb,
    const float* __restrict__ lb, float* __restrict__ loc) {
  __shared__ __align__(16) unsigned short im[16 * LCP];
  int bid = blockIdx.x;
  int b = bid / 196, rem = bid % 196;
  int th = rem / 7, tw = rem % 7;
  int h0 = th * 2, w0 = tw * 8;
  size_t bN = (size_t)b * Nv;
  int t = threadIdx.x;
  for (int p = t; p < 1152; p += 256) {
    int sub = p & 7, s = p >> 3;
    int tok = s / 9, tap = s % 9;
    int tr = tok >> 3, tc = tok & 7;
    int dh = tap / 3, dw = tap % 3;
    int gh = h0 + tr - 1 + dh, gw = w0 + tc - 1 + dw;
    bf16x8 v = {};
    if (gh >= 0 && gh < Hh && gw >= 0 && gw < Ww)
      v = *(const bf16x8*)&x16[(bN + gh * Ww + gw) * 64 + sub * 8];
    *(bf16x8*)&im[tok * LCP + tap * 64 + sub * 8] = v;
  }
  __syncthreads();
  int wv = t >> 6, lane = t & 63;
  int n16 = lane & 15, quad = lane >> 4;
  const unsigned short* wrow = &lwb[(size_t)(wv * 16 + n16) * 576];
  f32x4 acc = {0.f, 0.f, 0.f, 0.f};
#pragma unroll 6
  for (int kk = 0; kk < 18; ++kk) {
    bf16x8 af = *(const bf16x8*)&im[n16 * LCP + kk * 32 + quad * 8];
    bf16x8 bfr = *(const bf16x8*)&wrow[kk * 32 + quad * 8];
    acc = __builtin_amdgcn_mfma_f32_16x16x32_bf16(af, bfr, acc, 0, 0, 0);
  }
  float bias = lb[wv * 16 + n16];
#pragma unroll
  for (int r = 0; r < 4; ++r) {
    int tok = quad * 4 + r;
    int trr = tok >> 3, tcc = tok & 7;
    size_t idx = (bN + (size_t)(h0 + trr) * Ww + w0 + tcc) * 64 + wv * 16 + n16;
    loc[idx] = acc[r] + bias;
  }
}

// ---------------- K3b: proj + add loc + LN1 + residual + LN2 ----------------
__global__ void k_proj_res(const float* __restrict__ x, const float* __restrict__ gin,
                           const float* __restrict__ loc,
                           const float* __restrict__ wproj, const float* __restrict__ bproj,
                           const float* __restrict__ g1, const float* __restrict__ b1,
                           const float* __restrict__ g2, const float* __restrict__ b2,
                           float* __restrict__ x2, unsigned short* __restrict__ xn2b) {
  __shared__ float gs[4][64];
  int tok = threadIdx.x >> 6, c = threadIdx.x & 63;
  int nt = blockIdx.x * 4 + tok;
  gs[tok][c] = gin[(size_t)nt * 64 + c];
  __syncthreads();
  float acc = bproj[c];
#pragma unroll 8
  for (int j = 0; j < 64; ++j) acc += gs[tok][j] * wproj[j * 64 + c];
  float y = acc + loc[(size_t)nt * 64 + c];
  float m = wave_sum(y) * (1.0f / 64.0f);
  float d = y - m;
  float var = wave_sum(d * d) * (1.0f / 64.0f);
  float t1 = d * rsqrtf(var + EPS) * g1[c] + b1[c];
  float x2v = x[(size_t)nt * 64 + c] + t1;
  float m2 = wave_sum(x2v) * (1.0f / 64.0f);
  float d2 = x2v - m2;
  float v2 = wave_sum(d2 * d2) * (1.0f / 64.0f);
  float xn2v = d2 * rsqrtf(v2 + EPS) * g2[c] + b2[c];
  x2[(size_t)nt * 64 + c] = x2v;
  xn2b[(size_t)nt * 64 + c] = f2bf(xn2v);
}

// ---------------- K5: MSFN — depthwise in regs, 1x1 via MFMA ----------------
__global__ __launch_bounds__(256) void k_msfn(
    const unsigned short* __restrict__ xn2b, const float* __restrict__ x2,
    const float* __restrict__ w3t, const float* __restrict__ b3,
    const float* __restrict__ w5t, const float* __restrict__ b5,
    const unsigned short* __restrict__ w1bf, const float* __restrict__ b1,
    float* __restrict__ out) {
  __shared__ __align__(16) unsigned short xtS[6 * 12 * 64];
  __shared__ __align__(16) unsigned short tsS[16 * TSP];

  int bid = blockIdx.x;
  int b = bid / 196;
  int rem = bid % 196;
  int th = rem / 7, tw = rem % 7;
  int h0 = th * 2, w0 = tw * 8;
  size_t bN = (size_t)b * Nv;
  int t = threadIdx.x;

  unsigned int* xtU = (unsigned int*)xtS;
  for (int p = t; p < 6 * 12 * 32; p += 256) {
    int cp = p & 31, rc = p >> 5;
    int r = rc / 12, cc = rc % 12;
    int gh = h0 - 2 + r, gw = w0 - 2 + cc;
    unsigned int v = 0;
    if (gh >= 0 && gh < Hh && gw >= 0 && gw < Ww)
      v = *(const unsigned int*)&xn2b[(bN + gh * Ww + gw) * 64 + cp * 2];
    xtU[rc * 32 + cp] = v;
  }
  __syncthreads();

  int cin = t & 63, tg = t >> 6;
  int tr = tg >> 1, tc0 = (tg & 1) * 4;
  float win[5][8];
#pragma unroll
  for (int r = 0; r < 5; ++r)
#pragma unroll
    for (int c = 0; c < 8; ++c)
      win[r][c] = bf2f(xtS[((tr + r) * 12 + tc0 + c) * 64 + cin]);

  unsigned int* tsU = (unsigned int*)tsS;
#pragma unroll 1
  for (int m2 = 0; m2 < 4; m2 += 2) {
    float a3[2][9], a5[2][25], bb3[2], bb5[2];
#pragma unroll
    for (int mm = 0; mm < 2; ++mm) {
      int m = m2 + mm;
#pragma unroll
      for (int tap = 0; tap < 9; ++tap) a3[mm][tap] = w3t[(tap * 4 + m) * 64 + cin];
#pragma unroll
      for (int tap = 0; tap < 25; ++tap) a5[mm][tap] = w5t[(tap * 4 + m) * 64 + cin];
      bb3[mm] = b3[cin * 4 + m];
      bb5[mm] = b5[cin * 4 + m];
    }
#pragma unroll
    for (int tk = 0; tk < 4; ++tk) {
      int tok = tg * 4 + tk;
      unsigned int p3 = 0, p5 = 0;
#pragma unroll
      for (int mm = 0; mm < 2; ++mm) {
        float acc3 = bb3[mm];
#pragma unroll
        for (int kh = 0; kh < 3; ++kh)
#pragma unroll
          for (int kw2 = 0; kw2 < 3; ++kw2)
            acc3 += win[1 + kh][tk + 1 + kw2] * a3[mm][kh * 3 + kw2];
        float acc5 = bb5[mm];
#pragma unroll
        for (int kh = 0; kh < 5; ++kh)
#pragma unroll
          for (int kw2 = 0; kw2 < 5; ++kw2)
            acc5 += win[kh][tk + kw2] * a5[mm][kh * 5 + kw2];
        p3 |= (unsigned int)f2bf(acc3) << (16 * mm);
        p5 |= (unsigned int)f2bf(acc5) << (16 * mm);
      }
      tsU[(tok * TSP + cin * 4 + m2) >> 1] = p3;
      tsU[(tok * TSP + 256 + cin * 4 + m2) >> 1] = p5;
    }
  }
  __syncthreads();

  int wv = tg, lane = t & 63;
  int n16 = lane & 15, quad = lane >> 4;
  const unsigned short* wrow = &w1bf[(size_t)(wv * 16 + n16) * 512];
  f32x4 acc = {0.f, 0.f, 0.f, 0.f};
#pragma unroll 4
  for (int kk = 0; kk < 16; ++kk) {
    bf16x8 af = *(const bf16x8*)&tsS[n16 * TSP + kk * 32 + quad * 8];
    bf16x8 bfr = *(const bf16x8*)&wrow[kk * 32 + quad * 8];
    acc = __builtin_amdgcn_mfma_f32_16x16x32_bf16(af, bfr, acc, 0, 0, 0);
  }
  float bias = b1[wv * 16 + n16];
#pragma unroll
  for (int r = 0; r < 4; ++r) {
    int tok = quad * 4 + r;
    int trr = tok >> 3, tcc = tok & 7;
    size_t idx = (bN + (size_t)(h0 + trr) * Ww + w0 + tcc) * 64 + wv * 16 + n16;
    out[idx] = x2[idx] + acc[r] + bias;
  }
}

extern "C" void kernel_launch(void* const* d_in, const int* in_sizes, int n_in,
                              void* d_out, int out_size, void* d_ws, size_t ws_size,
                              hipStream_t stream) {
  const float* x = (const float*)d_in[0];
  const float* n1g = (const float*)d_in[1];
  const float* n1b = (const float*)d_in[2];
  const float* wq = (const float*)d_in[3];
  const float* bq = (const float*)d_in[4];
  const float* wkv = (const float*)d_in[5];
  const float* bkv = (const float*)d_in[6];
  const float* wproj = (const float*)d_in[7];
  const float* bproj = (const float*)d_in[8];
  const float* lw = (const float*)d_in[9];
  const float* lb = (const float*)d_in[10];
  const float* n2g = (const float*)d_in[11];
  const float* n2b = (const float*)d_in[12];
  const float* w3 = (const float*)d_in[13];
  const float* b3 = (const float*)d_in[14];
  const float* w5 = (const float*)d_in[15];
  const float* b5 = (const float*)d_in[16];
  const float* w1 = (const float*)d_in[17];
  const float* b1 = (const float*)d_in[18];
  float* out = (float*)d_out;

  float* ws = (float*)d_ws;
  const size_t TOK = (size_t)Bv * Nv * Cv;  // 802816
  float* vb = ws;
  float* gb = vb + TOK;
  float* sumv = gb + TOK;            // 256
  float* loc = sumv + 256;
  float* x2 = loc + TOK;
  float* w3t = x2 + TOK;             // 2304
  float* w5t = w3t + 2304;           // 6400
  unsigned short* q16 = (unsigned short*)(w5t + 6400);
  unsigned short* k16 = q16 + TOK;
  unsigned short* xn2b = k16 + TOK;
  unsigned short* x16 = xn2b + TOK;
  unsigned short* w1bf = x16 + TOK;       // 64*512
  unsigned short* lwb = w1bf + 64 * 512;  // 64*576
  unsigned int* top8ws = (unsigned int*)(lwb + 64 * 576);  // 12544*16 uints

  k_transpose<<<144, 256, 0, stream>>>(w1, lw, w3, w5, w1bf, lwb, w3t, w5t);
  k_ln_qkv<<<Bv * Nv / 4, 256, 0, stream>>>(x, n1g, n1b, wq, bq, wkv, bkv, q16, k16, vb, x16);
  hipMemsetAsync(sumv, 0, 256 * sizeof(float), stream);
  k_sumv<<<Bv * 49, 256, 0, stream>>>(vb, sumv);
  k_attn_topk<<<Bv * 196 * 2, 256, 0, stream>>>(q16, k16, top8ws);
  k_locconv<<<Bv * 196, 256, 0, stream>>>(x16, lwb, lb, loc);
  k_attn_out<<<Bv * 196, 256, 0, stream>>>(top8ws, vb, sumv, gb);
  k_proj_res<<<Bv * Nv / 4, 256, 0, stream>>>(x, gb, loc, wproj, bproj, n1g, n1b, n2g, n2b, x2, xn2b);
  k_msfn<<<Bv * 196, 256, 0, stream>>>(xn2b, x2, w3t, b3, w5t, b5, w1bf, b1, out);
}

// Round 6
// 197.369 us; speedup vs baseline: 4.4792x; 1.0987x over previous
//
#include <hip/hip_runtime.h>
#include <math.h>

#define Bv 4
#define Nv 3136
#define Cv 64
#define Hh 56
#define Ww 56
#define HIDv 256
#define TOPKv 8
#define TSP 520   // msfn ts row pitch (bf16): dword pitch % 32 == 4 -> conflict-free b128
#define LCP 584   // locconv im2col row pitch (576+8): same property
#define XNP 72    // ln/proj LDS bf16 row pitch (64+8): <=2-way banks

constexpr float SCALE = 0.125f;   // d^-0.5, d=64
constexpr float EPS = 1e-5f;

typedef short bf16x8 __attribute__((ext_vector_type(8)));
typedef float f32x4 __attribute__((ext_vector_type(4)));

#define CSWAP(a, b) { unsigned int _hi = max(a, b); unsigned int _lo = min(a, b); a = _hi; b = _lo; }
// descending bitonic clean of 8 (input: bitonic), 3 stages
#define BITONIC8(T) \
  CSWAP(T[0], T[4]); CSWAP(T[1], T[5]); CSWAP(T[2], T[6]); CSWAP(T[3], T[7]); \
  CSWAP(T[0], T[2]); CSWAP(T[1], T[3]); CSWAP(T[4], T[6]); CSWAP(T[5], T[7]); \
  CSWAP(T[0], T[1]); CSWAP(T[2], T[3]); CSWAP(T[4], T[5]); CSWAP(T[6], T[7]);

__device__ __forceinline__ unsigned short f2bf(float f) {
  unsigned int u = __float_as_uint(f);
  u = (u + 0x7FFFu + ((u >> 16) & 1u)) >> 16;
  return (unsigned short)u;
}
__device__ __forceinline__ float bf2f(unsigned short u) {
  return __uint_as_float(((unsigned int)u) << 16);
}
__device__ __forceinline__ unsigned int pack2(float a, float b) {
  return (unsigned int)f2bf(a) | ((unsigned int)f2bf(b) << 16);
}

// monotone float->uint map, low 12 bits replaced by index
__device__ __forceinline__ unsigned int packScore(float s, int j) {
  unsigned int b = __float_as_uint(s);
  unsigned int m = b ^ ((b & 0x80000000u) ? 0xFFFFFFFFu : 0x80000000u);
  return (m & 0xFFFFF000u) | (unsigned int)j;
}
__device__ __forceinline__ float unpackScore(unsigned int p) {
  unsigned int m = p & 0xFFFFF000u;
  unsigned int b = (m & 0x80000000u) ? (m ^ 0x80000000u) : ~m;
  return __uint_as_float(b);
}

// ---------------- K0: weight prep -------------------------------------------
// w1bf    : bf16 of w1 ([cout][512] already B-frag layout)
// lwb     : bf16 im2col of local_w (tap-major K): [co][tap*64+ci]
// w3t/w5t : depthwise weights transposed for coalesced reads
// wqkvt   : bf16 [192][64]; rows 0..63 wq^T, 64..191 wkv^T
// qkvb    : fp32 [192] = concat(bq, bkv)
// wprojt  : bf16 [64][64] = wproj^T
__global__ void k_transpose(const float* __restrict__ w1, const float* __restrict__ lw,
                            const float* __restrict__ w3, const float* __restrict__ w5,
                            const float* __restrict__ wq, const float* __restrict__ wkv,
                            const float* __restrict__ bq, const float* __restrict__ bkv,
                            const float* __restrict__ wproj,
                            unsigned short* __restrict__ w1bf, unsigned short* __restrict__ lwb,
                            float* __restrict__ w3t, float* __restrict__ w5t,
                            unsigned short* __restrict__ wqkvt, float* __restrict__ qkvb,
                            unsigned short* __restrict__ wprojt) {
  int p = blockIdx.x * 256 + threadIdx.x;
  if (p < 64 * 512) w1bf[p] = f2bf(w1[p]);
  if (p < 64 * 576) {
    int co = p / 576, k = p % 576;
    int tap = k >> 6, ci = k & 63;
    lwb[p] = f2bf(lw[co * 576 + ci * 9 + tap]);
  }
  if (p < 36 * 64) {
    int cin = p & 63, tm = p >> 6;
    int tap = tm >> 2, m = tm & 3;
    w3t[p] = w3[(cin * 4 + m) * 9 + tap];
  }
  if (p < 100 * 64) {
    int cin = p & 63, tm = p >> 6;
    int tap = tm >> 2, m = tm & 3;
    w5t[p] = w5[(cin * 4 + m) * 25 + tap];
  }
  if (p < 192 * 64) {
    int o = p >> 6, i = p & 63;
    float v = (o < 64) ? wq[i * 64 + o] : wkv[i * 128 + (o - 64)];
    wqkvt[p] = f2bf(v);
  }
  if (p < 192) qkvb[p] = (p < 64) ? bq[p] : bkv[p - 64];
  if (p < 64 * 64) {
    int o = p >> 6, i = p & 63;
    wprojt[p] = f2bf(wproj[i * 64 + o]);
  }
}

// ---------------- K1: LN1 + QKV projection via MFMA (64 tokens/block) -------
__global__ __launch_bounds__(256) void k_ln_qkv(
    const float* __restrict__ x, const float* __restrict__ g1, const float* __restrict__ b1,
    const unsigned short* __restrict__ wqkvt, const float* __restrict__ qkvb,
    unsigned short* __restrict__ q16, unsigned short* __restrict__ k16,
    float* __restrict__ vo, unsigned short* __restrict__ x16) {
  __shared__ __align__(16) unsigned short xnS[64 * XNP];
  int t = threadIdx.x;
  int w = t >> 6, l = t & 63;
  int n = l & 15, q = l >> 4;
  int tokL = w * 16 + n;
  size_t tok = (size_t)blockIdx.x * 64 + tokL;
  int ch0 = q * 16;
  float v[16];
  const float* xp = &x[tok * 64 + ch0];
#pragma unroll
  for (int i = 0; i < 4; ++i) *(float4*)&v[i * 4] = *(const float4*)&xp[i * 4];
  {
    unsigned int pk[8];
#pragma unroll
    for (int i = 0; i < 8; ++i) pk[i] = pack2(v[2 * i], v[2 * i + 1]);
    *(uint4*)&x16[tok * 64 + ch0] = *(uint4*)&pk[0];
    *(uint4*)&x16[tok * 64 + ch0 + 8] = *(uint4*)&pk[4];
  }
  float s = 0.f, s2 = 0.f;
#pragma unroll
  for (int i = 0; i < 16; ++i) { s += v[i]; s2 += v[i] * v[i]; }
  s += __shfl_xor(s, 16, 64); s += __shfl_xor(s, 32, 64);
  s2 += __shfl_xor(s2, 16, 64); s2 += __shfl_xor(s2, 32, 64);
  float m = s * (1.f / 64.f);
  float var = s2 * (1.f / 64.f) - m * m;
  float rs = rsqrtf(var + EPS);
  {
    unsigned int* xnU = (unsigned int*)xnS;
    unsigned int pk[8];
#pragma unroll
    for (int i = 0; i < 8; ++i) {
      float a = (v[2 * i] - m) * rs * g1[ch0 + 2 * i] + b1[ch0 + 2 * i];
      float b_ = (v[2 * i + 1] - m) * rs * g1[ch0 + 2 * i + 1] + b1[ch0 + 2 * i + 1];
      pk[i] = pack2(a, b_);
    }
#pragma unroll
    for (int i = 0; i < 8; ++i) xnU[(tokL * XNP + ch0) / 2 + i] = pk[i];
  }
  __syncthreads();

  const bf16x8 a0 = *(const bf16x8*)&xnS[(w * 16 + n) * XNP + q * 8];
  const bf16x8 a1 = *(const bf16x8*)&xnS[(w * 16 + n) * XNP + 32 + q * 8];
  size_t tbase = (size_t)blockIdx.x * 64 + w * 16;
  // Q tiles (outs 0..63)
#pragma unroll
  for (int j = 0; j < 4; ++j) {
    const unsigned short* wr = &wqkvt[(size_t)(j * 16 + n) * 64];
    bf16x8 b0 = *(const bf16x8*)&wr[q * 8];
    bf16x8 b1_ = *(const bf16x8*)&wr[32 + q * 8];
    f32x4 acc = {0.f, 0.f, 0.f, 0.f};
    acc = __builtin_amdgcn_mfma_f32_16x16x32_bf16(a0, b0, acc, 0, 0, 0);
    acc = __builtin_amdgcn_mfma_f32_16x16x32_bf16(a1, b1_, acc, 0, 0, 0);
    float bias = qkvb[j * 16 + n];
#pragma unroll
    for (int r = 0; r < 4; ++r)
      q16[(tbase + q * 4 + r) * 64 + j * 16 + n] = f2bf(acc[r] + bias);
  }
  // K tiles (outs 64..127)
#pragma unroll
  for (int j = 0; j < 4; ++j) {
    const unsigned short* wr = &wqkvt[(size_t)((j + 4) * 16 + n) * 64];
    bf16x8 b0 = *(const bf16x8*)&wr[q * 8];
    bf16x8 b1_ = *(const bf16x8*)&wr[32 + q * 8];
    f32x4 acc = {0.f, 0.f, 0.f, 0.f};
    acc = __builtin_amdgcn_mfma_f32_16x16x32_bf16(a0, b0, acc, 0, 0, 0);
    acc = __builtin_amdgcn_mfma_f32_16x16x32_bf16(a1, b1_, acc, 0, 0, 0);
    float bias = qkvb[64 + j * 16 + n];
#pragma unroll
    for (int r = 0; r < 4; ++r)
      k16[(tbase + q * 4 + r) * 64 + j * 16 + n] = f2bf(acc[r] + bias);
  }
  // V tiles (outs 128..191)
#pragma unroll
  for (int j = 0; j < 4; ++j) {
    const unsigned short* wr = &wqkvt[(size_t)((j + 8) * 16 + n) * 64];
    bf16x8 b0 = *(const bf16x8*)&wr[q * 8];
    bf16x8 b1_ = *(const bf16x8*)&wr[32 + q * 8];
    f32x4 acc = {0.f, 0.f, 0.f, 0.f};
    acc = __builtin_amdgcn_mfma_f32_16x16x32_bf16(a0, b0, acc, 0, 0, 0);
    acc = __builtin_amdgcn_mfma_f32_16x16x32_bf16(a1, b1_, acc, 0, 0, 0);
    float bias = qkvb[128 + j * 16 + n];
#pragma unroll
    for (int r = 0; r < 4; ++r)
      vo[(tbase + q * 4 + r) * 64 + j * 16 + n] = acc[r] + bias;
  }
}

// ---------------- K1b: sum of V rows per batch ------------------------------
__global__ void k_sumv(const float* __restrict__ v, float* __restrict__ sumv) {
  __shared__ float part[4][64];
  int b = blockIdx.x / 49, slice = blockIdx.x % 49;
  int w = threadIdx.x >> 6, c = threadIdx.x & 63;
  float acc = 0.0f;
  int base = b * Nv + slice * 64 + w * 16;
#pragma unroll
  for (int n = 0; n < 16; ++n) acc += v[(size_t)(base + n) * 64 + c];
  part[w][c] = acc;
  __syncthreads();
  if (threadIdx.x < 64) {
    float s = part[0][c] + part[1][c] + part[2][c] + part[3][c];
    atomicAdd(&sumv[b * 64 + c], s);
  }
}

// ---------------- K2a: MFMA QK^T + per-row top-8 over a key half ------------
__global__ __launch_bounds__(256) void k_attn_topk(
    const unsigned short* __restrict__ q16, const unsigned short* __restrict__ k16,
    unsigned int* __restrict__ top8out) {
  __shared__ unsigned int candLDS[16][4][9];  // pad 9: avoid 16-way write conflict
  int bid = blockIdx.x;
  int half = bid & 1;
  int lin = bid >> 1;
  int b = lin / 196, tile = lin % 196;
  int qbase = b * Nv + tile * 16;
  size_t bN = (size_t)b * Nv;
  int t = threadIdx.x;
  int w = t >> 6, lane = t & 63;
  int qcol = lane & 15, quad = lane >> 4;

  const bf16x8 qf0 = *(const bf16x8*)&q16[((size_t)(qbase + qcol)) * 64 + quad * 8];
  const bf16x8 qf1 = *(const bf16x8*)&q16[((size_t)(qbase + qcol)) * 64 + 32 + quad * 8];

  unsigned int t8[8];
  unsigned int PACKNEG = packScore(-1e30f, 0);
#pragma unroll
  for (int u = 0; u < 8; ++u) t8[u] = PACKNEG;
  float thrRaw = -3.0e38f;

  int chBeg = half ? 24 : 0;
  int chEnd = half ? 49 : 24;
  int keyRow = w * 16 + qcol;
  bf16x8 kf0 = *(const bf16x8*)&k16[(bN + chBeg * 64 + keyRow) * 64 + quad * 8];
  bf16x8 kf1 = *(const bf16x8*)&k16[(bN + chBeg * 64 + keyRow) * 64 + 32 + quad * 8];

  for (int ch = chBeg; ch < chEnd; ++ch) {
    bf16x8 c0 = kf0, c1 = kf1;
    if (ch + 1 < chEnd) {
      kf0 = *(const bf16x8*)&k16[(bN + (ch + 1) * 64 + keyRow) * 64 + quad * 8];
      kf1 = *(const bf16x8*)&k16[(bN + (ch + 1) * 64 + keyRow) * 64 + 32 + quad * 8];
    }
    f32x4 acc = {0.f, 0.f, 0.f, 0.f};
    acc = __builtin_amdgcn_mfma_f32_16x16x32_bf16(c0, qf0, acc, 0, 0, 0);
    acc = __builtin_amdgcn_mfma_f32_16x16x32_bf16(c1, qf1, acc, 0, 0, 0);
    float m01 = fmaxf(acc[0], acc[1]);
    float m23 = fmaxf(acc[2], acc[3]);
    if (fmaxf(m01, m23) > thrRaw) {
      int jb = ch * 64 + w * 16 + quad * 4;
      unsigned int p0 = packScore(acc[0] * SCALE, jb + 0);
      unsigned int p1 = packScore(acc[1] * SCALE, jb + 1);
      unsigned int p2 = packScore(acc[2] * SCALE, jb + 2);
      unsigned int p3 = packScore(acc[3] * SCALE, jb + 3);
      CSWAP(p0, p1); CSWAP(p2, p3); CSWAP(p0, p2); CSWAP(p1, p3); CSWAP(p1, p2);
      t8[4] = max(t8[4], p3);
      t8[5] = max(t8[5], p2);
      t8[6] = max(t8[6], p1);
      t8[7] = max(t8[7], p0);
      BITONIC8(t8);
      thrRaw = unpackScore(t8[7]) * 8.0f;
    }
  }

#pragma unroll
  for (int step = 16; step <= 32; step <<= 1) {
    unsigned int o[8];
#pragma unroll
    for (int i = 0; i < 8; ++i) o[i] = (unsigned int)__shfl_xor((int)t8[i], step, 64);
    unsigned int nw[8];
#pragma unroll
    for (int i = 0; i < 8; ++i) nw[i] = max(t8[i], o[7 - i]);
#pragma unroll
    for (int i = 0; i < 8; ++i) t8[i] = nw[i];
    BITONIC8(t8);
  }
  if (quad == 0) {
#pragma unroll
    for (int i = 0; i < 8; ++i) candLDS[qcol][w][i] = t8[i];
  }
  __syncthreads();

  if (t < 16) {
    int r = t;
    int p0 = 0, p1 = 0, p2 = 0, p3 = 0;
    size_t obase = ((size_t)(bN + tile * 16 + r)) * 16 + half * 8;
#pragma unroll
    for (int u = 0; u < 8; ++u) {
      unsigned int c0 = (p0 < 8) ? candLDS[r][0][p0] : 0u;
      unsigned int c1 = (p1 < 8) ? candLDS[r][1][p1] : 0u;
      unsigned int c2 = (p2 < 8) ? candLDS[r][2][p2] : 0u;
      unsigned int c3 = (p3 < 8) ? candLDS[r][3][p3] : 0u;
      unsigned int best = c0;
      int bw = 0;
      if (c1 > best) { best = c1; bw = 1; }
      if (c2 > best) { best = c2; bw = 2; }
      if (c3 > best) { best = c3; bw = 3; }
      p0 += (bw == 0); p1 += (bw == 1); p2 += (bw == 2); p3 += (bw == 3);
      top8out[obase + u] = best;
    }
  }
}

// ---------------- K2b: merge halves + corrected softmax*V -------------------
__global__ __launch_bounds__(256) void k_attn_out(
    const unsigned int* __restrict__ top8, const float* __restrict__ vg,
    const float* __restrict__ sumv, float* __restrict__ gout) {
  __shared__ float kwS[16][8];
  __shared__ int kidxS[16][8];
  __shared__ float invZS[16];
  int b = blockIdx.x / 196, tile = blockIdx.x % 196;
  int qbase = b * Nv + tile * 16;
  size_t bN = (size_t)b * Nv;
  int t = threadIdx.x;
  if (t < 16) {
    size_t base = (size_t)(qbase + t) * 16;
    unsigned int A[8], Bb[8];
#pragma unroll
    for (int i = 0; i < 8; ++i) A[i] = top8[base + i];
#pragma unroll
    for (int i = 0; i < 8; ++i) Bb[i] = top8[base + 8 + i];
#pragma unroll
    for (int i = 0; i < 8; ++i) A[i] = max(A[i], Bb[7 - i]);
    BITONIC8(A);
    float Z = (float)(Nv - TOPKv);
#pragma unroll
    for (int u = 0; u < 8; ++u) {
      float s = unpackScore(A[u]);
      float e = __expf(s);
      kwS[t][u] = e - 1.0f;
      kidxS[t][u] = (int)(A[u] & 0xFFFu);
      Z += e;
    }
    invZS[t] = 1.0f / Z;
  }
  __syncthreads();
  int c = t & 63, rg = t >> 6;
#pragma unroll 1
  for (int rr = 0; rr < 4; ++rr) {
    int r = rg * 4 + rr;
    float acc = sumv[b * 64 + c];
#pragma unroll
    for (int u = 0; u < 8; ++u)
      acc += kwS[r][u] * vg[(bN + kidxS[r][u]) * 64 + c];
    gout[(size_t)(qbase + r) * 64 + c] = acc * invZS[r];
  }
}

// ---------------- K3a: local 3x3 full conv (64->64) via im2col + MFMA -------
__global__ __launch_bounds__(256) void k_locconv(
    const unsigned short* __restrict__ x16, const unsigned short* __restrict__ lwb,
    const float* __restrict__ lb, float* __restrict__ loc) {
  __shared__ __align__(16) unsigned short im[16 * LCP];
  int bid = blockIdx.x;
  int b = bid / 196, rem = bid % 196;
  int th = rem / 7, tw = rem % 7;
  int h0 = th * 2, w0 = tw * 8;
  size_t bN = (size_t)b * Nv;
  int t = threadIdx.x;
  for (int p = t; p < 1152; p += 256) {
    int sub = p & 7, s = p >> 3;
    int tok = s / 9, tap = s % 9;
    int tr = tok >> 3, tc = tok & 7;
    int dh = tap / 3, dw = tap % 3;
    int gh = h0 + tr - 1 + dh, gw = w0 + tc - 1 + dw;
    bf16x8 v = {};
    if (gh >= 0 && gh < Hh && gw >= 0 && gw < Ww)
      v = *(const bf16x8*)&x16[(bN + gh * Ww + gw) * 64 + sub * 8];
    *(bf16x8*)&im[tok * LCP + tap * 64 + sub * 8] = v;
  }
  __syncthreads();
  int wv = t >> 6, lane = t & 63;
  int n16 = lane & 15, quad = lane >> 4;
  const unsigned short* wrow = &lwb[(size_t)(wv * 16 + n16) * 576];
  f32x4 acc = {0.f, 0.f, 0.f, 0.f};
#pragma unroll 6
  for (int kk = 0; kk < 18; ++kk) {
    bf16x8 af = *(const bf16x8*)&im[n16 * LCP + kk * 32 + quad * 8];
    bf16x8 bfr = *(const bf16x8*)&wrow[kk * 32 + quad * 8];
    acc = __builtin_amdgcn_mfma_f32_16x16x32_bf16(af, bfr, acc, 0, 0, 0);
  }
  float bias = lb[wv * 16 + n16];
#pragma unroll
  for (int r = 0; r < 4; ++r) {
    int tok = quad * 4 + r;
    int trr = tok >> 3, tcc = tok & 7;
    size_t idx = (bN + (size_t)(h0 + trr) * Ww + w0 + tcc) * 64 + wv * 16 + n16;
    loc[idx] = acc[r] + bias;
  }
}

// ---------------- K3b: proj (MFMA) + loc + LN1 + residual + LN2 -------------
__global__ __launch_bounds__(256) void k_proj_res(
    const float* __restrict__ x, const float* __restrict__ gin,
    const float* __restrict__ loc,
    const unsigned short* __restrict__ wprojt, const float* __restrict__ bproj,
    const float* __restrict__ g1, const float* __restrict__ b1,
    const float* __restrict__ g2, const float* __restrict__ b2,
    float* __restrict__ x2, unsigned short* __restrict__ xn2b) {
  __shared__ __align__(16) unsigned short gS[64 * XNP];
  __shared__ float yS[64 * 66];
  int t = threadIdx.x;
  int w = t >> 6, l = t & 63;
  int n = l & 15, q = l >> 4;
  int tokL = w * 16 + n;
  size_t tok = (size_t)blockIdx.x * 64 + tokL;
  int ch0 = q * 16;
  // stage g -> LDS bf16
  {
    float gv[16];
    const float* gp = &gin[tok * 64 + ch0];
#pragma unroll
    for (int i = 0; i < 4; ++i) *(float4*)&gv[i * 4] = *(const float4*)&gp[i * 4];
    unsigned int* gU = (unsigned int*)gS;
#pragma unroll
    for (int i = 0; i < 8; ++i)
      gU[(tokL * XNP + ch0) / 2 + i] = pack2(gv[2 * i], gv[2 * i + 1]);
  }
  __syncthreads();
  // proj GEMM
  {
    const bf16x8 a0 = *(const bf16x8*)&gS[(w * 16 + n) * XNP + q * 8];
    const bf16x8 a1 = *(const bf16x8*)&gS[(w * 16 + n) * XNP + 32 + q * 8];
    size_t tbase = (size_t)blockIdx.x * 64 + w * 16;
#pragma unroll
    for (int j = 0; j < 4; ++j) {
      const unsigned short* wr = &wprojt[(size_t)(j * 16 + n) * 64];
      bf16x8 b0 = *(const bf16x8*)&wr[q * 8];
      bf16x8 b1_ = *(const bf16x8*)&wr[32 + q * 8];
      f32x4 acc = {0.f, 0.f, 0.f, 0.f};
      acc = __builtin_amdgcn_mfma_f32_16x16x32_bf16(a0, b0, acc, 0, 0, 0);
      acc = __builtin_amdgcn_mfma_f32_16x16x32_bf16(a1, b1_, acc, 0, 0, 0);
      float bias = bproj[j * 16 + n];
#pragma unroll
      for (int r = 0; r < 4; ++r) {
        size_t idx = (tbase + q * 4 + r) * 64 + j * 16 + n;
        yS[(w * 16 + q * 4 + r) * 66 + j * 16 + n] = acc[r] + bias + loc[idx];
      }
    }
  }
  __syncthreads();
  // LN1 -> residual -> LN2 (lane-per-token, quad channel split)
  float y[16];
#pragma unroll
  for (int i = 0; i < 4; ++i) *(float4*)&y[i * 4] = *(const float4*)&yS[tokL * 66 + ch0 + i * 4];
  float s = 0.f, s2 = 0.f;
#pragma unroll
  for (int i = 0; i < 16; ++i) { s += y[i]; s2 += y[i] * y[i]; }
  s += __shfl_xor(s, 16, 64); s += __shfl_xor(s, 32, 64);
  s2 += __shfl_xor(s2, 16, 64); s2 += __shfl_xor(s2, 32, 64);
  float m1 = s * (1.f / 64.f);
  float rs1 = rsqrtf(s2 * (1.f / 64.f) - m1 * m1 + EPS);
  float xv[16];
  const float* xp = &x[tok * 64 + ch0];
#pragma unroll
  for (int i = 0; i < 4; ++i) *(float4*)&xv[i * 4] = *(const float4*)&xp[i * 4];
  float x2v[16];
  float t_s = 0.f, t_s2 = 0.f;
#pragma unroll
  for (int i = 0; i < 16; ++i) {
    float t1 = (y[i] - m1) * rs1 * g1[ch0 + i] + b1[ch0 + i];
    x2v[i] = xv[i] + t1;
    t_s += x2v[i]; t_s2 += x2v[i] * x2v[i];
  }
  t_s += __shfl_xor(t_s, 16, 64); t_s += __shfl_xor(t_s, 32, 64);
  t_s2 += __shfl_xor(t_s2, 16, 64); t_s2 += __shfl_xor(t_s2, 32, 64);
  float m2 = t_s * (1.f / 64.f);
  float rs2 = rsqrtf(t_s2 * (1.f / 64.f) - m2 * m2 + EPS);
  float* x2p = &x2[tok * 64 + ch0];
#pragma unroll
  for (int i = 0; i < 4; ++i) *(float4*)&x2p[i * 4] = *(const float4*)&x2v[i * 4];
  unsigned int pk[8];
#pragma unroll
  for (int i = 0; i < 8; ++i) {
    float a = (x2v[2 * i] - m2) * rs2 * g2[ch0 + 2 * i] + b2[ch0 + 2 * i];
    float b_ = (x2v[2 * i + 1] - m2) * rs2 * g2[ch0 + 2 * i + 1] + b2[ch0 + 2 * i + 1];
    pk[i] = pack2(a, b_);
  }
  *(uint4*)&xn2b[tok * 64 + ch0] = *(uint4*)&pk[0];
  *(uint4*)&xn2b[tok * 64 + ch0 + 8] = *(uint4*)&pk[4];
}

// ---------------- K5: MSFN — depthwise in regs, 1x1 via MFMA ----------------
__global__ __launch_bounds__(256) void k_msfn(
    const unsigned short* __restrict__ xn2b, const float* __restrict__ x2,
    const float* __restrict__ w3t, const float* __restrict__ b3,
    const float* __restrict__ w5t, const float* __restrict__ b5,
    const unsigned short* __restrict__ w1bf, const float* __restrict__ b1,
    float* __restrict__ out) {
  __shared__ __align__(16) unsigned short xtS[6 * 12 * 64];
  __shared__ __align__(16) unsigned short tsS[16 * TSP];

  int bid = blockIdx.x;
  int b = bid / 196;
  int rem = bid % 196;
  int th = rem / 7, tw = rem % 7;
  int h0 = th * 2, w0 = tw * 8;
  size_t bN = (size_t)b * Nv;
  int t = threadIdx.x;

  unsigned int* xtU = (unsigned int*)xtS;
  for (int p = t; p < 6 * 12 * 32; p += 256) {
    int cp = p & 31, rc = p >> 5;
    int r = rc / 12, cc = rc % 12;
    int gh = h0 - 2 + r, gw = w0 - 2 + cc;
    unsigned int v = 0;
    if (gh >= 0 && gh < Hh && gw >= 0 && gw < Ww)
      v = *(const unsigned int*)&xn2b[(bN + gh * Ww + gw) * 64 + cp * 2];
    xtU[rc * 32 + cp] = v;
  }
  __syncthreads();

  int cin = t & 63, tg = t >> 6;
  int tr = tg >> 1, tc0 = (tg & 1) * 4;
  float win[5][8];
#pragma unroll
  for (int r = 0; r < 5; ++r)
#pragma unroll
    for (int c = 0; c < 8; ++c)
      win[r][c] = bf2f(xtS[((tr + r) * 12 + tc0 + c) * 64 + cin]);

  unsigned int* tsU = (unsigned int*)tsS;
#pragma unroll 1
  for (int m2 = 0; m2 < 4; m2 += 2) {
    float a3[2][9], a5[2][25], bb3[2], bb5[2];
#pragma unroll
    for (int mm = 0; mm < 2; ++mm) {
      int m = m2 + mm;
#pragma unroll
      for (int tap = 0; tap < 9; ++tap) a3[mm][tap] = w3t[(tap * 4 + m) * 64 + cin];
#pragma unroll
      for (int tap = 0; tap < 25; ++tap) a5[mm][tap] = w5t[(tap * 4 + m) * 64 + cin];
      bb3[mm] = b3[cin * 4 + m];
      bb5[mm] = b5[cin * 4 + m];
    }
#pragma unroll
    for (int tk = 0; tk < 4; ++tk) {
      int tok = tg * 4 + tk;
      unsigned int p3 = 0, p5 = 0;
#pragma unroll
      for (int mm = 0; mm < 2; ++mm) {
        float acc3 = bb3[mm];
#pragma unroll
        for (int kh = 0; kh < 3; ++kh)
#pragma unroll
          for (int kw2 = 0; kw2 < 3; ++kw2)
            acc3 += win[1 + kh][tk + 1 + kw2] * a3[mm][kh * 3 + kw2];
        float acc5 = bb5[mm];
#pragma unroll
        for (int kh = 0; kh < 5; ++kh)
#pragma unroll
          for (int kw2 = 0; kw2 < 5; ++kw2)
            acc5 += win[kh][tk + kw2] * a5[mm][kh * 5 + kw2];
        p3 |= (unsigned int)f2bf(acc3) << (16 * mm);
        p5 |= (unsigned int)f2bf(acc5) << (16 * mm);
      }
      tsU[(tok * TSP + cin * 4 + m2) >> 1] = p3;
      tsU[(tok * TSP + 256 + cin * 4 + m2) >> 1] = p5;
    }
  }
  __syncthreads();

  int wv = tg, lane = t & 63;
  int n16 = lane & 15, quad = lane >> 4;
  const unsigned short* wrow = &w1bf[(size_t)(wv * 16 + n16) * 512];
  f32x4 acc = {0.f, 0.f, 0.f, 0.f};
#pragma unroll 4
  for (int kk = 0; kk < 16; ++kk) {
    bf16x8 af = *(const bf16x8*)&tsS[n16 * TSP + kk * 32 + quad * 8];
    bf16x8 bfr = *(const bf16x8*)&wrow[kk * 32 + quad * 8];
    acc = __builtin_amdgcn_mfma_f32_16x16x32_bf16(af, bfr, acc, 0, 0, 0);
  }
  float bias = b1[wv * 16 + n16];
#pragma unroll
  for (int r = 0; r < 4; ++r) {
    int tok = quad * 4 + r;
    int trr = tok >> 3, tcc = tok & 7;
    size_t idx = (bN + (size_t)(h0 + trr) * Ww + w0 + tcc) * 64 + wv * 16 + n16;
    out[idx] = x2[idx] + acc[r] + bias;
  }
}

extern "C" void kernel_launch(void* const* d_in, const int* in_sizes, int n_in,
                              void* d_out, int out_size, void* d_ws, size_t ws_size,
                              hipStream_t stream) {
  const float* x = (const float*)d_in[0];
  const float* n1g = (const float*)d_in[1];
  const float* n1b = (const float*)d_in[2];
  const float* wq = (const float*)d_in[3];
  const float* bq = (const float*)d_in[4];
  const float* wkv = (const float*)d_in[5];
  const float* bkv = (const float*)d_in[6];
  const float* wproj = (const float*)d_in[7];
  const float* bproj = (const float*)d_in[8];
  const float* lw = (const float*)d_in[9];
  const float* lb = (const float*)d_in[10];
  const float* n2g = (const float*)d_in[11];
  const float* n2b = (const float*)d_in[12];
  const float* w3 = (const float*)d_in[13];
  const float* b3 = (const float*)d_in[14];
  const float* w5 = (const float*)d_in[15];
  const float* b5 = (const float*)d_in[16];
  const float* w1 = (const float*)d_in[17];
  const float* b1 = (const float*)d_in[18];
  float* out = (float*)d_out;

  float* ws = (float*)d_ws;
  const size_t TOK = (size_t)Bv * Nv * Cv;  // 802816
  float* vb = ws;
  float* gb = vb + TOK;
  float* sumv = gb + TOK;            // 256
  float* loc = sumv + 256;
  float* x2 = loc + TOK;
  float* w3t = x2 + TOK;             // 2304
  float* w5t = w3t + 2304;           // 6400
  float* qkvb = w5t + 6400;          // 192
  unsigned short* q16 = (unsigned short*)(qkvb + 192);
  unsigned short* k16 = q16 + TOK;
  unsigned short* xn2b = k16 + TOK;
  unsigned short* x16 = xn2b + TOK;
  unsigned short* w1bf = x16 + TOK;        // 64*512
  unsigned short* lwb = w1bf + 64 * 512;   // 64*576
  unsigned short* wqkvt = lwb + 64 * 576;  // 192*64
  unsigned short* wprojt = wqkvt + 192 * 64;  // 64*64
  unsigned int* top8ws = (unsigned int*)(wprojt + 64 * 64 + 64);  // 12544*16 uints

  k_transpose<<<144, 256, 0, stream>>>(w1, lw, w3, w5, wq, wkv, bq, bkv, wproj,
                                       w1bf, lwb, w3t, w5t, wqkvt, qkvb, wprojt);
  k_ln_qkv<<<Bv * Nv / 64, 256, 0, stream>>>(x, n1g, n1b, wqkvt, qkvb, q16, k16, vb, x16);
  hipMemsetAsync(sumv, 0, 256 * sizeof(float), stream);
  k_sumv<<<Bv * 49, 256, 0, stream>>>(vb, sumv);
  k_attn_topk<<<Bv * 196 * 2, 256, 0, stream>>>(q16, k16, top8ws);
  k_locconv<<<Bv * 196, 256, 0, stream>>>(x16, lwb, lb, loc);
  k_attn_out<<<Bv * 196, 256, 0, stream>>>(top8ws, vb, sumv, gb);
  k_proj_res<<<Bv * Nv / 64, 256, 0, stream>>>(x, gb, loc, wprojt, bproj, n1g, n1b, n2g, n2b, x2, xn2b);
  k_msfn<<<Bv * 196, 256, 0, stream>>>(xn2b, x2, w3t, b3, w5t, b5, w1bf, b1, out);
}

// Round 7
// 194.770 us; speedup vs baseline: 4.5390x; 1.0133x over previous
//
#include <hip/hip_runtime.h>
#include <math.h>

#define Bv 4
#define Nv 3136
#define Cv 64
#define Hh 56
#define Ww 56
#define HIDv 256
#define TOPKv 8
#define TSP 520   // msfn ts row pitch (bf16): dword pitch % 32 == 4 -> conflict-free b128
#define LCP 584   // locconv im2col row pitch (576+8): same property
#define XNP 72    // ln/proj LDS bf16 row pitch (64+8): dword pitch 36 % 32 == 4

constexpr float SCALE = 0.125f;   // d^-0.5, d=64
constexpr float EPS = 1e-5f;

typedef short bf16x8 __attribute__((ext_vector_type(8)));
typedef float f32x4 __attribute__((ext_vector_type(4)));

#define CSWAP(a, b) { unsigned int _hi = max(a, b); unsigned int _lo = min(a, b); a = _hi; b = _lo; }
// descending bitonic clean of 8 (input: bitonic), 3 stages
#define BITONIC8(T) \
  CSWAP(T[0], T[4]); CSWAP(T[1], T[5]); CSWAP(T[2], T[6]); CSWAP(T[3], T[7]); \
  CSWAP(T[0], T[2]); CSWAP(T[1], T[3]); CSWAP(T[4], T[6]); CSWAP(T[5], T[7]); \
  CSWAP(T[0], T[1]); CSWAP(T[2], T[3]); CSWAP(T[4], T[5]); CSWAP(T[6], T[7]);

__device__ __forceinline__ unsigned short f2bf(float f) {
  unsigned int u = __float_as_uint(f);
  u = (u + 0x7FFFu + ((u >> 16) & 1u)) >> 16;
  return (unsigned short)u;
}
__device__ __forceinline__ float bf2f(unsigned short u) {
  return __uint_as_float(((unsigned int)u) << 16);
}
__device__ __forceinline__ unsigned int pack2(float a, float b) {
  return (unsigned int)f2bf(a) | ((unsigned int)f2bf(b) << 16);
}

// monotone float->uint map, low 12 bits replaced by index
__device__ __forceinline__ unsigned int packScore(float s, int j) {
  unsigned int b = __float_as_uint(s);
  unsigned int m = b ^ ((b & 0x80000000u) ? 0xFFFFFFFFu : 0x80000000u);
  return (m & 0xFFFFF000u) | (unsigned int)j;
}
__device__ __forceinline__ float unpackScore(unsigned int p) {
  unsigned int m = p & 0xFFFFF000u;
  unsigned int b = (m & 0x80000000u) ? (m ^ 0x80000000u) : ~m;
  return __uint_as_float(b);
}

// ---------------- K0: weight prep -------------------------------------------
__global__ void k_transpose(const float* __restrict__ w1, const float* __restrict__ lw,
                            const float* __restrict__ w3, const float* __restrict__ w5,
                            const float* __restrict__ wq, const float* __restrict__ wkv,
                            const float* __restrict__ bq, const float* __restrict__ bkv,
                            const float* __restrict__ wproj,
                            unsigned short* __restrict__ w1bf, unsigned short* __restrict__ lwb,
                            float* __restrict__ w3t, float* __restrict__ w5t,
                            unsigned short* __restrict__ wqkvt, float* __restrict__ qkvb,
                            unsigned short* __restrict__ wprojt) {
  int p = blockIdx.x * 256 + threadIdx.x;
  if (p < 64 * 512) w1bf[p] = f2bf(w1[p]);
  if (p < 64 * 576) {
    int co = p / 576, k = p % 576;
    int tap = k >> 6, ci = k & 63;
    lwb[p] = f2bf(lw[co * 576 + ci * 9 + tap]);
  }
  if (p < 36 * 64) {
    int cin = p & 63, tm = p >> 6;
    int tap = tm >> 2, m = tm & 3;
    w3t[p] = w3[(cin * 4 + m) * 9 + tap];
  }
  if (p < 100 * 64) {
    int cin = p & 63, tm = p >> 6;
    int tap = tm >> 2, m = tm & 3;
    w5t[p] = w5[(cin * 4 + m) * 25 + tap];
  }
  if (p < 192 * 64) {
    int o = p >> 6, i = p & 63;
    float v = (o < 64) ? wq[i * 64 + o] : wkv[i * 128 + (o - 64)];
    wqkvt[p] = f2bf(v);
  }
  if (p < 192) qkvb[p] = (p < 64) ? bq[p] : bkv[p - 64];
  if (p < 64 * 64) {
    int o = p >> 6, i = p & 63;
    wprojt[p] = f2bf(wproj[i * 64 + o]);
  }
}

// ---------------- K1: LN1 + QKV via MFMA (16 tokens/block) + V-sum ----------
__global__ __launch_bounds__(256) void k_ln_qkv(
    const float* __restrict__ x, const float* __restrict__ g1, const float* __restrict__ b1,
    const unsigned short* __restrict__ wqkvt, const float* __restrict__ qkvb,
    unsigned short* __restrict__ q16, unsigned short* __restrict__ k16,
    float* __restrict__ vo, unsigned short* __restrict__ x16,
    float* __restrict__ sumv) {
  __shared__ __align__(16) unsigned short xnS[16 * XNP];
  int bid = blockIdx.x;
  int b = bid / 196, tile = bid % 196;
  size_t tok0 = (size_t)b * Nv + tile * 16;
  int t = threadIdx.x;
  int w = t >> 6, l = t & 63;
  int tokL = t >> 4;        // 0..15
  int ch0 = (t & 15) * 4;
  size_t tok = tok0 + tokL;
  float v[4];
  *(float4*)v = *(const float4*)&x[tok * 64 + ch0];
  {
    unsigned int pk[2] = {pack2(v[0], v[1]), pack2(v[2], v[3])};
    *(uint2*)&x16[tok * 64 + ch0] = *(uint2*)pk;
  }
  float s = v[0] + v[1] + v[2] + v[3];
  float s2 = v[0] * v[0] + v[1] * v[1] + v[2] * v[2] + v[3] * v[3];
#pragma unroll
  for (int off = 1; off <= 8; off <<= 1) {
    s += __shfl_xor(s, off, 64);
    s2 += __shfl_xor(s2, off, 64);
  }
  float m = s * (1.f / 64.f);
  float rs = rsqrtf(s2 * (1.f / 64.f) - m * m + EPS);
  {
    unsigned int pk[2];
    float a0_ = (v[0] - m) * rs * g1[ch0] + b1[ch0];
    float a1_ = (v[1] - m) * rs * g1[ch0 + 1] + b1[ch0 + 1];
    float a2_ = (v[2] - m) * rs * g1[ch0 + 2] + b1[ch0 + 2];
    float a3_ = (v[3] - m) * rs * g1[ch0 + 3] + b1[ch0 + 3];
    pk[0] = pack2(a0_, a1_);
    pk[1] = pack2(a2_, a3_);
    *(uint2*)&xnS[tokL * XNP + ch0] = *(uint2*)pk;
  }
  __syncthreads();
  int n = l & 15, q = l >> 4;
  const bf16x8 a0 = *(const bf16x8*)&xnS[n * XNP + q * 8];
  const bf16x8 a1 = *(const bf16x8*)&xnS[n * XNP + 32 + q * 8];
  // Q tile j=w
  {
    const unsigned short* wr = &wqkvt[(size_t)(w * 16 + n) * 64];
    bf16x8 b0 = *(const bf16x8*)&wr[q * 8];
    bf16x8 b1_ = *(const bf16x8*)&wr[32 + q * 8];
    f32x4 acc = {0.f, 0.f, 0.f, 0.f};
    acc = __builtin_amdgcn_mfma_f32_16x16x32_bf16(a0, b0, acc, 0, 0, 0);
    acc = __builtin_amdgcn_mfma_f32_16x16x32_bf16(a1, b1_, acc, 0, 0, 0);
    float bias = qkvb[w * 16 + n];
#pragma unroll
    for (int r = 0; r < 4; ++r)
      q16[(tok0 + q * 4 + r) * 64 + w * 16 + n] = f2bf(acc[r] + bias);
  }
  // K tile j=w
  {
    const unsigned short* wr = &wqkvt[(size_t)((w + 4) * 16 + n) * 64];
    bf16x8 b0 = *(const bf16x8*)&wr[q * 8];
    bf16x8 b1_ = *(const bf16x8*)&wr[32 + q * 8];
    f32x4 acc = {0.f, 0.f, 0.f, 0.f};
    acc = __builtin_amdgcn_mfma_f32_16x16x32_bf16(a0, b0, acc, 0, 0, 0);
    acc = __builtin_amdgcn_mfma_f32_16x16x32_bf16(a1, b1_, acc, 0, 0, 0);
    float bias = qkvb[64 + w * 16 + n];
#pragma unroll
    for (int r = 0; r < 4; ++r)
      k16[(tok0 + q * 4 + r) * 64 + w * 16 + n] = f2bf(acc[r] + bias);
  }
  // V tile j=w + fused per-batch column sum
  {
    const unsigned short* wr = &wqkvt[(size_t)((w + 8) * 16 + n) * 64];
    bf16x8 b0 = *(const bf16x8*)&wr[q * 8];
    bf16x8 b1_ = *(const bf16x8*)&wr[32 + q * 8];
    f32x4 acc = {0.f, 0.f, 0.f, 0.f};
    acc = __builtin_amdgcn_mfma_f32_16x16x32_bf16(a0, b0, acc, 0, 0, 0);
    acc = __builtin_amdgcn_mfma_f32_16x16x32_bf16(a1, b1_, acc, 0, 0, 0);
    float bias = qkvb[128 + w * 16 + n];
    float vp = acc[0] + acc[1] + acc[2] + acc[3] + 4.0f * bias;
#pragma unroll
    for (int r = 0; r < 4; ++r)
      vo[(tok0 + q * 4 + r) * 64 + w * 16 + n] = acc[r] + bias;
    vp += __shfl_xor(vp, 16, 64);
    vp += __shfl_xor(vp, 32, 64);
    if (q == 0) atomicAdd(&sumv[b * 64 + w * 16 + n], vp);
  }
}

// ---------------- K2a: MFMA QK^T + per-row top-8 over a key quarter ---------
__global__ __launch_bounds__(256) void k_attn_topk(
    const unsigned short* __restrict__ q16, const unsigned short* __restrict__ k16,
    unsigned int* __restrict__ top8out) {
  __shared__ unsigned int candLDS[16][4][9];
  int bid = blockIdx.x;
  int quarter = bid & 3;
  int lin = bid >> 2;
  int b = lin / 196, tile = lin % 196;
  int qbase = b * Nv + tile * 16;
  size_t bN = (size_t)b * Nv;
  int t = threadIdx.x;
  int w = t >> 6, lane = t & 63;
  int qcol = lane & 15, quad = lane >> 4;

  const bf16x8 qf0 = *(const bf16x8*)&q16[((size_t)(qbase + qcol)) * 64 + quad * 8];
  const bf16x8 qf1 = *(const bf16x8*)&q16[((size_t)(qbase + qcol)) * 64 + 32 + quad * 8];

  unsigned int t8[8];
  unsigned int PACKNEG = packScore(-1e30f, 0);
#pragma unroll
  for (int u = 0; u < 8; ++u) t8[u] = PACKNEG;
  float thrRaw = -3.0e38f;

  int chBeg = (quarter * 49) >> 2;        // 0,12,24,36
  int chEnd = ((quarter + 1) * 49) >> 2;  // 12,24,36,49
  int keyRow = w * 16 + qcol;
  bf16x8 kf0 = *(const bf16x8*)&k16[(bN + chBeg * 64 + keyRow) * 64 + quad * 8];
  bf16x8 kf1 = *(const bf16x8*)&k16[(bN + chBeg * 64 + keyRow) * 64 + 32 + quad * 8];

  for (int ch = chBeg; ch < chEnd; ++ch) {
    bf16x8 c0 = kf0, c1 = kf1;
    if (ch + 1 < chEnd) {
      kf0 = *(const bf16x8*)&k16[(bN + (ch + 1) * 64 + keyRow) * 64 + quad * 8];
      kf1 = *(const bf16x8*)&k16[(bN + (ch + 1) * 64 + keyRow) * 64 + 32 + quad * 8];
    }
    f32x4 acc = {0.f, 0.f, 0.f, 0.f};
    acc = __builtin_amdgcn_mfma_f32_16x16x32_bf16(c0, qf0, acc, 0, 0, 0);
    acc = __builtin_amdgcn_mfma_f32_16x16x32_bf16(c1, qf1, acc, 0, 0, 0);
    float m01 = fmaxf(acc[0], acc[1]);
    float m23 = fmaxf(acc[2], acc[3]);
    if (fmaxf(m01, m23) > thrRaw) {
      int jb = ch * 64 + w * 16 + quad * 4;
      unsigned int p0 = packScore(acc[0] * SCALE, jb + 0);
      unsigned int p1 = packScore(acc[1] * SCALE, jb + 1);
      unsigned int p2 = packScore(acc[2] * SCALE, jb + 2);
      unsigned int p3 = packScore(acc[3] * SCALE, jb + 3);
      CSWAP(p0, p1); CSWAP(p2, p3); CSWAP(p0, p2); CSWAP(p1, p3); CSWAP(p1, p2);
      t8[4] = max(t8[4], p3);
      t8[5] = max(t8[5], p2);
      t8[6] = max(t8[6], p1);
      t8[7] = max(t8[7], p0);
      BITONIC8(t8);
      thrRaw = unpackScore(t8[7]) * 8.0f;
    }
  }

#pragma unroll
  for (int step = 16; step <= 32; step <<= 1) {
    unsigned int o[8];
#pragma unroll
    for (int i = 0; i < 8; ++i) o[i] = (unsigned int)__shfl_xor((int)t8[i], step, 64);
    unsigned int nw[8];
#pragma unroll
    for (int i = 0; i < 8; ++i) nw[i] = max(t8[i], o[7 - i]);
#pragma unroll
    for (int i = 0; i < 8; ++i) t8[i] = nw[i];
    BITONIC8(t8);
  }
  if (quad == 0) {
#pragma unroll
    for (int i = 0; i < 8; ++i) candLDS[qcol][w][i] = t8[i];
  }
  __syncthreads();

  if (t < 16) {
    int r = t;
    int p0 = 0, p1 = 0, p2 = 0, p3 = 0;
    size_t obase = ((size_t)(bN + tile * 16 + r)) * 32 + quarter * 8;
#pragma unroll
    for (int u = 0; u < 8; ++u) {
      unsigned int c0 = (p0 < 8) ? candLDS[r][0][p0] : 0u;
      unsigned int c1 = (p1 < 8) ? candLDS[r][1][p1] : 0u;
      unsigned int c2 = (p2 < 8) ? candLDS[r][2][p2] : 0u;
      unsigned int c3 = (p3 < 8) ? candLDS[r][3][p3] : 0u;
      unsigned int best = c0;
      int bw = 0;
      if (c1 > best) { best = c1; bw = 1; }
      if (c2 > best) { best = c2; bw = 2; }
      if (c3 > best) { best = c3; bw = 3; }
      p0 += (bw == 0); p1 += (bw == 1); p2 += (bw == 2); p3 += (bw == 3);
      top8out[obase + u] = best;
    }
  }
}

// ---------------- K2b: merge quarters + PV + proj + LN1 + res + LN2 ---------
// 16 tokens/block, grid Bv*196.
__global__ __launch_bounds__(256) void k_attn_proj(
    const unsigned int* __restrict__ top8, const float* __restrict__ vg,
    const float* __restrict__ sumv,
    const float* __restrict__ x, const float* __restrict__ loc,
    const unsigned short* __restrict__ wprojt, const float* __restrict__ bproj,
    const float* __restrict__ g1, const float* __restrict__ b1,
    const float* __restrict__ g2, const float* __restrict__ b2,
    float* __restrict__ x2, unsigned short* __restrict__ xn2b) {
  __shared__ float kwS[16][8];
  __shared__ int kidxS[16][8];
  __shared__ float invZS[16];
  __shared__ __align__(16) unsigned short gS[16 * XNP];
  __shared__ float yS[16 * 66];
  int bid = blockIdx.x;
  int b = bid / 196, tile = bid % 196;
  size_t bN = (size_t)b * Nv;
  size_t tok0 = bN + tile * 16;
  int t = threadIdx.x;
  // Phase A: merge the 4 sorted quarter-lists per row
  if (t < 16) {
    size_t base = (tok0 + t) * 32;
    unsigned int A[8];
#pragma unroll
    for (int i = 0; i < 8; ++i) A[i] = top8[base + i];
#pragma unroll
    for (int h = 1; h < 4; ++h) {
      unsigned int Bb[8];
#pragma unroll
      for (int i = 0; i < 8; ++i) Bb[i] = top8[base + h * 8 + i];
#pragma unroll
      for (int i = 0; i < 8; ++i) A[i] = max(A[i], Bb[7 - i]);
      BITONIC8(A);
    }
    float Z = (float)(Nv - TOPKv);
#pragma unroll
    for (int u = 0; u < 8; ++u) {
      float s = unpackScore(A[u]);
      float e = __expf(s);
      kwS[t][u] = e - 1.0f;
      kidxS[t][u] = (int)(A[u] & 0xFFFu);
      Z += e;
    }
    invZS[t] = 1.0f / Z;
  }
  __syncthreads();
  // Phase B: g = (sumv + sum_top8 (e^s-1) v)/Z -> gS (bf16)
  {
    int c = t & 63, rg = t >> 6;
    float sv = sumv[b * 64 + c];
#pragma unroll
    for (int rr = 0; rr < 4; ++rr) {
      int tokL = rg * 4 + rr;
      float acc = sv;
#pragma unroll
      for (int u = 0; u < 8; ++u)
        acc += kwS[tokL][u] * vg[(bN + kidxS[tokL][u]) * 64 + c];
      gS[tokL * XNP + c] = f2bf(acc * invZS[tokL]);
    }
  }
  __syncthreads();
  // Phase C: proj GEMM (wave w -> couts w*16..w*16+15), y = proj + loc
  int w = t >> 6, l = t & 63;
  int n = l & 15, q = l >> 4;
  {
    const bf16x8 a0 = *(const bf16x8*)&gS[n * XNP + q * 8];
    const bf16x8 a1 = *(const bf16x8*)&gS[n * XNP + 32 + q * 8];
    const unsigned short* wr = &wprojt[(size_t)(w * 16 + n) * 64];
    bf16x8 b0 = *(const bf16x8*)&wr[q * 8];
    bf16x8 b1_ = *(const bf16x8*)&wr[32 + q * 8];
    f32x4 acc = {0.f, 0.f, 0.f, 0.f};
    acc = __builtin_amdgcn_mfma_f32_16x16x32_bf16(a0, b0, acc, 0, 0, 0);
    acc = __builtin_amdgcn_mfma_f32_16x16x32_bf16(a1, b1_, acc, 0, 0, 0);
    float bias = bproj[w * 16 + n];
#pragma unroll
    for (int r = 0; r < 4; ++r) {
      size_t idx = (tok0 + q * 4 + r) * 64 + w * 16 + n;
      yS[(q * 4 + r) * 66 + w * 16 + n] = acc[r] + bias + loc[idx];
    }
  }
  __syncthreads();
  // Phase D: LN1 -> residual -> LN2 (16-lane group per token, 4 ch each)
  int tokL = t >> 4;
  int ch0 = (t & 15) * 4;
  size_t tok = tok0 + tokL;
  float y[4];
#pragma unroll
  for (int i = 0; i < 4; ++i) y[i] = yS[tokL * 66 + ch0 + i];
  float s = y[0] + y[1] + y[2] + y[3];
  float s2 = y[0] * y[0] + y[1] * y[1] + y[2] * y[2] + y[3] * y[3];
#pragma unroll
  for (int off = 1; off <= 8; off <<= 1) {
    s += __shfl_xor(s, off, 64);
    s2 += __shfl_xor(s2, off, 64);
  }
  float m1 = s * (1.f / 64.f);
  float rs1 = rsqrtf(s2 * (1.f / 64.f) - m1 * m1 + EPS);
  float xv[4];
  *(float4*)xv = *(const float4*)&x[tok * 64 + ch0];
  float x2v[4];
  float t_s = 0.f, t_s2 = 0.f;
#pragma unroll
  for (int i = 0; i < 4; ++i) {
    float t1 = (y[i] - m1) * rs1 * g1[ch0 + i] + b1[ch0 + i];
    x2v[i] = xv[i] + t1;
    t_s += x2v[i];
    t_s2 += x2v[i] * x2v[i];
  }
#pragma unroll
  for (int off = 1; off <= 8; off <<= 1) {
    t_s += __shfl_xor(t_s, off, 64);
    t_s2 += __shfl_xor(t_s2, off, 64);
  }
  float m2 = t_s * (1.f / 64.f);
  float rs2 = rsqrtf(t_s2 * (1.f / 64.f) - m2 * m2 + EPS);
  *(float4*)&x2[tok * 64 + ch0] = *(float4*)x2v;
  unsigned int pk[2];
  {
    float a0_ = (x2v[0] - m2) * rs2 * g2[ch0] + b2[ch0];
    float a1_ = (x2v[1] - m2) * rs2 * g2[ch0 + 1] + b2[ch0 + 1];
    float a2_ = (x2v[2] - m2) * rs2 * g2[ch0 + 2] + b2[ch0 + 2];
    float a3_ = (x2v[3] - m2) * rs2 * g2[ch0 + 3] + b2[ch0 + 3];
    pk[0] = pack2(a0_, a1_);
    pk[1] = pack2(a2_, a3_);
  }
  *(uint2*)&xn2b[tok * 64 + ch0] = *(uint2*)pk;
}

// ---------------- K3a: local 3x3 full conv (64->64) via im2col + MFMA -------
__global__ __launch_bounds__(256) void k_locconv(
    const unsigned short* __restrict__ x16, const unsigned short* __restrict__ lwb,
    const float* __restrict__ lb, float* __restrict__ loc) {
  __shared__ __align__(16) unsigned short im[16 * LCP];
  int bid = blockIdx.x;
  int b = bid / 196, rem = bid % 196;
  int th = rem / 7, tw = rem % 7;
  int h0 = th * 2, w0 = tw * 8;
  size_t bN = (size_t)b * Nv;
  int t = threadIdx.x;
  for (int p = t; p < 1152; p += 256) {
    int sub = p & 7, s = p >> 3;
    int tok = s / 9, tap = s % 9;
    int tr = tok >> 3, tc = tok & 7;
    int dh = tap / 3, dw = tap % 3;
    int gh = h0 + tr - 1 + dh, gw = w0 + tc - 1 + dw;
    bf16x8 v = {};
    if (gh >= 0 && gh < Hh && gw >= 0 && gw < Ww)
      v = *(const bf16x8*)&x16[(bN + gh * Ww + gw) * 64 + sub * 8];
    *(bf16x8*)&im[tok * LCP + tap * 64 + sub * 8] = v;
  }
  __syncthreads();
  int wv = t >> 6, lane = t & 63;
  int n16 = lane & 15, quad = lane >> 4;
  const unsigned short* wrow = &lwb[(size_t)(wv * 16 + n16) * 576];
  f32x4 acc = {0.f, 0.f, 0.f, 0.f};
#pragma unroll 6
  for (int kk = 0; kk < 18; ++kk) {
    bf16x8 af = *(const bf16x8*)&im[n16 * LCP + kk * 32 + quad * 8];
    bf16x8 bfr = *(const bf16x8*)&wrow[kk * 32 + quad * 8];
    acc = __builtin_amdgcn_mfma_f32_16x16x32_bf16(af, bfr, acc, 0, 0, 0);
  }
  float bias = lb[wv * 16 + n16];
#pragma unroll
  for (int r = 0; r < 4; ++r) {
    int tok = quad * 4 + r;
    int trr = tok >> 3, tcc = tok & 7;
    size_t idx = (bN + (size_t)(h0 + trr) * Ww + w0 + tcc) * 64 + wv * 16 + n16;
    loc[idx] = acc[r] + bias;
  }
}

// ---------------- K5: MSFN — depthwise in regs, 1x1 via MFMA ----------------
__global__ __launch_bounds__(256) void k_msfn(
    const unsigned short* __restrict__ xn2b, const float* __restrict__ x2,
    const float* __restrict__ w3t, const float* __restrict__ b3,
    const float* __restrict__ w5t, const float* __restrict__ b5,
    const unsigned short* __restrict__ w1bf, const float* __restrict__ b1,
    float* __restrict__ out) {
  __shared__ __align__(16) unsigned short xtS[6 * 12 * 64];
  __shared__ __align__(16) unsigned short tsS[16 * TSP];

  int bid = blockIdx.x;
  int b = bid / 196;
  int rem = bid % 196;
  int th = rem / 7, tw = rem % 7;
  int h0 = th * 2, w0 = tw * 8;
  size_t bN = (size_t)b * Nv;
  int t = threadIdx.x;

  unsigned int* xtU = (unsigned int*)xtS;
  for (int p = t; p < 6 * 12 * 32; p += 256) {
    int cp = p & 31, rc = p >> 5;
    int r = rc / 12, cc = rc % 12;
    int gh = h0 - 2 + r, gw = w0 - 2 + cc;
    unsigned int v = 0;
    if (gh >= 0 && gh < Hh && gw >= 0 && gw < Ww)
      v = *(const unsigned int*)&xn2b[(bN + gh * Ww + gw) * 64 + cp * 2];
    xtU[rc * 32 + cp] = v;
  }
  __syncthreads();

  int cin = t & 63, tg = t >> 6;
  int tr = tg >> 1, tc0 = (tg & 1) * 4;
  float win[5][8];
#pragma unroll
  for (int r = 0; r < 5; ++r)
#pragma unroll
    for (int c = 0; c < 8; ++c)
      win[r][c] = bf2f(xtS[((tr + r) * 12 + tc0 + c) * 64 + cin]);

  unsigned int* tsU = (unsigned int*)tsS;
#pragma unroll 1
  for (int m2 = 0; m2 < 4; m2 += 2) {
    float a3[2][9], a5[2][25], bb3[2], bb5[2];
#pragma unroll
    for (int mm = 0; mm < 2; ++mm) {
      int m = m2 + mm;
#pragma unroll
      for (int tap = 0; tap < 9; ++tap) a3[mm][tap] = w3t[(tap * 4 + m) * 64 + cin];
#pragma unroll
      for (int tap = 0; tap < 25; ++tap) a5[mm][tap] = w5t[(tap * 4 + m) * 64 + cin];
      bb3[mm] = b3[cin * 4 + m];
      bb5[mm] = b5[cin * 4 + m];
    }
#pragma unroll
    for (int tk = 0; tk < 4; ++tk) {
      int tok = tg * 4 + tk;
      unsigned int p3 = 0, p5 = 0;
#pragma unroll
      for (int mm = 0; mm < 2; ++mm) {
        float acc3 = bb3[mm];
#pragma unroll
        for (int kh = 0; kh < 3; ++kh)
#pragma unroll
          for (int kw2 = 0; kw2 < 3; ++kw2)
            acc3 += win[1 + kh][tk + 1 + kw2] * a3[mm][kh * 3 + kw2];
        float acc5 = bb5[mm];
#pragma unroll
        for (int kh = 0; kh < 5; ++kh)
#pragma unroll
          for (int kw2 = 0; kw2 < 5; ++kw2)
            acc5 += win[kh][tk + kw2] * a5[mm][kh * 5 + kw2];
        p3 |= (unsigned int)f2bf(acc3) << (16 * mm);
        p5 |= (unsigned int)f2bf(acc5) << (16 * mm);
      }
      tsU[(tok * TSP + cin * 4 + m2) >> 1] = p3;
      tsU[(tok * TSP + 256 + cin * 4 + m2) >> 1] = p5;
    }
  }
  __syncthreads();

  int wv = tg, lane = t & 63;
  int n16 = lane & 15, quad = lane >> 4;
  const unsigned short* wrow = &w1bf[(size_t)(wv * 16 + n16) * 512];
  f32x4 acc = {0.f, 0.f, 0.f, 0.f};
#pragma unroll 4
  for (int kk = 0; kk < 16; ++kk) {
    bf16x8 af = *(const bf16x8*)&tsS[n16 * TSP + kk * 32 + quad * 8];
    bf16x8 bfr = *(const bf16x8*)&wrow[kk * 32 + quad * 8];
    acc = __builtin_amdgcn_mfma_f32_16x16x32_bf16(af, bfr, acc, 0, 0, 0);
  }
  float bias = b1[wv * 16 + n16];
#pragma unroll
  for (int r = 0; r < 4; ++r) {
    int tok = quad * 4 + r;
    int trr = tok >> 3, tcc = tok & 7;
    size_t idx = (bN + (size_t)(h0 + trr) * Ww + w0 + tcc) * 64 + wv * 16 + n16;
    out[idx] = x2[idx] + acc[r] + bias;
  }
}

extern "C" void kernel_launch(void* const* d_in, const int* in_sizes, int n_in,
                              void* d_out, int out_size, void* d_ws, size_t ws_size,
                              hipStream_t stream) {
  const float* x = (const float*)d_in[0];
  const float* n1g = (const float*)d_in[1];
  const float* n1b = (const float*)d_in[2];
  const float* wq = (const float*)d_in[3];
  const float* bq = (const float*)d_in[4];
  const float* wkv = (const float*)d_in[5];
  const float* bkv = (const float*)d_in[6];
  const float* wproj = (const float*)d_in[7];
  const float* bproj = (const float*)d_in[8];
  const float* lw = (const float*)d_in[9];
  const float* lb = (const float*)d_in[10];
  const float* n2g = (const float*)d_in[11];
  const float* n2b = (const float*)d_in[12];
  const float* w3 = (const float*)d_in[13];
  const float* b3 = (const float*)d_in[14];
  const float* w5 = (const float*)d_in[15];
  const float* b5 = (const float*)d_in[16];
  const float* w1 = (const float*)d_in[17];
  const float* b1 = (const float*)d_in[18];
  float* out = (float*)d_out;

  float* ws = (float*)d_ws;
  const size_t TOK = (size_t)Bv * Nv * Cv;  // 802816
  float* vb = ws;
  float* sumv = vb + TOK;            // 256
  float* loc = sumv + 256;
  float* x2 = loc + TOK;
  float* w3t = x2 + TOK;             // 2304
  float* w5t = w3t + 2304;           // 6400
  float* qkvb = w5t + 6400;          // 192
  unsigned short* q16 = (unsigned short*)(qkvb + 192);
  unsigned short* k16 = q16 + TOK;
  unsigned short* xn2b = k16 + TOK;
  unsigned short* x16 = xn2b + TOK;
  unsigned short* w1bf = x16 + TOK;        // 64*512
  unsigned short* lwb = w1bf + 64 * 512;   // 64*576
  unsigned short* wqkvt = lwb + 64 * 576;  // 192*64
  unsigned short* wprojt = wqkvt + 192 * 64;  // 64*64
  unsigned int* top8ws = (unsigned int*)(wprojt + 64 * 64 + 64);  // 12544*32 uints

  hipMemsetAsync(sumv, 0, 256 * sizeof(float), stream);
  k_transpose<<<144, 256, 0, stream>>>(w1, lw, w3, w5, wq, wkv, bq, bkv, wproj,
                                       w1bf, lwb, w3t, w5t, wqkvt, qkvb, wprojt);
  k_ln_qkv<<<Bv * 196, 256, 0, stream>>>(x, n1g, n1b, wqkvt, qkvb, q16, k16, vb, x16, sumv);
  k_attn_topk<<<Bv * 196 * 4, 256, 0, stream>>>(q16, k16, top8ws);
  k_locconv<<<Bv * 196, 256, 0, stream>>>(x16, lwb, lb, loc);
  k_attn_proj<<<Bv * 196, 256, 0, stream>>>(top8ws, vb, sumv, x, loc, wprojt, bproj,
                                            n1g, n1b, n2g, n2b, x2, xn2b);
  k_msfn<<<Bv * 196, 256, 0, stream>>>(xn2b, x2, w3t, b3, w5t, b5, w1bf, b1, out);
}

// Round 8
// 193.906 us; speedup vs baseline: 4.5592x; 1.0045x over previous
//
#include <hip/hip_runtime.h>
#include <math.h>

#define Bv 4
#define Nv 3136
#define Cv 64
#define Hh 56
#define Ww 56
#define HIDv 256
#define TOPKv 8
#define TSP 520   // msfn ts row pitch (bf16): dword pitch % 32 == 4 -> conflict-free b128
#define LCP 584   // locconv im2col row pitch (576+8): same property
#define XNP 72    // ln/proj LDS bf16 row pitch (64+8): dword pitch 36 % 32 == 4

constexpr float SCALE = 0.125f;   // d^-0.5, d=64
constexpr float EPS = 1e-5f;

typedef short bf16x8 __attribute__((ext_vector_type(8)));
typedef float f32x4 __attribute__((ext_vector_type(4)));

#define CSWAP(a, b) { unsigned int _hi = max(a, b); unsigned int _lo = min(a, b); a = _hi; b = _lo; }
// descending bitonic clean of 8 (input: bitonic), 3 stages
#define BITONIC8(T) \
  CSWAP(T[0], T[4]); CSWAP(T[1], T[5]); CSWAP(T[2], T[6]); CSWAP(T[3], T[7]); \
  CSWAP(T[0], T[2]); CSWAP(T[1], T[3]); CSWAP(T[4], T[6]); CSWAP(T[5], T[7]); \
  CSWAP(T[0], T[1]); CSWAP(T[2], T[3]); CSWAP(T[4], T[5]); CSWAP(T[6], T[7]);

__device__ __forceinline__ unsigned short f2bf(float f) {
  unsigned int u = __float_as_uint(f);
  u = (u + 0x7FFFu + ((u >> 16) & 1u)) >> 16;
  return (unsigned short)u;
}
__device__ __forceinline__ float bf2f(unsigned short u) {
  return __uint_as_float(((unsigned int)u) << 16);
}
__device__ __forceinline__ unsigned int pack2(float a, float b) {
  return (unsigned int)f2bf(a) | ((unsigned int)f2bf(b) << 16);
}

// monotone float->uint map, low 12 bits replaced by index
__device__ __forceinline__ unsigned int packScore(float s, int j) {
  unsigned int b = __float_as_uint(s);
  unsigned int m = b ^ ((b & 0x80000000u) ? 0xFFFFFFFFu : 0x80000000u);
  return (m & 0xFFFFF000u) | (unsigned int)j;
}
__device__ __forceinline__ float unpackScore(unsigned int p) {
  unsigned int m = p & 0xFFFFF000u;
  unsigned int b = (m & 0x80000000u) ? (m ^ 0x80000000u) : ~m;
  return __uint_as_float(b);
}

// ---------------- K0: weight prep -------------------------------------------
__global__ void k_transpose(const float* __restrict__ w1, const float* __restrict__ lw,
                            const float* __restrict__ w3, const float* __restrict__ w5,
                            const float* __restrict__ wq, const float* __restrict__ wkv,
                            const float* __restrict__ bq, const float* __restrict__ bkv,
                            const float* __restrict__ wproj,
                            unsigned short* __restrict__ w1bf, unsigned short* __restrict__ lwb,
                            float* __restrict__ w3t, float* __restrict__ w5t,
                            unsigned short* __restrict__ wqkvt, float* __restrict__ qkvb,
                            unsigned short* __restrict__ wprojt) {
  int p = blockIdx.x * 256 + threadIdx.x;
  if (p < 64 * 512) w1bf[p] = f2bf(w1[p]);
  if (p < 64 * 576) {
    int co = p / 576, k = p % 576;
    int tap = k >> 6, ci = k & 63;
    lwb[p] = f2bf(lw[co * 576 + ci * 9 + tap]);
  }
  if (p < 36 * 64) {
    int cin = p & 63, tm = p >> 6;
    int tap = tm >> 2, m = tm & 3;
    w3t[p] = w3[(cin * 4 + m) * 9 + tap];
  }
  if (p < 100 * 64) {
    int cin = p & 63, tm = p >> 6;
    int tap = tm >> 2, m = tm & 3;
    w5t[p] = w5[(cin * 4 + m) * 25 + tap];
  }
  if (p < 192 * 64) {
    int o = p >> 6, i = p & 63;
    float v = (o < 64) ? wq[i * 64 + o] : wkv[i * 128 + (o - 64)];
    wqkvt[p] = f2bf(v);
  }
  if (p < 192) qkvb[p] = (p < 64) ? bq[p] : bkv[p - 64];
  if (p < 64 * 64) {
    int o = p >> 6, i = p & 63;
    wprojt[p] = f2bf(wproj[i * 64 + o]);
  }
}

// ---------------- K1: LN1 + QKV via MFMA (16 tokens/block) + V-sum ----------
__global__ __launch_bounds__(256) void k_ln_qkv(
    const float* __restrict__ x, const float* __restrict__ g1, const float* __restrict__ b1,
    const unsigned short* __restrict__ wqkvt, const float* __restrict__ qkvb,
    unsigned short* __restrict__ q16, unsigned short* __restrict__ k16,
    float* __restrict__ vo, unsigned short* __restrict__ x16,
    float* __restrict__ sumv) {
  __shared__ __align__(16) unsigned short xnS[16 * XNP];
  int bid = blockIdx.x;
  int b = bid / 196, tile = bid % 196;
  size_t tok0 = (size_t)b * Nv + tile * 16;
  int t = threadIdx.x;
  int w = t >> 6, l = t & 63;
  int tokL = t >> 4;        // 0..15
  int ch0 = (t & 15) * 4;
  size_t tok = tok0 + tokL;
  float v[4];
  *(float4*)v = *(const float4*)&x[tok * 64 + ch0];
  {
    unsigned int pk[2] = {pack2(v[0], v[1]), pack2(v[2], v[3])};
    *(uint2*)&x16[tok * 64 + ch0] = *(uint2*)pk;
  }
  float s = v[0] + v[1] + v[2] + v[3];
  float s2 = v[0] * v[0] + v[1] * v[1] + v[2] * v[2] + v[3] * v[3];
#pragma unroll
  for (int off = 1; off <= 8; off <<= 1) {
    s += __shfl_xor(s, off, 64);
    s2 += __shfl_xor(s2, off, 64);
  }
  float m = s * (1.f / 64.f);
  float rs = rsqrtf(s2 * (1.f / 64.f) - m * m + EPS);
  {
    unsigned int pk[2];
    float a0_ = (v[0] - m) * rs * g1[ch0] + b1[ch0];
    float a1_ = (v[1] - m) * rs * g1[ch0 + 1] + b1[ch0 + 1];
    float a2_ = (v[2] - m) * rs * g1[ch0 + 2] + b1[ch0 + 2];
    float a3_ = (v[3] - m) * rs * g1[ch0 + 3] + b1[ch0 + 3];
    pk[0] = pack2(a0_, a1_);
    pk[1] = pack2(a2_, a3_);
    *(uint2*)&xnS[tokL * XNP + ch0] = *(uint2*)pk;
  }
  __syncthreads();
  int n = l & 15, q = l >> 4;
  const bf16x8 a0 = *(const bf16x8*)&xnS[n * XNP + q * 8];
  const bf16x8 a1 = *(const bf16x8*)&xnS[n * XNP + 32 + q * 8];
  // Q tile j=w
  {
    const unsigned short* wr = &wqkvt[(size_t)(w * 16 + n) * 64];
    bf16x8 b0 = *(const bf16x8*)&wr[q * 8];
    bf16x8 b1_ = *(const bf16x8*)&wr[32 + q * 8];
    f32x4 acc = {0.f, 0.f, 0.f, 0.f};
    acc = __builtin_amdgcn_mfma_f32_16x16x32_bf16(a0, b0, acc, 0, 0, 0);
    acc = __builtin_amdgcn_mfma_f32_16x16x32_bf16(a1, b1_, acc, 0, 0, 0);
    float bias = qkvb[w * 16 + n];
#pragma unroll
    for (int r = 0; r < 4; ++r)
      q16[(tok0 + q * 4 + r) * 64 + w * 16 + n] = f2bf(acc[r] + bias);
  }
  // K tile j=w
  {
    const unsigned short* wr = &wqkvt[(size_t)((w + 4) * 16 + n) * 64];
    bf16x8 b0 = *(const bf16x8*)&wr[q * 8];
    bf16x8 b1_ = *(const bf16x8*)&wr[32 + q * 8];
    f32x4 acc = {0.f, 0.f, 0.f, 0.f};
    acc = __builtin_amdgcn_mfma_f32_16x16x32_bf16(a0, b0, acc, 0, 0, 0);
    acc = __builtin_amdgcn_mfma_f32_16x16x32_bf16(a1, b1_, acc, 0, 0, 0);
    float bias = qkvb[64 + w * 16 + n];
#pragma unroll
    for (int r = 0; r < 4; ++r)
      k16[(tok0 + q * 4 + r) * 64 + w * 16 + n] = f2bf(acc[r] + bias);
  }
  // V tile j=w + fused per-batch column sum
  {
    const unsigned short* wr = &wqkvt[(size_t)((w + 8) * 16 + n) * 64];
    bf16x8 b0 = *(const bf16x8*)&wr[q * 8];
    bf16x8 b1_ = *(const bf16x8*)&wr[32 + q * 8];
    f32x4 acc = {0.f, 0.f, 0.f, 0.f};
    acc = __builtin_amdgcn_mfma_f32_16x16x32_bf16(a0, b0, acc, 0, 0, 0);
    acc = __builtin_amdgcn_mfma_f32_16x16x32_bf16(a1, b1_, acc, 0, 0, 0);
    float bias = qkvb[128 + w * 16 + n];
    float vp = acc[0] + acc[1] + acc[2] + acc[3] + 4.0f * bias;
#pragma unroll
    for (int r = 0; r < 4; ++r)
      vo[(tok0 + q * 4 + r) * 64 + w * 16 + n] = acc[r] + bias;
    vp += __shfl_xor(vp, 16, 64);
    vp += __shfl_xor(vp, 32, 64);
    if (q == 0) atomicAdd(&sumv[b * 64 + w * 16 + n], vp);
  }
}

// ---------------- K2a: MFMA QK^T + branchless per-row top-8 (key quarter) ---
// Scores kept UNSCALED (selection is scale-invariant; SCALE applied in K2b).
__global__ __launch_bounds__(256) void k_attn_topk(
    const unsigned short* __restrict__ q16, const unsigned short* __restrict__ k16,
    unsigned int* __restrict__ top8out) {
  __shared__ unsigned int candLDS[16][4][9];
  int bid = blockIdx.x;
  int quarter = bid & 3;
  int lin = bid >> 2;
  int b = lin / 196, tile = lin % 196;
  int qbase = b * Nv + tile * 16;
  size_t bN = (size_t)b * Nv;
  int t = threadIdx.x;
  int w = t >> 6, lane = t & 63;
  int qcol = lane & 15, quad = lane >> 4;

  const bf16x8 qf0 = *(const bf16x8*)&q16[((size_t)(qbase + qcol)) * 64 + quad * 8];
  const bf16x8 qf1 = *(const bf16x8*)&q16[((size_t)(qbase + qcol)) * 64 + 32 + quad * 8];

  unsigned int t8[8];
  unsigned int PACKNEG = packScore(-1e30f, 0);
#pragma unroll
  for (int u = 0; u < 8; ++u) t8[u] = PACKNEG;

  int chBeg = (quarter * 49) >> 2;        // 0,12,24,36
  int chEnd = ((quarter + 1) * 49) >> 2;  // 12,24,36,49
  int keyRow = w * 16 + qcol;
  bf16x8 kf0 = *(const bf16x8*)&k16[(bN + chBeg * 64 + keyRow) * 64 + quad * 8];
  bf16x8 kf1 = *(const bf16x8*)&k16[(bN + chBeg * 64 + keyRow) * 64 + 32 + quad * 8];

  for (int ch = chBeg; ch < chEnd; ++ch) {
    bf16x8 c0 = kf0, c1 = kf1;
    if (ch + 1 < chEnd) {
      kf0 = *(const bf16x8*)&k16[(bN + (ch + 1) * 64 + keyRow) * 64 + quad * 8];
      kf1 = *(const bf16x8*)&k16[(bN + (ch + 1) * 64 + keyRow) * 64 + 32 + quad * 8];
    }
    f32x4 acc = {0.f, 0.f, 0.f, 0.f};
    acc = __builtin_amdgcn_mfma_f32_16x16x32_bf16(c0, qf0, acc, 0, 0, 0);
    acc = __builtin_amdgcn_mfma_f32_16x16x32_bf16(c1, qf1, acc, 0, 0, 0);
    // branchless: pack4 (unscaled) -> sort4 -> tail merge -> bitonic clean
    int jb = ch * 64 + w * 16 + quad * 4;
    unsigned int p0 = packScore(acc[0], jb + 0);
    unsigned int p1 = packScore(acc[1], jb + 1);
    unsigned int p2 = packScore(acc[2], jb + 2);
    unsigned int p3 = packScore(acc[3], jb + 3);
    CSWAP(p0, p1); CSWAP(p2, p3); CSWAP(p0, p2); CSWAP(p1, p3); CSWAP(p1, p2);
    t8[4] = max(t8[4], p3);
    t8[5] = max(t8[5], p2);
    t8[6] = max(t8[6], p1);
    t8[7] = max(t8[7], p0);
    BITONIC8(t8);
  }

#pragma unroll
  for (int step = 16; step <= 32; step <<= 1) {
    unsigned int o[8];
#pragma unroll
    for (int i = 0; i < 8; ++i) o[i] = (unsigned int)__shfl_xor((int)t8[i], step, 64);
    unsigned int nw[8];
#pragma unroll
    for (int i = 0; i < 8; ++i) nw[i] = max(t8[i], o[7 - i]);
#pragma unroll
    for (int i = 0; i < 8; ++i) t8[i] = nw[i];
    BITONIC8(t8);
  }
  if (quad == 0) {
#pragma unroll
    for (int i = 0; i < 8; ++i) candLDS[qcol][w][i] = t8[i];
  }
  __syncthreads();

  if (t < 16) {
    int r = t;
    int p0 = 0, p1 = 0, p2 = 0, p3 = 0;
    size_t obase = ((size_t)(bN + tile * 16 + r)) * 32 + quarter * 8;
#pragma unroll
    for (int u = 0; u < 8; ++u) {
      unsigned int c0 = (p0 < 8) ? candLDS[r][0][p0] : 0u;
      unsigned int c1 = (p1 < 8) ? candLDS[r][1][p1] : 0u;
      unsigned int c2 = (p2 < 8) ? candLDS[r][2][p2] : 0u;
      unsigned int c3 = (p3 < 8) ? candLDS[r][3][p3] : 0u;
      unsigned int best = c0;
      int bw = 0;
      if (c1 > best) { best = c1; bw = 1; }
      if (c2 > best) { best = c2; bw = 2; }
      if (c3 > best) { best = c3; bw = 3; }
      p0 += (bw == 0); p1 += (bw == 1); p2 += (bw == 2); p3 += (bw == 3);
      top8out[obase + u] = best;
    }
  }
}

// ---------------- K2b: merge quarters + PV + proj + LN1 + res + LN2 ---------
// 16 tokens/block, grid Bv*196.  (scores arrive UNSCALED -> apply SCALE here)
__global__ __launch_bounds__(256) void k_attn_proj(
    const unsigned int* __restrict__ top8, const float* __restrict__ vg,
    const float* __restrict__ sumv,
    const float* __restrict__ x, const float* __restrict__ loc,
    const unsigned short* __restrict__ wprojt, const float* __restrict__ bproj,
    const float* __restrict__ g1, const float* __restrict__ b1,
    const float* __restrict__ g2, const float* __restrict__ b2,
    float* __restrict__ x2, unsigned short* __restrict__ xn2b) {
  __shared__ float kwS[16][8];
  __shared__ int kidxS[16][8];
  __shared__ float invZS[16];
  __shared__ __align__(16) unsigned short gS[16 * XNP];
  __shared__ float yS[16 * 66];
  int bid = blockIdx.x;
  int b = bid / 196, tile = bid % 196;
  size_t bN = (size_t)b * Nv;
  size_t tok0 = bN + tile * 16;
  int t = threadIdx.x;
  // Phase A: merge the 4 sorted quarter-lists per row
  if (t < 16) {
    size_t base = (tok0 + t) * 32;
    unsigned int A[8];
#pragma unroll
    for (int i = 0; i < 8; ++i) A[i] = top8[base + i];
#pragma unroll
    for (int h = 1; h < 4; ++h) {
      unsigned int Bb[8];
#pragma unroll
      for (int i = 0; i < 8; ++i) Bb[i] = top8[base + h * 8 + i];
#pragma unroll
      for (int i = 0; i < 8; ++i) A[i] = max(A[i], Bb[7 - i]);
      BITONIC8(A);
    }
    float Z = (float)(Nv - TOPKv);
#pragma unroll
    for (int u = 0; u < 8; ++u) {
      float s = unpackScore(A[u]) * SCALE;
      float e = __expf(s);
      kwS[t][u] = e - 1.0f;
      kidxS[t][u] = (int)(A[u] & 0xFFFu);
      Z += e;
    }
    invZS[t] = 1.0f / Z;
  }
  __syncthreads();
  // Phase B: g = (sumv + sum_top8 (e^s-1) v)/Z -> gS (bf16)
  {
    int c = t & 63, rg = t >> 6;
    float sv = sumv[b * 64 + c];
#pragma unroll
    for (int rr = 0; rr < 4; ++rr) {
      int tokL = rg * 4 + rr;
      float acc = sv;
#pragma unroll
      for (int u = 0; u < 8; ++u)
        acc += kwS[tokL][u] * vg[(bN + kidxS[tokL][u]) * 64 + c];
      gS[tokL * XNP + c] = f2bf(acc * invZS[tokL]);
    }
  }
  __syncthreads();
  // Phase C: proj GEMM (wave w -> couts w*16..w*16+15), y = proj + loc
  int w = t >> 6, l = t & 63;
  int n = l & 15, q = l >> 4;
  {
    const bf16x8 a0 = *(const bf16x8*)&gS[n * XNP + q * 8];
    const bf16x8 a1 = *(const bf16x8*)&gS[n * XNP + 32 + q * 8];
    const unsigned short* wr = &wprojt[(size_t)(w * 16 + n) * 64];
    bf16x8 b0 = *(const bf16x8*)&wr[q * 8];
    bf16x8 b1_ = *(const bf16x8*)&wr[32 + q * 8];
    f32x4 acc = {0.f, 0.f, 0.f, 0.f};
    acc = __builtin_amdgcn_mfma_f32_16x16x32_bf16(a0, b0, acc, 0, 0, 0);
    acc = __builtin_amdgcn_mfma_f32_16x16x32_bf16(a1, b1_, acc, 0, 0, 0);
    float bias = bproj[w * 16 + n];
#pragma unroll
    for (int r = 0; r < 4; ++r) {
      size_t idx = (tok0 + q * 4 + r) * 64 + w * 16 + n;
      yS[(q * 4 + r) * 66 + w * 16 + n] = acc[r] + bias + loc[idx];
    }
  }
  __syncthreads();
  // Phase D: LN1 -> residual -> LN2 (16-lane group per token, 4 ch each)
  int tokL = t >> 4;
  int ch0 = (t & 15) * 4;
  size_t tok = tok0 + tokL;
  float y[4];
#pragma unroll
  for (int i = 0; i < 4; ++i) y[i] = yS[tokL * 66 + ch0 + i];
  float s = y[0] + y[1] + y[2] + y[3];
  float s2 = y[0] * y[0] + y[1] * y[1] + y[2] * y[2] + y[3] * y[3];
#pragma unroll
  for (int off = 1; off <= 8; off <<= 1) {
    s += __shfl_xor(s, off, 64);
    s2 += __shfl_xor(s2, off, 64);
  }
  float m1 = s * (1.f / 64.f);
  float rs1 = rsqrtf(s2 * (1.f / 64.f) - m1 * m1 + EPS);
  float xv[4];
  *(float4*)xv = *(const float4*)&x[tok * 64 + ch0];
  float x2v[4];
  float t_s = 0.f, t_s2 = 0.f;
#pragma unroll
  for (int i = 0; i < 4; ++i) {
    float t1 = (y[i] - m1) * rs1 * g1[ch0 + i] + b1[ch0 + i];
    x2v[i] = xv[i] + t1;
    t_s += x2v[i];
    t_s2 += x2v[i] * x2v[i];
  }
#pragma unroll
  for (int off = 1; off <= 8; off <<= 1) {
    t_s += __shfl_xor(t_s, off, 64);
    t_s2 += __shfl_xor(t_s2, off, 64);
  }
  float m2 = t_s * (1.f / 64.f);
  float rs2 = rsqrtf(t_s2 * (1.f / 64.f) - m2 * m2 + EPS);
  *(float4*)&x2[tok * 64 + ch0] = *(float4*)x2v;
  unsigned int pk[2];
  {
    float a0_ = (x2v[0] - m2) * rs2 * g2[ch0] + b2[ch0];
    float a1_ = (x2v[1] - m2) * rs2 * g2[ch0 + 1] + b2[ch0 + 1];
    float a2_ = (x2v[2] - m2) * rs2 * g2[ch0 + 2] + b2[ch0 + 2];
    float a3_ = (x2v[3] - m2) * rs2 * g2[ch0 + 3] + b2[ch0 + 3];
    pk[0] = pack2(a0_, a1_);
    pk[1] = pack2(a2_, a3_);
  }
  *(uint2*)&xn2b[tok * 64 + ch0] = *(uint2*)pk;
}

// ---------------- K3a: local 3x3 full conv (64->64) via im2col + MFMA -------
__global__ __launch_bounds__(256) void k_locconv(
    const unsigned short* __restrict__ x16, const unsigned short* __restrict__ lwb,
    const float* __restrict__ lb, float* __restrict__ loc) {
  __shared__ __align__(16) unsigned short im[16 * LCP];
  int bid = blockIdx.x;
  int b = bid / 196, rem = bid % 196;
  int th = rem / 7, tw = rem % 7;
  int h0 = th * 2, w0 = tw * 8;
  size_t bN = (size_t)b * Nv;
  int t = threadIdx.x;
  for (int p = t; p < 1152; p += 256) {
    int sub = p & 7, s = p >> 3;
    int tok = s / 9, tap = s % 9;
    int tr = tok >> 3, tc = tok & 7;
    int dh = tap / 3, dw = tap % 3;
    int gh = h0 + tr - 1 + dh, gw = w0 + tc - 1 + dw;
    bf16x8 v = {};
    if (gh >= 0 && gh < Hh && gw >= 0 && gw < Ww)
      v = *(const bf16x8*)&x16[(bN + gh * Ww + gw) * 64 + sub * 8];
    *(bf16x8*)&im[tok * LCP + tap * 64 + sub * 8] = v;
  }
  __syncthreads();
  int wv = t >> 6, lane = t & 63;
  int n16 = lane & 15, quad = lane >> 4;
  const unsigned short* wrow = &lwb[(size_t)(wv * 16 + n16) * 576];
  f32x4 acc = {0.f, 0.f, 0.f, 0.f};
#pragma unroll 6
  for (int kk = 0; kk < 18; ++kk) {
    bf16x8 af = *(const bf16x8*)&im[n16 * LCP + kk * 32 + quad * 8];
    bf16x8 bfr = *(const bf16x8*)&wrow[kk * 32 + quad * 8];
    acc = __builtin_amdgcn_mfma_f32_16x16x32_bf16(af, bfr, acc, 0, 0, 0);
  }
  float bias = lb[wv * 16 + n16];
#pragma unroll
  for (int r = 0; r < 4; ++r) {
    int tok = quad * 4 + r;
    int trr = tok >> 3, tcc = tok & 7;
    size_t idx = (bN + (size_t)(h0 + trr) * Ww + w0 + tcc) * 64 + wv * 16 + n16;
    loc[idx] = acc[r] + bias;
  }
}

// ---------------- K5: MSFN — depthwise in regs, 1x1 via MFMA ----------------
__global__ __launch_bounds__(256) void k_msfn(
    const unsigned short* __restrict__ xn2b, const float* __restrict__ x2,
    const float* __restrict__ w3t, const float* __restrict__ b3,
    const float* __restrict__ w5t, const float* __restrict__ b5,
    const unsigned short* __restrict__ w1bf, const float* __restrict__ b1,
    float* __restrict__ out) {
  __shared__ __align__(16) unsigned short xtS[6 * 12 * 64];
  __shared__ __align__(16) unsigned short tsS[16 * TSP];

  int bid = blockIdx.x;
  int b = bid / 196;
  int rem = bid % 196;
  int th = rem / 7, tw = rem % 7;
  int h0 = th * 2, w0 = tw * 8;
  size_t bN = (size_t)b * Nv;
  int t = threadIdx.x;

  unsigned int* xtU = (unsigned int*)xtS;
  for (int p = t; p < 6 * 12 * 32; p += 256) {
    int cp = p & 31, rc = p >> 5;
    int r = rc / 12, cc = rc % 12;
    int gh = h0 - 2 + r, gw = w0 - 2 + cc;
    unsigned int v = 0;
    if (gh >= 0 && gh < Hh && gw >= 0 && gw < Ww)
      v = *(const unsigned int*)&xn2b[(bN + gh * Ww + gw) * 64 + cp * 2];
    xtU[rc * 32 + cp] = v;
  }
  __syncthreads();

  int cin = t & 63, tg = t >> 6;
  int tr = tg >> 1, tc0 = (tg & 1) * 4;
  float win[5][8];
#pragma unroll
  for (int r = 0; r < 5; ++r)
#pragma unroll
    for (int c = 0; c < 8; ++c)
      win[r][c] = bf2f(xtS[((tr + r) * 12 + tc0 + c) * 64 + cin]);

  unsigned int* tsU = (unsigned int*)tsS;
#pragma unroll 1
  for (int m2 = 0; m2 < 4; m2 += 2) {
    float a3[2][9], a5[2][25], bb3[2], bb5[2];
#pragma unroll
    for (int mm = 0; mm < 2; ++mm) {
      int m = m2 + mm;
#pragma unroll
      for (int tap = 0; tap < 9; ++tap) a3[mm][tap] = w3t[(tap * 4 + m) * 64 + cin];
#pragma unroll
      for (int tap = 0; tap < 25; ++tap) a5[mm][tap] = w5t[(tap * 4 + m) * 64 + cin];
      bb3[mm] = b3[cin * 4 + m];
      bb5[mm] = b5[cin * 4 + m];
    }
#pragma unroll
    for (int tk = 0; tk < 4; ++tk) {
      int tok = tg * 4 + tk;
      unsigned int p3 = 0, p5 = 0;
#pragma unroll
      for (int mm = 0; mm < 2; ++mm) {
        float acc3 = bb3[mm];
#pragma unroll
        for (int kh = 0; kh < 3; ++kh)
#pragma unroll
          for (int kw2 = 0; kw2 < 3; ++kw2)
            acc3 += win[1 + kh][tk + 1 + kw2] * a3[mm][kh * 3 + kw2];
        float acc5 = bb5[mm];
#pragma unroll
        for (int kh = 0; kh < 5; ++kh)
#pragma unroll
          for (int kw2 = 0; kw2 < 5; ++kw2)
            acc5 += win[kh][tk + kw2] * a5[mm][kh * 5 + kw2];
        p3 |= (unsigned int)f2bf(acc3) << (16 * mm);
        p5 |= (unsigned int)f2bf(acc5) << (16 * mm);
      }
      tsU[(tok * TSP + cin * 4 + m2) >> 1] = p3;
      tsU[(tok * TSP + 256 + cin * 4 + m2) >> 1] = p5;
    }
  }
  __syncthreads();

  int wv = tg, lane = t & 63;
  int n16 = lane & 15, quad = lane >> 4;
  const unsigned short* wrow = &w1bf[(size_t)(wv * 16 + n16) * 512];
  f32x4 acc = {0.f, 0.f, 0.f, 0.f};
#pragma unroll 4
  for (int kk = 0; kk < 16; ++kk) {
    bf16x8 af = *(const bf16x8*)&tsS[n16 * TSP + kk * 32 + quad * 8];
    bf16x8 bfr = *(const bf16x8*)&wrow[kk * 32 + quad * 8];
    acc = __builtin_amdgcn_mfma_f32_16x16x32_bf16(af, bfr, acc, 0, 0, 0);
  }
  float bias = b1[wv * 16 + n16];
#pragma unroll
  for (int r = 0; r < 4; ++r) {
    int tok = quad * 4 + r;
    int trr = tok >> 3, tcc = tok & 7;
    size_t idx = (bN + (size_t)(h0 + trr) * Ww + w0 + tcc) * 64 + wv * 16 + n16;
    out[idx] = x2[idx] + acc[r] + bias;
  }
}

extern "C" void kernel_launch(void* const* d_in, const int* in_sizes, int n_in,
                              void* d_out, int out_size, void* d_ws, size_t ws_size,
                              hipStream_t stream) {
  const float* x = (const float*)d_in[0];
  const float* n1g = (const float*)d_in[1];
  const float* n1b = (const float*)d_in[2];
  const float* wq = (const float*)d_in[3];
  const float* bq = (const float*)d_in[4];
  const float* wkv = (const float*)d_in[5];
  const float* bkv = (const float*)d_in[6];
  const float* wproj = (const float*)d_in[7];
  const float* bproj = (const float*)d_in[8];
  const float* lw = (const float*)d_in[9];
  const float* lb = (const float*)d_in[10];
  const float* n2g = (const float*)d_in[11];
  const float* n2b = (const float*)d_in[12];
  const float* w3 = (const float*)d_in[13];
  const float* b3 = (const float*)d_in[14];
  const float* w5 = (const float*)d_in[15];
  const float* b5 = (const float*)d_in[16];
  const float* w1 = (const float*)d_in[17];
  const float* b1 = (const float*)d_in[18];
  float* out = (float*)d_out;

  float* ws = (float*)d_ws;
  const size_t TOK = (size_t)Bv * Nv * Cv;  // 802816
  float* vb = ws;
  float* sumv = vb + TOK;            // 256
  float* loc = sumv + 256;
  float* x2 = loc + TOK;
  float* w3t = x2 + TOK;             // 2304
  float* w5t = w3t + 2304;           // 6400
  float* qkvb = w5t + 6400;          // 192
  unsigned short* q16 = (unsigned short*)(qkvb + 192);
  unsigned short* k16 = q16 + TOK;
  unsigned short* xn2b = k16 + TOK;
  unsigned short* x16 = xn2b + TOK;
  unsigned short* w1bf = x16 + TOK;        // 64*512
  unsigned short* lwb = w1bf + 64 * 512;   // 64*576
  unsigned short* wqkvt = lwb + 64 * 576;  // 192*64
  unsigned short* wprojt = wqkvt + 192 * 64;  // 64*64
  unsigned int* top8ws = (unsigned int*)(wprojt + 64 * 64 + 64);  // 12544*32 uints

  hipMemsetAsync(sumv, 0, 256 * sizeof(float), stream);
  k_transpose<<<144, 256, 0, stream>>>(w1, lw, w3, w5, wq, wkv, bq, bkv, wproj,
                                       w1bf, lwb, w3t, w5t, wqkvt, qkvb, wprojt);
  k_ln_qkv<<<Bv * 196, 256, 0, stream>>>(x, n1g, n1b, wqkvt, qkvb, q16, k16, vb, x16, sumv);
  k_attn_topk<<<Bv * 196 * 4, 256, 0, stream>>>(q16, k16, top8ws);
  k_locconv<<<Bv * 196, 256, 0, stream>>>(x16, lwb, lb, loc);
  k_attn_proj<<<Bv * 196, 256, 0, stream>>>(top8ws, vb, sumv, x, loc, wprojt, bproj,
                                            n1g, n1b, n2g, n2b, x2, xn2b);
  k_msfn<<<Bv * 196, 256, 0, stream>>>(xn2b, x2, w3t, b3, w5t, b5, w1bf, b1, out);
}

// Round 9
// 191.892 us; speedup vs baseline: 4.6070x; 1.0105x over previous
//
#include <hip/hip_runtime.h>
#include <math.h>

#define Bv 4
#define Nv 3136
#define Cv 64
#define Hh 56
#define Ww 56
#define HIDv 256
#define TOPKv 8
#define TSP 520   // msfn ts row pitch (bf16): dword pitch % 32 == 4 -> conflict-free b128
#define LCP 584   // locconv im2col row pitch (576+8): same property
#define XNP 72    // ln/proj LDS bf16 row pitch (64+8): dword pitch 36 % 32 == 4

constexpr float SCALE = 0.125f;   // d^-0.5, d=64
constexpr float EPS = 1e-5f;

typedef short bf16x8 __attribute__((ext_vector_type(8)));
typedef float f32x4 __attribute__((ext_vector_type(4)));

#define CSWAP(a, b) { unsigned int _hi = max(a, b); unsigned int _lo = min(a, b); a = _hi; b = _lo; }
// descending bitonic clean of 8 (input: bitonic), 3 stages
#define BITONIC8(T) \
  CSWAP(T[0], T[4]); CSWAP(T[1], T[5]); CSWAP(T[2], T[6]); CSWAP(T[3], T[7]); \
  CSWAP(T[0], T[2]); CSWAP(T[1], T[3]); CSWAP(T[4], T[6]); CSWAP(T[5], T[7]); \
  CSWAP(T[0], T[1]); CSWAP(T[2], T[3]); CSWAP(T[4], T[5]); CSWAP(T[6], T[7]);

__device__ __forceinline__ unsigned short f2bf(float f) {
  unsigned int u = __float_as_uint(f);
  u = (u + 0x7FFFu + ((u >> 16) & 1u)) >> 16;
  return (unsigned short)u;
}
__device__ __forceinline__ float bf2f(unsigned short u) {
  return __uint_as_float(((unsigned int)u) << 16);
}
__device__ __forceinline__ unsigned int pack2(float a, float b) {
  return (unsigned int)f2bf(a) | ((unsigned int)f2bf(b) << 16);
}

// monotone float->uint map, low 12 bits replaced by index
__device__ __forceinline__ unsigned int packScore(float s, int j) {
  unsigned int b = __float_as_uint(s);
  unsigned int m = b ^ ((b & 0x80000000u) ? 0xFFFFFFFFu : 0x80000000u);
  return (m & 0xFFFFF000u) | (unsigned int)j;
}
__device__ __forceinline__ float unpackScore(unsigned int p) {
  unsigned int m = p & 0xFFFFF000u;
  unsigned int b = (m & 0x80000000u) ? (m ^ 0x80000000u) : ~m;
  return __uint_as_float(b);
}

// ---------------- K0: weight prep -------------------------------------------
__global__ void k_transpose(const float* __restrict__ w1, const float* __restrict__ lw,
                            const float* __restrict__ w3, const float* __restrict__ w5,
                            const float* __restrict__ wq, const float* __restrict__ wkv,
                            const float* __restrict__ bq, const float* __restrict__ bkv,
                            const float* __restrict__ wproj,
                            unsigned short* __restrict__ w1bf, unsigned short* __restrict__ lwb,
                            float* __restrict__ w3t, float* __restrict__ w5t,
                            unsigned short* __restrict__ wqkvt, float* __restrict__ qkvb,
                            unsigned short* __restrict__ wprojt) {
  int p = blockIdx.x * 256 + threadIdx.x;
  if (p < 64 * 512) w1bf[p] = f2bf(w1[p]);
  if (p < 64 * 576) {
    int co = p / 576, k = p % 576;
    int tap = k >> 6, ci = k & 63;
    lwb[p] = f2bf(lw[co * 576 + ci * 9 + tap]);
  }
  if (p < 36 * 64) {
    int cin = p & 63, tm = p >> 6;
    int tap = tm >> 2, m = tm & 3;
    w3t[p] = w3[(cin * 4 + m) * 9 + tap];
  }
  if (p < 100 * 64) {
    int cin = p & 63, tm = p >> 6;
    int tap = tm >> 2, m = tm & 3;
    w5t[p] = w5[(cin * 4 + m) * 25 + tap];
  }
  if (p < 192 * 64) {
    int o = p >> 6, i = p & 63;
    float v = (o < 64) ? wq[i * 64 + o] : wkv[i * 128 + (o - 64)];
    wqkvt[p] = f2bf(v);
  }
  if (p < 192) qkvb[p] = (p < 64) ? bq[p] : bkv[p - 64];
  if (p < 64 * 64) {
    int o = p >> 6, i = p & 63;
    wprojt[p] = f2bf(wproj[i * 64 + o]);
  }
}

// ---------------- K1: LN1 + QKV via MFMA (16 tokens/block) + V-sum ----------
__global__ __launch_bounds__(256) void k_ln_qkv(
    const float* __restrict__ x, const float* __restrict__ g1, const float* __restrict__ b1,
    const unsigned short* __restrict__ wqkvt, const float* __restrict__ qkvb,
    unsigned short* __restrict__ q16, unsigned short* __restrict__ k16,
    float* __restrict__ vo, unsigned short* __restrict__ x16,
    float* __restrict__ sumv) {
  __shared__ __align__(16) unsigned short xnS[16 * XNP];
  int bid = blockIdx.x;
  int b = bid / 196, tile = bid % 196;
  size_t tok0 = (size_t)b * Nv + tile * 16;
  int t = threadIdx.x;
  int w = t >> 6, l = t & 63;
  int tokL = t >> 4;        // 0..15
  int ch0 = (t & 15) * 4;
  size_t tok = tok0 + tokL;
  float v[4];
  *(float4*)v = *(const float4*)&x[tok * 64 + ch0];
  {
    unsigned int pk[2] = {pack2(v[0], v[1]), pack2(v[2], v[3])};
    *(uint2*)&x16[tok * 64 + ch0] = *(uint2*)pk;
  }
  float s = v[0] + v[1] + v[2] + v[3];
  float s2 = v[0] * v[0] + v[1] * v[1] + v[2] * v[2] + v[3] * v[3];
#pragma unroll
  for (int off = 1; off <= 8; off <<= 1) {
    s += __shfl_xor(s, off, 64);
    s2 += __shfl_xor(s2, off, 64);
  }
  float m = s * (1.f / 64.f);
  float rs = rsqrtf(s2 * (1.f / 64.f) - m * m + EPS);
  {
    unsigned int pk[2];
    float a0_ = (v[0] - m) * rs * g1[ch0] + b1[ch0];
    float a1_ = (v[1] - m) * rs * g1[ch0 + 1] + b1[ch0 + 1];
    float a2_ = (v[2] - m) * rs * g1[ch0 + 2] + b1[ch0 + 2];
    float a3_ = (v[3] - m) * rs * g1[ch0 + 3] + b1[ch0 + 3];
    pk[0] = pack2(a0_, a1_);
    pk[1] = pack2(a2_, a3_);
    *(uint2*)&xnS[tokL * XNP + ch0] = *(uint2*)pk;
  }
  __syncthreads();
  int n = l & 15, q = l >> 4;
  const bf16x8 a0 = *(const bf16x8*)&xnS[n * XNP + q * 8];
  const bf16x8 a1 = *(const bf16x8*)&xnS[n * XNP + 32 + q * 8];
  // Q tile j=w
  {
    const unsigned short* wr = &wqkvt[(size_t)(w * 16 + n) * 64];
    bf16x8 b0 = *(const bf16x8*)&wr[q * 8];
    bf16x8 b1_ = *(const bf16x8*)&wr[32 + q * 8];
    f32x4 acc = {0.f, 0.f, 0.f, 0.f};
    acc = __builtin_amdgcn_mfma_f32_16x16x32_bf16(a0, b0, acc, 0, 0, 0);
    acc = __builtin_amdgcn_mfma_f32_16x16x32_bf16(a1, b1_, acc, 0, 0, 0);
    float bias = qkvb[w * 16 + n];
#pragma unroll
    for (int r = 0; r < 4; ++r)
      q16[(tok0 + q * 4 + r) * 64 + w * 16 + n] = f2bf(acc[r] + bias);
  }
  // K tile j=w
  {
    const unsigned short* wr = &wqkvt[(size_t)((w + 4) * 16 + n) * 64];
    bf16x8 b0 = *(const bf16x8*)&wr[q * 8];
    bf16x8 b1_ = *(const bf16x8*)&wr[32 + q * 8];
    f32x4 acc = {0.f, 0.f, 0.f, 0.f};
    acc = __builtin_amdgcn_mfma_f32_16x16x32_bf16(a0, b0, acc, 0, 0, 0);
    acc = __builtin_amdgcn_mfma_f32_16x16x32_bf16(a1, b1_, acc, 0, 0, 0);
    float bias = qkvb[64 + w * 16 + n];
#pragma unroll
    for (int r = 0; r < 4; ++r)
      k16[(tok0 + q * 4 + r) * 64 + w * 16 + n] = f2bf(acc[r] + bias);
  }
  // V tile j=w + fused per-batch column sum
  {
    const unsigned short* wr = &wqkvt[(size_t)((w + 8) * 16 + n) * 64];
    bf16x8 b0 = *(const bf16x8*)&wr[q * 8];
    bf16x8 b1_ = *(const bf16x8*)&wr[32 + q * 8];
    f32x4 acc = {0.f, 0.f, 0.f, 0.f};
    acc = __builtin_amdgcn_mfma_f32_16x16x32_bf16(a0, b0, acc, 0, 0, 0);
    acc = __builtin_amdgcn_mfma_f32_16x16x32_bf16(a1, b1_, acc, 0, 0, 0);
    float bias = qkvb[128 + w * 16 + n];
    float vp = acc[0] + acc[1] + acc[2] + acc[3] + 4.0f * bias;
#pragma unroll
    for (int r = 0; r < 4; ++r)
      vo[(tok0 + q * 4 + r) * 64 + w * 16 + n] = acc[r] + bias;
    vp += __shfl_xor(vp, 16, 64);
    vp += __shfl_xor(vp, 32, 64);
    if (q == 0) atomicAdd(&sumv[b * 64 + w * 16 + n], vp);
  }
}

// ---------------- K2a: MFMA QK^T + dual-chain branchless top-8 (quarter) ----
// Two independent top-8 states (even/odd chunks) break the loop-carried sort
// dependency; 2-deep clamped prefetch covers L2 latency. Scores UNSCALED.
__global__ __launch_bounds__(256) void k_attn_topk(
    const unsigned short* __restrict__ q16, const unsigned short* __restrict__ k16,
    unsigned int* __restrict__ top8out) {
  __shared__ unsigned int candLDS[16][4][9];
  int bid = blockIdx.x;
  int quarter = bid & 3;
  int lin = bid >> 2;
  int b = lin / 196, tile = lin % 196;
  int qbase = b * Nv + tile * 16;
  size_t bN = (size_t)b * Nv;
  int t = threadIdx.x;
  int w = t >> 6, lane = t & 63;
  int qcol = lane & 15, quad = lane >> 4;

  const bf16x8 qf0 = *(const bf16x8*)&q16[((size_t)(qbase + qcol)) * 64 + quad * 8];
  const bf16x8 qf1 = *(const bf16x8*)&q16[((size_t)(qbase + qcol)) * 64 + 32 + quad * 8];

  unsigned int t8a[8], t8b[8];
  unsigned int PACKNEG = packScore(-1e30f, 0);
#pragma unroll
  for (int u = 0; u < 8; ++u) { t8a[u] = PACKNEG; t8b[u] = PACKNEG; }

  int chBeg = (quarter * 49) >> 2;        // 0,12,24,36
  int chEnd = ((quarter + 1) * 49) >> 2;  // 12,24,36,49
  int nch = chEnd - chBeg;                // 12 or 13
  int keyRow = w * 16 + qcol;
  const unsigned short* kbase = &k16[(bN + (size_t)chBeg * 64 + keyRow) * 64];

  // prefetch chunks 0 and 1 (nch >= 12 always)
  bf16x8 ka0 = *(const bf16x8*)&kbase[quad * 8];
  bf16x8 ka1 = *(const bf16x8*)&kbase[32 + quad * 8];
  bf16x8 kb0 = *(const bf16x8*)&kbase[(size_t)64 * 64 + quad * 8];
  bf16x8 kb1 = *(const bf16x8*)&kbase[(size_t)64 * 64 + 32 + quad * 8];

#pragma unroll 1
  for (int i = 0; i + 1 < nch; i += 2) {
    bf16x8 ca0 = ka0, ca1 = ka1, cb0 = kb0, cb1 = kb1;
    // clamped 2-deep prefetch (always-valid addresses, no branches)
    int ia = min(i + 2, nch - 1), ib = min(i + 3, nch - 1);
    ka0 = *(const bf16x8*)&kbase[(size_t)ia * 4096 + quad * 8];
    ka1 = *(const bf16x8*)&kbase[(size_t)ia * 4096 + 32 + quad * 8];
    kb0 = *(const bf16x8*)&kbase[(size_t)ib * 4096 + quad * 8];
    kb1 = *(const bf16x8*)&kbase[(size_t)ib * 4096 + 32 + quad * 8];

    f32x4 accA = {0.f, 0.f, 0.f, 0.f};
    accA = __builtin_amdgcn_mfma_f32_16x16x32_bf16(ca0, qf0, accA, 0, 0, 0);
    accA = __builtin_amdgcn_mfma_f32_16x16x32_bf16(ca1, qf1, accA, 0, 0, 0);
    f32x4 accB = {0.f, 0.f, 0.f, 0.f};
    accB = __builtin_amdgcn_mfma_f32_16x16x32_bf16(cb0, qf0, accB, 0, 0, 0);
    accB = __builtin_amdgcn_mfma_f32_16x16x32_bf16(cb1, qf1, accB, 0, 0, 0);

    {
      int jb = (chBeg + i) * 64 + w * 16 + quad * 4;
      unsigned int p0 = packScore(accA[0], jb + 0);
      unsigned int p1 = packScore(accA[1], jb + 1);
      unsigned int p2 = packScore(accA[2], jb + 2);
      unsigned int p3 = packScore(accA[3], jb + 3);
      CSWAP(p0, p1); CSWAP(p2, p3); CSWAP(p0, p2); CSWAP(p1, p3); CSWAP(p1, p2);
      t8a[4] = max(t8a[4], p3);
      t8a[5] = max(t8a[5], p2);
      t8a[6] = max(t8a[6], p1);
      t8a[7] = max(t8a[7], p0);
      BITONIC8(t8a);
    }
    {
      int jb = (chBeg + i + 1) * 64 + w * 16 + quad * 4;
      unsigned int p0 = packScore(accB[0], jb + 0);
      unsigned int p1 = packScore(accB[1], jb + 1);
      unsigned int p2 = packScore(accB[2], jb + 2);
      unsigned int p3 = packScore(accB[3], jb + 3);
      CSWAP(p0, p1); CSWAP(p2, p3); CSWAP(p0, p2); CSWAP(p1, p3); CSWAP(p1, p2);
      t8b[4] = max(t8b[4], p3);
      t8b[5] = max(t8b[5], p2);
      t8b[6] = max(t8b[6], p1);
      t8b[7] = max(t8b[7], p0);
      BITONIC8(t8b);
    }
  }
  if (nch & 1) {  // leftover chunk (ka holds it via clamp)
    f32x4 accA = {0.f, 0.f, 0.f, 0.f};
    accA = __builtin_amdgcn_mfma_f32_16x16x32_bf16(ka0, qf0, accA, 0, 0, 0);
    accA = __builtin_amdgcn_mfma_f32_16x16x32_bf16(ka1, qf1, accA, 0, 0, 0);
    int jb = (chEnd - 1) * 64 + w * 16 + quad * 4;
    unsigned int p0 = packScore(accA[0], jb + 0);
    unsigned int p1 = packScore(accA[1], jb + 1);
    unsigned int p2 = packScore(accA[2], jb + 2);
    unsigned int p3 = packScore(accA[3], jb + 3);
    CSWAP(p0, p1); CSWAP(p2, p3); CSWAP(p0, p2); CSWAP(p1, p3); CSWAP(p1, p2);
    t8a[4] = max(t8a[4], p3);
    t8a[5] = max(t8a[5], p2);
    t8a[6] = max(t8a[6], p1);
    t8a[7] = max(t8a[7], p0);
    BITONIC8(t8a);
  }

  // merge the two chains
  unsigned int t8[8];
#pragma unroll
  for (int i = 0; i < 8; ++i) t8[i] = max(t8a[i], t8b[7 - i]);
  BITONIC8(t8);

#pragma unroll
  for (int step = 16; step <= 32; step <<= 1) {
    unsigned int o[8];
#pragma unroll
    for (int i = 0; i < 8; ++i) o[i] = (unsigned int)__shfl_xor((int)t8[i], step, 64);
    unsigned int nw[8];
#pragma unroll
    for (int i = 0; i < 8; ++i) nw[i] = max(t8[i], o[7 - i]);
#pragma unroll
    for (int i = 0; i < 8; ++i) t8[i] = nw[i];
    BITONIC8(t8);
  }
  if (quad == 0) {
#pragma unroll
    for (int i = 0; i < 8; ++i) candLDS[qcol][w][i] = t8[i];
  }
  __syncthreads();

  if (t < 16) {
    int r = t;
    int p0 = 0, p1 = 0, p2 = 0, p3 = 0;
    size_t obase = ((size_t)(bN + tile * 16 + r)) * 32 + quarter * 8;
#pragma unroll
    for (int u = 0; u < 8; ++u) {
      unsigned int c0 = (p0 < 8) ? candLDS[r][0][p0] : 0u;
      unsigned int c1 = (p1 < 8) ? candLDS[r][1][p1] : 0u;
      unsigned int c2 = (p2 < 8) ? candLDS[r][2][p2] : 0u;
      unsigned int c3 = (p3 < 8) ? candLDS[r][3][p3] : 0u;
      unsigned int best = c0;
      int bw = 0;
      if (c1 > best) { best = c1; bw = 1; }
      if (c2 > best) { best = c2; bw = 2; }
      if (c3 > best) { best = c3; bw = 3; }
      p0 += (bw == 0); p1 += (bw == 1); p2 += (bw == 2); p3 += (bw == 3);
      top8out[obase + u] = best;
    }
  }
}

// ---------------- K2b: merge quarters + PV + proj + LN1 + res + LN2 ---------
// 16 tokens/block, grid Bv*196.  (scores arrive UNSCALED -> apply SCALE here)
__global__ __launch_bounds__(256) void k_attn_proj(
    const unsigned int* __restrict__ top8, const float* __restrict__ vg,
    const float* __restrict__ sumv,
    const float* __restrict__ x, const float* __restrict__ loc,
    const unsigned short* __restrict__ wprojt, const float* __restrict__ bproj,
    const float* __restrict__ g1, const float* __restrict__ b1,
    const float* __restrict__ g2, const float* __restrict__ b2,
    float* __restrict__ x2, unsigned short* __restrict__ xn2b) {
  __shared__ float kwS[16][8];
  __shared__ int kidxS[16][8];
  __shared__ float invZS[16];
  __shared__ __align__(16) unsigned short gS[16 * XNP];
  __shared__ float yS[16 * 66];
  int bid = blockIdx.x;
  int b = bid / 196, tile = bid % 196;
  size_t bN = (size_t)b * Nv;
  size_t tok0 = bN + tile * 16;
  int t = threadIdx.x;
  // Phase A: merge the 4 sorted quarter-lists per row
  if (t < 16) {
    size_t base = (tok0 + t) * 32;
    unsigned int A[8];
#pragma unroll
    for (int i = 0; i < 8; ++i) A[i] = top8[base + i];
#pragma unroll
    for (int h = 1; h < 4; ++h) {
      unsigned int Bb[8];
#pragma unroll
      for (int i = 0; i < 8; ++i) Bb[i] = top8[base + h * 8 + i];
#pragma unroll
      for (int i = 0; i < 8; ++i) A[i] = max(A[i], Bb[7 - i]);
      BITONIC8(A);
    }
    float Z = (float)(Nv - TOPKv);
#pragma unroll
    for (int u = 0; u < 8; ++u) {
      float s = unpackScore(A[u]) * SCALE;
      float e = __expf(s);
      kwS[t][u] = e - 1.0f;
      kidxS[t][u] = (int)(A[u] & 0xFFFu);
      Z += e;
    }
    invZS[t] = 1.0f / Z;
  }
  __syncthreads();
  // Phase B: g = (sumv + sum_top8 (e^s-1) v)/Z -> gS (bf16)
  {
    int c = t & 63, rg = t >> 6;
    float sv = sumv[b * 64 + c];
#pragma unroll
    for (int rr = 0; rr < 4; ++rr) {
      int tokL = rg * 4 + rr;
      float acc = sv;
#pragma unroll
      for (int u = 0; u < 8; ++u)
        acc += kwS[tokL][u] * vg[(bN + kidxS[tokL][u]) * 64 + c];
      gS[tokL * XNP + c] = f2bf(acc * invZS[tokL]);
    }
  }
  __syncthreads();
  // Phase C: proj GEMM (wave w -> couts w*16..w*16+15), y = proj + loc
  int w = t >> 6, l = t & 63;
  int n = l & 15, q = l >> 4;
  {
    const bf16x8 a0 = *(const bf16x8*)&gS[n * XNP + q * 8];
    const bf16x8 a1 = *(const bf16x8*)&gS[n * XNP + 32 + q * 8];
    const unsigned short* wr = &wprojt[(size_t)(w * 16 + n) * 64];
    bf16x8 b0 = *(const bf16x8*)&wr[q * 8];
    bf16x8 b1_ = *(const bf16x8*)&wr[32 + q * 8];
    f32x4 acc = {0.f, 0.f, 0.f, 0.f};
    acc = __builtin_amdgcn_mfma_f32_16x16x32_bf16(a0, b0, acc, 0, 0, 0);
    acc = __builtin_amdgcn_mfma_f32_16x16x32_bf16(a1, b1_, acc, 0, 0, 0);
    float bias = bproj[w * 16 + n];
#pragma unroll
    for (int r = 0; r < 4; ++r) {
      size_t idx = (tok0 + q * 4 + r) * 64 + w * 16 + n;
      yS[(q * 4 + r) * 66 + w * 16 + n] = acc[r] + bias + loc[idx];
    }
  }
  __syncthreads();
  // Phase D: LN1 -> residual -> LN2 (16-lane group per token, 4 ch each)
  int tokL = t >> 4;
  int ch0 = (t & 15) * 4;
  size_t tok = tok0 + tokL;
  float y[4];
#pragma unroll
  for (int i = 0; i < 4; ++i) y[i] = yS[tokL * 66 + ch0 + i];
  float s = y[0] + y[1] + y[2] + y[3];
  float s2 = y[0] * y[0] + y[1] * y[1] + y[2] * y[2] + y[3] * y[3];
#pragma unroll
  for (int off = 1; off <= 8; off <<= 1) {
    s += __shfl_xor(s, off, 64);
    s2 += __shfl_xor(s2, off, 64);
  }
  float m1 = s * (1.f / 64.f);
  float rs1 = rsqrtf(s2 * (1.f / 64.f) - m1 * m1 + EPS);
  float xv[4];
  *(float4*)xv = *(const float4*)&x[tok * 64 + ch0];
  float x2v[4];
  float t_s = 0.f, t_s2 = 0.f;
#pragma unroll
  for (int i = 0; i < 4; ++i) {
    float t1 = (y[i] - m1) * rs1 * g1[ch0 + i] + b1[ch0 + i];
    x2v[i] = xv[i] + t1;
    t_s += x2v[i];
    t_s2 += x2v[i] * x2v[i];
  }
#pragma unroll
  for (int off = 1; off <= 8; off <<= 1) {
    t_s += __shfl_xor(t_s, off, 64);
    t_s2 += __shfl_xor(t_s2, off, 64);
  }
  float m2 = t_s * (1.f / 64.f);
  float rs2 = rsqrtf(t_s2 * (1.f / 64.f) - m2 * m2 + EPS);
  *(float4*)&x2[tok * 64 + ch0] = *(float4*)x2v;
  unsigned int pk[2];
  {
    float a0_ = (x2v[0] - m2) * rs2 * g2[ch0] + b2[ch0];
    float a1_ = (x2v[1] - m2) * rs2 * g2[ch0 + 1] + b2[ch0 + 1];
    float a2_ = (x2v[2] - m2) * rs2 * g2[ch0 + 2] + b2[ch0 + 2];
    float a3_ = (x2v[3] - m2) * rs2 * g2[ch0 + 3] + b2[ch0 + 3];
    pk[0] = pack2(a0_, a1_);
    pk[1] = pack2(a2_, a3_);
  }
  *(uint2*)&xn2b[tok * 64 + ch0] = *(uint2*)pk;
}

// ---------------- K3a: local 3x3 full conv (64->64) via im2col + MFMA -------
__global__ __launch_bounds__(256) void k_locconv(
    const unsigned short* __restrict__ x16, const unsigned short* __restrict__ lwb,
    const float* __restrict__ lb, float* __restrict__ loc) {
  __shared__ __align__(16) unsigned short im[16 * LCP];
  int bid = blockIdx.x;
  int b = bid / 196, rem = bid % 196;
  int th = rem / 7, tw = rem % 7;
  int h0 = th * 2, w0 = tw * 8;
  size_t bN = (size_t)b * Nv;
  int t = threadIdx.x;
  for (int p = t; p < 1152; p += 256) {
    int sub = p & 7, s = p >> 3;
    int tok = s / 9, tap = s % 9;
    int tr = tok >> 3, tc = tok & 7;
    int dh = tap / 3, dw = tap % 3;
    int gh = h0 + tr - 1 + dh, gw = w0 + tc - 1 + dw;
    bf16x8 v = {};
    if (gh >= 0 && gh < Hh && gw >= 0 && gw < Ww)
      v = *(const bf16x8*)&x16[(bN + gh * Ww + gw) * 64 + sub * 8];
    *(bf16x8*)&im[tok * LCP + tap * 64 + sub * 8] = v;
  }
  __syncthreads();
  int wv = t >> 6, lane = t & 63;
  int n16 = lane & 15, quad = lane >> 4;
  const unsigned short* wrow = &lwb[(size_t)(wv * 16 + n16) * 576];
  f32x4 acc = {0.f, 0.f, 0.f, 0.f};
#pragma unroll 6
  for (int kk = 0; kk < 18; ++kk) {
    bf16x8 af = *(const bf16x8*)&im[n16 * LCP + kk * 32 + quad * 8];
    bf16x8 bfr = *(const bf16x8*)&wrow[kk * 32 + quad * 8];
    acc = __builtin_amdgcn_mfma_f32_16x16x32_bf16(af, bfr, acc, 0, 0, 0);
  }
  float bias = lb[wv * 16 + n16];
#pragma unroll
  for (int r = 0; r < 4; ++r) {
    int tok = quad * 4 + r;
    int trr = tok >> 3, tcc = tok & 7;
    size_t idx = (bN + (size_t)(h0 + trr) * Ww + w0 + tcc) * 64 + wv * 16 + n16;
    loc[idx] = acc[r] + bias;
  }
}

// ---------------- K5: MSFN — depthwise in regs, 1x1 via MFMA ----------------
__global__ __launch_bounds__(256) void k_msfn(
    const unsigned short* __restrict__ xn2b, const float* __restrict__ x2,
    const float* __restrict__ w3t, const float* __restrict__ b3,
    const float* __restrict__ w5t, const float* __restrict__ b5,
    const unsigned short* __restrict__ w1bf, const float* __restrict__ b1,
    float* __restrict__ out) {
  __shared__ __align__(16) unsigned short xtS[6 * 12 * 64];
  __shared__ __align__(16) unsigned short tsS[16 * TSP];

  int bid = blockIdx.x;
  int b = bid / 196;
  int rem = bid % 196;
  int th = rem / 7, tw = rem % 7;
  int h0 = th * 2, w0 = tw * 8;
  size_t bN = (size_t)b * Nv;
  int t = threadIdx.x;

  unsigned int* xtU = (unsigned int*)xtS;
  for (int p = t; p < 6 * 12 * 32; p += 256) {
    int cp = p & 31, rc = p >> 5;
    int r = rc / 12, cc = rc % 12;
    int gh = h0 - 2 + r, gw = w0 - 2 + cc;
    unsigned int v = 0;
    if (gh >= 0 && gh < Hh && gw >= 0 && gw < Ww)
      v = *(const unsigned int*)&xn2b[(bN + gh * Ww + gw) * 64 + cp * 2];
    xtU[rc * 32 + cp] = v;
  }
  __syncthreads();

  int cin = t & 63, tg = t >> 6;
  int tr = tg >> 1, tc0 = (tg & 1) * 4;
  float win[5][8];
#pragma unroll
  for (int r = 0; r < 5; ++r)
#pragma unroll
    for (int c = 0; c < 8; ++c)
      win[r][c] = bf2f(xtS[((tr + r) * 12 + tc0 + c) * 64 + cin]);

  unsigned int* tsU = (unsigned int*)tsS;
#pragma unroll 1
  for (int m2 = 0; m2 < 4; m2 += 2) {
    float a3[2][9], a5[2][25], bb3[2], bb5[2];
#pragma unroll
    for (int mm = 0; mm < 2; ++mm) {
      int m = m2 + mm;
#pragma unroll
      for (int tap = 0; tap < 9; ++tap) a3[mm][tap] = w3t[(tap * 4 + m) * 64 + cin];
#pragma unroll
      for (int tap = 0; tap < 25; ++tap) a5[mm][tap] = w5t[(tap * 4 + m) * 64 + cin];
      bb3[mm] = b3[cin * 4 + m];
      bb5[mm] = b5[cin * 4 + m];
    }
#pragma unroll
    for (int tk = 0; tk < 4; ++tk) {
      int tok = tg * 4 + tk;
      unsigned int p3 = 0, p5 = 0;
#pragma unroll
      for (int mm = 0; mm < 2; ++mm) {
        float acc3 = bb3[mm];
#pragma unroll
        for (int kh = 0; kh < 3; ++kh)
#pragma unroll
          for (int kw2 = 0; kw2 < 3; ++kw2)
            acc3 += win[1 + kh][tk + 1 + kw2] * a3[mm][kh * 3 + kw2];
        float acc5 = bb5[mm];
#pragma unroll
        for (int kh = 0; kh < 5; ++kh)
#pragma unroll
          for (int kw2 = 0; kw2 < 5; ++kw2)
            acc5 += win[kh][tk + kw2] * a5[mm][kh * 5 + kw2];
        p3 |= (unsigned int)f2bf(acc3) << (16 * mm);
        p5 |= (unsigned int)f2bf(acc5) << (16 * mm);
      }
      tsU[(tok * TSP + cin * 4 + m2) >> 1] = p3;
      tsU[(tok * TSP + 256 + cin * 4 + m2) >> 1] = p5;
    }
  }
  __syncthreads();

  int wv = tg, lane = t & 63;
  int n16 = lane & 15, quad = lane >> 4;
  const unsigned short* wrow = &w1bf[(size_t)(wv * 16 + n16) * 512];
  f32x4 acc = {0.f, 0.f, 0.f, 0.f};
#pragma unroll 4
  for (int kk = 0; kk < 16; ++kk) {
    bf16x8 af = *(const bf16x8*)&tsS[n16 * TSP + kk * 32 + quad * 8];
    bf16x8 bfr = *(const bf16x8*)&wrow[kk * 32 + quad * 8];
    acc = __builtin_amdgcn_mfma_f32_16x16x32_bf16(af, bfr, acc, 0, 0, 0);
  }
  float bias = b1[wv * 16 + n16];
#pragma unroll
  for (int r = 0; r < 4; ++r) {
    int tok = quad * 4 + r;
    int trr = tok >> 3, tcc = tok & 7;
    size_t idx = (bN + (size_t)(h0 + trr) * Ww + w0 + tcc) * 64 + wv * 16 + n16;
    out[idx] = x2[idx] + acc[r] + bias;
  }
}

extern "C" void kernel_launch(void* const* d_in, const int* in_sizes, int n_in,
                              void* d_out, int out_size, void* d_ws, size_t ws_size,
                              hipStream_t stream) {
  const float* x = (const float*)d_in[0];
  const float* n1g = (const float*)d_in[1];
  const float* n1b = (const float*)d_in[2];
  const float* wq = (const float*)d_in[3];
  const float* bq = (const float*)d_in[4];
  const float* wkv = (const float*)d_in[5];
  const float* bkv = (const float*)d_in[6];
  const float* wproj = (const float*)d_in[7];
  const float* bproj = (const float*)d_in[8];
  const float* lw = (const float*)d_in[9];
  const float* lb = (const float*)d_in[10];
  const float* n2g = (const float*)d_in[11];
  const float* n2b = (const float*)d_in[12];
  const float* w3 = (const float*)d_in[13];
  const float* b3 = (const float*)d_in[14];
  const float* w5 = (const float*)d_in[15];
  const float* b5 = (const float*)d_in[16];
  const float* w1 = (const float*)d_in[17];
  const float* b1 = (const float*)d_in[18];
  float* out = (float*)d_out;

  float* ws = (float*)d_ws;
  const size_t TOK = (size_t)Bv * Nv * Cv;  // 802816
  float* vb = ws;
  float* sumv = vb + TOK;            // 256
  float* loc = sumv + 256;
  float* x2 = loc + TOK;
  float* w3t = x2 + TOK;             // 2304
  float* w5t = w3t + 2304;           // 6400
  float* qkvb = w5t + 6400;          // 192
  unsigned short* q16 = (unsigned short*)(qkvb + 192);
  unsigned short* k16 = q16 + TOK;
  unsigned short* xn2b = k16 + TOK;
  unsigned short* x16 = xn2b + TOK;
  unsigned short* w1bf = x16 + TOK;        // 64*512
  unsigned short* lwb = w1bf + 64 * 512;   // 64*576
  unsigned short* wqkvt = lwb + 64 * 576;  // 192*64
  unsigned short* wprojt = wqkvt + 192 * 64;  // 64*64
  unsigned int* top8ws = (unsigned int*)(wprojt + 64 * 64 + 64);  // 12544*32 uints

  hipMemsetAsync(sumv, 0, 256 * sizeof(float), stream);
  k_transpose<<<144, 256, 0, stream>>>(w1, lw, w3, w5, wq, wkv, bq, bkv, wproj,
                                       w1bf, lwb, w3t, w5t, wqkvt, qkvb, wprojt);
  k_ln_qkv<<<Bv * 196, 256, 0, stream>>>(x, n1g, n1b, wqkvt, qkvb, q16, k16, vb, x16, sumv);
  k_attn_topk<<<Bv * 196 * 4, 256, 0, stream>>>(q16, k16, top8ws);
  k_locconv<<<Bv * 196, 256, 0, stream>>>(x16, lwb, lb, loc);
  k_attn_proj<<<Bv * 196, 256, 0, stream>>>(top8ws, vb, sumv, x, loc, wprojt, bproj,
                                            n1g, n1b, n2g, n2b, x2, xn2b);
  k_msfn<<<Bv * 196, 256, 0, stream>>>(xn2b, x2, w3t, b3, w5t, b5, w1bf, b1, out);
}